// Round 4
// baseline (2585.644 us; speedup 1.0000x reference)
//
#include <hip/hip_runtime.h>
#include <stdint.h>

typedef uint16_t u16;
typedef uint32_t u32;

#define N_NODESC 100000
#define N_EDGESC 400000
#define E_TOT    500000   // edges + self loops
#define HID      256
#define NLAYERS  4
#define NGRAPHS  128
#define SEQLEN   5
#define VOCABC   5002
#define MAXDEPTH 20
#define NEG_SLOPE 0.2f
#define BN_EPSC  1e-5f

typedef __attribute__((ext_vector_type(8))) short short8;
typedef __attribute__((ext_vector_type(4))) float f32x4;
typedef __attribute__((ext_vector_type(4))) unsigned short u16x4;

__device__ __forceinline__ float b2f(u16 u){
  union { u32 i; float f; } v; v.i = ((u32)u) << 16; return v.f;
}
__device__ __forceinline__ u16 f2b(float f){
  union { float f; u32 i; } v; v.f = f;
  u32 u = v.i;
  u += 0x7FFFu + ((u >> 16) & 1u);   // RNE
  return (u16)(u >> 16);
}
// sanitize float: zero anything with |x| >= 32 or non-finite.
// Real params are ~N(0, 1/16)-scale; never triggers on valid data.
__device__ __forceinline__ float sanf(float x){
  float a = fabsf(x);
  return (a < 32.f) ? x : 0.f;    // NaN/Inf fail the compare -> 0
}
// dual-dtype parameter load: flag=1 -> f32, flag=0 -> bf16
__device__ __forceinline__ float ldp(const void* p, size_t i, int f){
  return f ? ((const float*)p)[i] : b2f(((const u16*)p)[i]);
}
__device__ __forceinline__ float ldps(const void* p, size_t i, int f){
  return sanf(ldp(p, i, f));
}

// ---------------- dtype detector: sample type_emb both ways ----------------
__global__ __launch_bounds__(64) void k_detect(const void* temb, int* flag){
  int lane = threadIdx.x;
  const u32* w32 = (const u32*)temb;
  int sf = 0, sb = 0;
  for (int i = lane; i < 256; i += 64){
    u32 w = w32[i];
    union { u32 u; float f; } cf; cf.u = w;
    float af = fabsf(cf.f);
    if (cf.f == 0.0f || (af >= 1e-12f && af <= 4096.f)) sf++;
    float b0 = b2f((u16)(w & 0xFFFFu));
    float b1 = b2f((u16)(w >> 16));
    float a0 = fabsf(b0), a1 = fabsf(b1);
    if (b0 == 0.f || (a0 >= 1e-12f && a0 <= 4096.f)) sb++;
    if (b1 == 0.f || (a1 >= 1e-12f && a1 <= 4096.f)) sb++;
  }
  #pragma unroll
  for (int o = 1; o < 64; o <<= 1){ sf += __shfl_xor(sf, o); sb += __shfl_xor(sb, o); }
  if (lane == 0) *flag = (2*sf > sb) ? 1 : 0;
}

// ---------------- utility ----------------
__global__ __launch_bounds__(256) void k_zero(int* __restrict__ p, int n){
  int i = blockIdx.x*256 + threadIdx.x;
  if (i < n) p[i] = 0;
}

// ---------------- embedding (writes bf16 h) ----------------
__global__ __launch_bounds__(256) void k_embed(const int* __restrict__ x, const int* __restrict__ nd,
    const void* __restrict__ temb, const void* __restrict__ aemb, const void* __restrict__ demb,
    u16* __restrict__ h, const int* __restrict__ flagp){
  int f = *flagp;
  int n = blockIdx.x; int c = threadIdx.x;
  int t = x[n*2+0], a = x[n*2+1];
  if (t < 0) t = 0; if (t > 97) t = 97;
  if (a < 0) a = 0; if (a > 10029) a = 10029;
  int d = nd[n]; if (d > MAXDEPTH) d = MAXDEPTH; if (d < 0) d = 0;
  float v = ldps(temb, (size_t)t*HID+c, f) + ldps(aemb, (size_t)a*HID+c, f) + ldps(demb, (size_t)d*HID+c, f);
  v = fminf(fmaxf(v, -1e4f), 1e4f);
  h[(size_t)n*HID+c] = f2b(v);
}

// ---------------- edge sort by dst (counting sort) ----------------
__global__ __launch_bounds__(256) void k_hist(const int* __restrict__ ei, int* __restrict__ cnt){
  int e = blockIdx.x*256 + threadIdx.x;
  if (e >= E_TOT) return;
  int dst = (e < N_EDGESC) ? ei[N_EDGESC + e] : (e - N_EDGESC);
  if ((unsigned)dst >= N_NODESC) return;
  atomicAdd(&cnt[dst], 1);
}

// single block, 256 threads: sequential chunked Hillis-Steele scan
__global__ __launch_bounds__(256) void k_scan(const int* __restrict__ cnt, int* __restrict__ off){
  __shared__ int lds[256];
  __shared__ int s_carry;
  int tid = threadIdx.x;
  if (tid == 0) s_carry = 0;
  __syncthreads();
  for (int base = 0; base < N_NODESC; base += 256){
    int i = base + tid;
    int v = (i < N_NODESC) ? cnt[i] : 0;
    lds[tid] = v;
    __syncthreads();
    for (int s = 1; s < 256; s <<= 1){
      int t = (tid >= s) ? lds[tid - s] : 0;
      __syncthreads();
      lds[tid] += t;
      __syncthreads();
    }
    int incl = lds[tid];
    if (i < N_NODESC) off[i] = s_carry + incl - v;   // exclusive
    __syncthreads();
    if (tid == 255) s_carry += incl;
    __syncthreads();
  }
  if (tid == 0) off[N_NODESC] = s_carry;
}

__global__ __launch_bounds__(256) void k_scatter(const int* __restrict__ ei,
    const int* __restrict__ soff, int* __restrict__ cursor, int* __restrict__ ssorted){
  int e = blockIdx.x*256 + threadIdx.x;
  if (e >= E_TOT) return;
  int src = (e < N_EDGESC) ? ei[e]            : (e - N_EDGESC);
  int dst = (e < N_EDGESC) ? ei[N_EDGESC + e] : (e - N_EDGESC);
  if ((unsigned)dst >= N_NODESC || (unsigned)src >= N_NODESC) return;
  int pos = soff[dst] + atomicAdd(&cursor[dst], 1);
  if ((unsigned)pos < E_TOT) ssorted[pos] = src;
}

// ---------------- W transpose -> bf16 WT, all layers ----------------
__global__ __launch_bounds__(256) void k_transW(const void* __restrict__ W, u16* __restrict__ WT,
    const int* __restrict__ flagp){
  int f = *flagp;
  int l = blockIdx.y, n2 = blockIdx.x, k = threadIdx.x;
  WT[(l*HID + n2)*HID + k] = f2b(ldps(W, (size_t)(l*HID + k)*HID + n2, f));
}

// ---------------- GEMM: hh = h @ W, MFMA 16x16x32 bf16 ----------------
// A frag: lane holds A[m=lane&15][k=quad*8+j]
// B frag: lane holds B[k=quad*8+j][n=lane&15]  (from WT[n][k])
// D frag: col=lane&15, row=quad*4+reg
__global__ __launch_bounds__(256) void k_gemm(const u16* __restrict__ h,
    const u16* __restrict__ WT, u16* __restrict__ hh){
  int wid = threadIdx.x >> 6, lane = threadIdx.x & 63;
  int m = lane & 15, quad = lane >> 4;
  int r0 = blockIdx.x*64 + wid*16;
  int row = r0 + m;
  f32x4 acc[16];
  #pragma unroll
  for (int i = 0; i < 16; ++i) acc[i] = (f32x4){0.f,0.f,0.f,0.f};

  for (int ks = 0; ks < 8; ++ks){
    int kb = ks*32 + quad*8;
    short8 a;
    if (row < N_NODESC){
      a = *(const short8*)(h + (size_t)row*HID + kb);
    } else {
      #pragma unroll
      for (int j = 0; j < 8; ++j) a[j] = 0;
    }
    #pragma unroll
    for (int nt = 0; nt < 16; ++nt){
      const short8 b = *(const short8*)(WT + (nt*16 + m)*HID + kb);
      acc[nt] = __builtin_amdgcn_mfma_f32_16x16x32_bf16(a, b, acc[nt], 0, 0, 0);
    }
  }
  int orow0 = r0 + quad*4;
  #pragma unroll
  for (int nt = 0; nt < 16; ++nt){
    int col = nt*16 + m;
    #pragma unroll
    for (int r = 0; r < 4; ++r){
      int orow = orow0 + r;
      if (orow < N_NODESC) hh[(size_t)orow*HID + col] = f2b(acc[nt][r]);
    }
  }
}

// ---------------- per-head scores ----------------
__global__ __launch_bounds__(256) void k_scores(const u16* __restrict__ hh,
    const void* __restrict__ asrc, const void* __restrict__ adst,
    float* __restrict__ ssrc, float* __restrict__ sdst, int H,
    const int* __restrict__ flagp, int loff){
  int f = *flagp;
  int wid = threadIdx.x >> 6, lane = threadIdx.x & 63;
  int n = blockIdx.x*4 + wid;
  if (n >= N_NODESC) return;
  int f0 = lane*4;
  const u16x4 hv = *(const u16x4*)(hh + (size_t)n*HID + f0);
  float ps = 0.f, pd = 0.f;
  #pragma unroll
  for (int j = 0; j < 4; ++j){
    float hvf = b2f(hv[j]);
    ps += hvf * ldps(asrc, (size_t)loff + f0 + j, f);
    pd += hvf * ldps(adst, (size_t)loff + f0 + j, f);
  }
  if (H == 8){
    #pragma unroll
    for (int o = 1; o < 8; o <<= 1){ ps += __shfl_xor(ps, o); pd += __shfl_xor(pd, o); }
    if ((lane & 7) == 0){ ssrc[n*8 + (lane>>3)] = ps; sdst[n*8 + (lane>>3)] = pd; }
  } else {
    #pragma unroll
    for (int o = 1; o < 64; o <<= 1){ ps += __shfl_xor(ps, o); pd += __shfl_xor(pd, o); }
    if (lane == 0){ ssrc[n] = ps; sdst[n] = pd; }
  }
}

// ---------------- attention core: online softmax aggregate for node n ----------------
// gat_bias dropped: per-channel constant cancels exactly inside BatchNorm.
__device__ __forceinline__ void attn_node(int n, int lane, const u16* __restrict__ hh,
    const float* __restrict__ ssrc, const float* __restrict__ sdst,
    const int* __restrict__ soff, const int* __restrict__ ssorted, int H, float r[4]){
  int f0 = lane*4;
  int hl = (H == 8) ? (lane >> 3) : 0;
  float sd = sdst[n*H + hl];
  int beg = soff[n], end = soff[n+1];
  if (beg < 0) beg = 0;
  if (end > E_TOT) end = E_TOT;
  float mval = -1e30f, lval = 0.f;
  float o0 = 0.f, o1 = 0.f, o2 = 0.f, o3 = 0.f;
  for (int i = beg; i < end; ++i){
    int src = ssorted[i];
    if ((unsigned)src >= N_NODESC) continue;
    float ev = ssrc[src*H + hl] + sd;
    ev = (ev > 0.f) ? ev : NEG_SLOPE*ev;
    float nm = fmaxf(mval, ev);
    float sc = __expf(mval - nm);
    float wv = __expf(ev - nm);
    const u16x4 hvv = *(const u16x4*)(hh + (size_t)src*HID + f0);
    lval = lval*sc + wv;
    o0 = o0*sc + wv*b2f(hvv[0]);
    o1 = o1*sc + wv*b2f(hvv[1]);
    o2 = o2*sc + wv*b2f(hvv[2]);
    o3 = o3*sc + wv*b2f(hvv[3]);
    mval = nm;
  }
  float inv = (lval > 0.f) ? 1.f/lval : 0.f;
  r[0] = o0*inv; r[1] = o1*inv; r[2] = o2*inv; r[3] = o3*inv;
}

// Tier A: write gout (bf16)
__global__ __launch_bounds__(256) void k_attn_gout(const u16* __restrict__ hh,
    const float* __restrict__ ssrc, const float* __restrict__ sdst,
    const int* __restrict__ soff, const int* __restrict__ ssorted,
    u16* __restrict__ gout, int H){
  int wid = threadIdx.x >> 6, lane = threadIdx.x & 63;
  int n = blockIdx.x*4 + wid;
  if (n >= N_NODESC) return;
  float r[4];
  attn_node(n, lane, hh, ssrc, sdst, soff, ssorted, H, r);
  u16x4 o;
  #pragma unroll
  for (int j = 0; j < 4; ++j) o[j] = f2b(r[j]);
  *(u16x4*)(gout + (size_t)n*HID + lane*4) = o;
}

// Tier B pass 1: recompute attention, block-reduce BN stats
__global__ __launch_bounds__(256) void k_attn_stats(const u16* __restrict__ hh,
    const float* __restrict__ ssrc, const float* __restrict__ sdst,
    const int* __restrict__ soff, const int* __restrict__ ssorted,
    float* __restrict__ bnsum, float* __restrict__ bnsq, int H){
  __shared__ float lsum[4*HID];
  __shared__ float lsq[4*HID];
  int wid = threadIdx.x >> 6, lane = threadIdx.x & 63;
  int gw = blockIdx.x*4 + wid;
  int nw = gridDim.x*4;
  float s[4] = {0.f,0.f,0.f,0.f}, q[4] = {0.f,0.f,0.f,0.f};
  for (int n = gw; n < N_NODESC; n += nw){
    float r[4];
    attn_node(n, lane, hh, ssrc, sdst, soff, ssorted, H, r);
    #pragma unroll
    for (int j = 0; j < 4; ++j){ s[j] += r[j]; q[j] += r[j]*r[j]; }
  }
  int f0 = lane*4;
  #pragma unroll
  for (int j = 0; j < 4; ++j){ lsum[wid*HID + f0 + j] = s[j]; lsq[wid*HID + f0 + j] = q[j]; }
  __syncthreads();
  int c = threadIdx.x;
  float ts = lsum[c] + lsum[HID+c] + lsum[2*HID+c] + lsum[3*HID+c];
  float tq = lsq[c]  + lsq[HID+c]  + lsq[2*HID+c]  + lsq[3*HID+c];
  atomicAdd(&bnsum[c], ts);
  atomicAdd(&bnsq[c], tq);
}

// Tier B pass 2: recompute attention, fused BN+ReLU+residual into h
__global__ __launch_bounds__(256) void k_attn_apply(const u16* __restrict__ hh,
    const float* __restrict__ ssrc, const float* __restrict__ sdst,
    const int* __restrict__ soff, const int* __restrict__ ssorted,
    const float* __restrict__ scale, const float* __restrict__ shift,
    u16* __restrict__ h, int H){
  int wid = threadIdx.x >> 6, lane = threadIdx.x & 63;
  int n = blockIdx.x*4 + wid;
  if (n >= N_NODESC) return;
  float r[4];
  attn_node(n, lane, hh, ssrc, sdst, soff, ssorted, H, r);
  int f0 = lane*4;
  const f32x4 sc = *(const f32x4*)(scale + f0);
  const f32x4 sh = *(const f32x4*)(shift + f0);
  u16x4 hv = *(u16x4*)(h + (size_t)n*HID + f0);
  u16x4 o;
  #pragma unroll
  for (int j = 0; j < 4; ++j){
    float t = r[j]*sc[j] + sh[j];
    t = (t > 0.f) ? t : 0.f;
    o[j] = f2b(b2f(hv[j]) + t);
  }
  *(u16x4*)(h + (size_t)n*HID + f0) = o;
}

// ---------------- batchnorm (Tier A) ----------------
__global__ __launch_bounds__(256) void k_bn_stats(const u16* __restrict__ g,
    float* __restrict__ bnsum, float* __restrict__ bnsq){
  int c = threadIdx.x;
  float s = 0.f, q = 0.f;
  for (int r = blockIdx.x; r < N_NODESC; r += gridDim.x){
    float v = b2f(g[(size_t)r*HID + c]);
    s += v; q += v*v;
  }
  atomicAdd(&bnsum[c], s);
  atomicAdd(&bnsq[c], q);
}

__global__ __launch_bounds__(256) void k_bn_final(const float* __restrict__ bnsum,
    const float* __restrict__ bnsq, const void* __restrict__ gamma, const void* __restrict__ beta,
    float* __restrict__ scale, float* __restrict__ shift,
    const int* __restrict__ flagp, int loff){
  int f = *flagp;
  int c = threadIdx.x;
  float mu  = bnsum[c] * (1.f/N_NODESC);
  float var = bnsq[c]  * (1.f/N_NODESC) - mu*mu;
  if (!(var >= 0.f)) var = 0.f;   // also catches NaN
  float sc = ldps(gamma, (size_t)loff + c, f) * rsqrtf(var + BN_EPSC);
  scale[c] = sc;
  shift[c] = ldps(beta, (size_t)loff + c, f) - mu*sc;
}

// Tier A: h += relu(bn(gout))
__global__ __launch_bounds__(256) void k_bn_apply(const u16* __restrict__ g,
    const float* __restrict__ scale, const float* __restrict__ shift, u16* __restrict__ h){
  int idx = blockIdx.x*256 + threadIdx.x;           // N*HID/4 total
  int c4 = (idx & 63) * 4;
  const u16x4 gv = *(const u16x4*)(g + (size_t)idx*4);
  const f32x4 sc = *(const f32x4*)(scale + c4);
  const f32x4 sh = *(const f32x4*)(shift + c4);
  u16x4 hv = *(u16x4*)(h + (size_t)idx*4);
  u16x4 o;
  #pragma unroll
  for (int j = 0; j < 4; ++j){
    float t = b2f(gv[j])*sc[j] + sh[j];
    t = (t > 0.f) ? t : 0.f;
    o[j] = f2b(b2f(hv[j]) + t);
  }
  *(u16x4*)(h + (size_t)idx*4) = o;
}

// ---------------- mean pool per graph (batch sorted) ----------------
__global__ __launch_bounds__(256) void k_count(const int* __restrict__ batch, int* __restrict__ gcnt){
  int i = blockIdx.x*256 + threadIdx.x;
  if (i < N_NODESC){
    int b = batch[i];
    if ((unsigned)b < NGRAPHS) atomicAdd(&gcnt[b], 1);
  }
}

__global__ __launch_bounds__(256) void k_pool(const u16* __restrict__ h,
    const int* __restrict__ batch, float* __restrict__ gsum){
  int c = threadIdx.x;
  int r0 = blockIdx.x * 256;
  int r1 = min(r0 + 256, N_NODESC);
  if (r0 >= N_NODESC) return;
  int cur = batch[r0];
  float acc = 0.f;
  for (int r = r0; r < r1; ++r){
    int b = batch[r];
    if ((unsigned)b >= NGRAPHS) continue;
    if (b != cur){
      if ((unsigned)cur < NGRAPHS) atomicAdd(&gsum[cur*HID + c], acc);
      acc = 0.f; cur = b;
    }
    acc += b2f(h[(size_t)r*HID + c]);
  }
  if ((unsigned)cur < NGRAPHS) atomicAdd(&gsum[cur*HID + c], acc);
}

__global__ __launch_bounds__(256) void k_pool_div(const int* __restrict__ gcnt, float* __restrict__ gsum){
  int gi = blockIdx.x, c = threadIdx.x;
  int cc = gcnt[gi]; if (cc < 1) cc = 1;
  gsum[gi*HID + c] *= (1.f / (float)cc);
}

// ---------------- token predictors (dual-dtype weights AND output) ----------------
__global__ __launch_bounds__(256) void k_pred(const float* __restrict__ g,
    const void* __restrict__ tokW, const void* __restrict__ tokb, void* __restrict__ out,
    const int* __restrict__ flagp){
  __shared__ float glds[8*HID];
  int f = *flagp;
  int tid = threadIdx.x;
  int vt = blockIdx.x, gg = blockIdx.y, s = blockIdx.z;
  int g0 = gg*8;
  #pragma unroll
  for (int j = 0; j < 8; ++j) glds[j*HID + tid] = g[(g0+j)*HID + tid];
  __syncthreads();
  int v = vt*256 + tid;
  if (v >= VOCABC) return;
  float acc[8];
  #pragma unroll
  for (int j = 0; j < 8; ++j) acc[j] = 0.f;
  size_t wbase = (size_t)s*HID*VOCABC + v;
  for (int k = 0; k < HID; ++k){
    float w = ldps(tokW, wbase + (size_t)k*VOCABC, f);
    #pragma unroll
    for (int j = 0; j < 8; ++j) acc[j] += glds[j*HID + k] * w;
  }
  float bb = ldps(tokb, (size_t)s*VOCABC + v, f);
  #pragma unroll
  for (int j = 0; j < 8; ++j){
    float val = acc[j] + bb;
    size_t oi = ((size_t)(s*NGRAPHS + g0 + j)*VOCABC) + v;
    if (f) ((float*)out)[oi] = val;
    else   ((u16*)out)[oi]   = f2b(val);
  }
}

// ---------------- host launcher ----------------
extern "C" void kernel_launch(void* const* d_in, const int* in_sizes, int n_in,
                              void* d_out, int out_size, void* d_ws, size_t ws_size,
                              hipStream_t stream) {
  const int* x          = (const int*)d_in[0];
  const int* node_depth = (const int*)d_in[1];
  const int* edge_index = (const int*)d_in[2];
  const int* batch      = (const int*)d_in[3];
  const void* type_emb  = d_in[4];
  const void* attr_emb  = d_in[5];
  const void* depth_emb = d_in[6];
  const void* Ws        = d_in[7];
  const void* att_src   = d_in[8];
  const void* att_dst   = d_in[9];
  // d_in[10] = gat_bias: dropped (constant per channel cancels inside BatchNorm)
  const void* bn_gamma  = d_in[11];
  const void* bn_beta   = d_in[12];
  const void* tok_W     = d_in[13];
  const void* tok_b     = d_in[14];

  // ---- workspace carve ----
  char* base = (char*)d_ws;
  size_t off = 0;
  auto carve = [&](size_t bytes) -> void* {
    void* p = base + off;
    off += (bytes + 255) & ~(size_t)255;
    return p;
  };
  u16*   h     = (u16*)carve((size_t)N_NODESC*HID*2);     // 51.2 MB
  u16*   hh    = (u16*)carve((size_t)N_NODESC*HID*2);     // 51.2 MB
  float* ssrc  = (float*)carve((size_t)N_NODESC*8*4);     // 3.2 MB
  float* sdst  = (float*)carve((size_t)N_NODESC*8*4);     // 3.2 MB
  int*   soff  = (int*)carve((size_t)(N_NODESC+1)*4);
  int*   cursor= (int*)carve((size_t)N_NODESC*4);
  int*   ssorted=(int*)carve((size_t)E_TOT*4);            // 2.0 MB
  u16*   WT    = (u16*)carve((size_t)NLAYERS*HID*HID*2);  // 0.5 MB
  float* bnsum = (float*)carve(HID*4);
  float* bnsq  = (float*)carve(HID*4);
  float* bnscale=(float*)carve(HID*4);
  float* bnshift=(float*)carve(HID*4);
  float* gsum  = (float*)carve((size_t)NGRAPHS*HID*4);
  int*   gcnt  = (int*)carve((size_t)NGRAPHS*4);
  int*   dflag = (int*)carve(256);
  size_t common = off;                                    // ~111 MiB
  u16*   gout  = (u16*)carve((size_t)N_NODESC*HID*2);     // +51.2 MB
  const bool useGout = (off <= ws_size);
  if (common > ws_size) return;  // cannot run at all

  const int EB  = (E_TOT + 255)/256;
  const int NB4 = (N_NODESC + 3)/4;      // wave-per-node kernels

  // dtype detection first
  k_detect<<<1, 64, 0, stream>>>(type_emb, dflag);

  // setup
  k_embed<<<N_NODESC, 256, 0, stream>>>(x, node_depth, type_emb, attr_emb, depth_emb, h, dflag);
  k_transW<<<dim3(256, NLAYERS), 256, 0, stream>>>(Ws, WT, dflag);
  k_zero<<<(N_NODESC+255)/256, 256, 0, stream>>>(cursor, N_NODESC);
  k_hist<<<EB, 256, 0, stream>>>(edge_index, cursor);
  k_scan<<<1, 256, 0, stream>>>(cursor, soff);
  k_zero<<<(N_NODESC+255)/256, 256, 0, stream>>>(cursor, N_NODESC);
  k_zero<<<EB, 256, 0, stream>>>(ssorted, E_TOT);          // poison-proof unwritten slots
  k_scatter<<<EB, 256, 0, stream>>>(edge_index, soff, cursor, ssorted);

  // layers
  for (int l = 0; l < NLAYERS; ++l){
    int H = (l == NLAYERS-1) ? 1 : 8;
    k_gemm<<<(N_NODESC + 63)/64, 256, 0, stream>>>(h, WT + (size_t)l*HID*HID, hh);
    k_scores<<<NB4, 256, 0, stream>>>(hh, att_src, att_dst, ssrc, sdst, H, dflag, l*HID);
    k_zero<<<2, 256, 0, stream>>>((int*)bnsum, 2*HID);   // bnsum+bnsq contiguous
    if (useGout){
      k_attn_gout<<<NB4, 256, 0, stream>>>(hh, ssrc, sdst, soff, ssorted, gout, H);
      k_bn_stats<<<256, 256, 0, stream>>>(gout, bnsum, bnsq);
      k_bn_final<<<1, 256, 0, stream>>>(bnsum, bnsq, bn_gamma, bn_beta, bnscale, bnshift, dflag, l*HID);
      k_bn_apply<<<(N_NODESC*HID/4)/256, 256, 0, stream>>>(gout, bnscale, bnshift, h);
    } else {
      k_attn_stats<<<2048, 256, 0, stream>>>(hh, ssrc, sdst, soff, ssorted, bnsum, bnsq, H);
      k_bn_final<<<1, 256, 0, stream>>>(bnsum, bnsq, bn_gamma, bn_beta, bnscale, bnshift, dflag, l*HID);
      k_attn_apply<<<NB4, 256, 0, stream>>>(hh, ssrc, sdst, soff, ssorted, bnscale, bnshift, h, H);
    }
  }

  // pool
  k_zero<<<(NGRAPHS*HID+255)/256, 256, 0, stream>>>((int*)gsum, NGRAPHS*HID);
  k_zero<<<1, 256, 0, stream>>>(gcnt, NGRAPHS);
  k_count<<<(N_NODESC+255)/256, 256, 0, stream>>>(batch, gcnt);
  k_pool<<<(N_NODESC+255)/256, 256, 0, stream>>>(h, batch, gsum);
  k_pool_div<<<NGRAPHS, 256, 0, stream>>>(gcnt, gsum);

  // predictors
  k_pred<<<dim3((VOCABC+255)/256, NGRAPHS/8, SEQLEN), 256, 0, stream>>>(gsum, tok_W, tok_b, d_out, dflag);
}

// Round 5
// 2178.594 us; speedup vs baseline: 1.1868x; 1.1868x over previous
//
#include <hip/hip_runtime.h>
#include <stdint.h>

typedef uint16_t u16;
typedef uint32_t u32;

#define N_NODESC 100000
#define N_EDGESC 400000
#define E_TOT    500000   // edges + self loops
#define HID      256
#define NLAYERS  4
#define NGRAPHS  128
#define SEQLEN   5
#define VOCABC   5002
#define MAXDEPTH 20
#define NEG_SLOPE 0.2f
#define BN_EPSC  1e-5f
#define NCHUNK   ((N_NODESC + 255)/256)   // 391

typedef __attribute__((ext_vector_type(8))) short short8;
typedef __attribute__((ext_vector_type(4))) float f32x4;
typedef __attribute__((ext_vector_type(4))) unsigned short u16x4;

__device__ __forceinline__ float b2f(u16 u){
  union { u32 i; float f; } v; v.i = ((u32)u) << 16; return v.f;
}
__device__ __forceinline__ u16 f2b(float f){
  union { float f; u32 i; } v; v.f = f;
  u32 u = v.i;
  u += 0x7FFFu + ((u >> 16) & 1u);   // RNE
  return (u16)(u >> 16);
}
// dual-dtype parameter load: flag=1 -> f32, flag=0 -> bf16
__device__ __forceinline__ float ldp(const void* p, size_t i, int f){
  return f ? ((const float*)p)[i] : b2f(((const u16*)p)[i]);
}

// ---------------- dtype detector: sample type_emb both ways ----------------
__global__ __launch_bounds__(64) void k_detect(const void* temb, int* flag){
  int lane = threadIdx.x;
  const u32* w32 = (const u32*)temb;
  int sf = 0, sb = 0;
  for (int i = lane; i < 256; i += 64){
    u32 w = w32[i];
    union { u32 u; float f; } cf; cf.u = w;
    float af = fabsf(cf.f);
    if (cf.f == 0.0f || (af >= 1e-12f && af <= 4096.f)) sf++;
    float b0 = b2f((u16)(w & 0xFFFFu));
    float b1 = b2f((u16)(w >> 16));
    float a0 = fabsf(b0), a1 = fabsf(b1);
    if (b0 == 0.f || (a0 >= 1e-12f && a0 <= 4096.f)) sb++;
    if (b1 == 0.f || (a1 >= 1e-12f && a1 <= 4096.f)) sb++;
  }
  #pragma unroll
  for (int o = 1; o < 64; o <<= 1){ sf += __shfl_xor(sf, o); sb += __shfl_xor(sb, o); }
  if (lane == 0) *flag = (2*sf > sb) ? 1 : 0;
}

// ---------------- utility ----------------
__global__ __launch_bounds__(256) void k_zero(int* __restrict__ p, int n){
  int i = blockIdx.x*256 + threadIdx.x;
  if (i < n) p[i] = 0;
}

// ---------------- embedding (writes bf16 h) ----------------
__global__ __launch_bounds__(256) void k_embed(const int* __restrict__ x, const int* __restrict__ nd,
    const void* __restrict__ temb, const void* __restrict__ aemb, const void* __restrict__ demb,
    u16* __restrict__ h, const int* __restrict__ flagp){
  int f = *flagp;
  int n = blockIdx.x; int c = threadIdx.x;
  int t = x[n*2+0], a = x[n*2+1];
  if (t < 0) t = 0; if (t > 97) t = 97;
  if (a < 0) a = 0; if (a > 10029) a = 10029;
  int d = nd[n]; if (d > MAXDEPTH) d = MAXDEPTH; if (d < 0) d = 0;
  float v = ldp(temb, (size_t)t*HID+c, f) + ldp(aemb, (size_t)a*HID+c, f) + ldp(demb, (size_t)d*HID+c, f);
  h[(size_t)n*HID+c] = f2b(v);
}

// ---------------- edge sort by dst (counting sort) ----------------
__global__ __launch_bounds__(256) void k_hist(const int* __restrict__ ei, int* __restrict__ cnt){
  int e = blockIdx.x*256 + threadIdx.x;
  if (e >= E_TOT) return;
  int dst = (e < N_EDGESC) ? ei[N_EDGESC + e] : (e - N_EDGESC);
  if ((unsigned)dst >= N_NODESC) return;
  atomicAdd(&cnt[dst], 1);
}

// hierarchical scan, phase 1: per-256-chunk exclusive scan + chunk total
__global__ __launch_bounds__(256) void k_scan_part(const int* __restrict__ cnt,
    int* __restrict__ off, int* __restrict__ btot){
  __shared__ int lds[256];
  int b = blockIdx.x, tid = threadIdx.x;
  int i = b*256 + tid;
  int v = (i < N_NODESC) ? cnt[i] : 0;
  lds[tid] = v;
  __syncthreads();
  #pragma unroll
  for (int s = 1; s < 256; s <<= 1){
    int t = (tid >= s) ? lds[tid - s] : 0;
    __syncthreads();
    lds[tid] += t;
    __syncthreads();
  }
  if (i < N_NODESC) off[i] = lds[tid] - v;   // chunk-local exclusive
  if (tid == 255) btot[b] = lds[255];
}

// phase 2: scan the 391 chunk totals (1 block), write grand total to offN
__global__ __launch_bounds__(256) void k_scan_tot(const int* __restrict__ btot,
    int* __restrict__ boff, int* __restrict__ offN){
  __shared__ int lds[256];
  __shared__ int s_carry;
  int tid = threadIdx.x;
  if (tid == 0) s_carry = 0;
  __syncthreads();
  for (int base = 0; base < NCHUNK; base += 256){
    int i = base + tid;
    int v = (i < NCHUNK) ? btot[i] : 0;
    lds[tid] = v;
    __syncthreads();
    #pragma unroll
    for (int s = 1; s < 256; s <<= 1){
      int t = (tid >= s) ? lds[tid - s] : 0;
      __syncthreads();
      lds[tid] += t;
      __syncthreads();
    }
    if (i < NCHUNK) boff[i] = s_carry + lds[tid] - v;
    __syncthreads();
    if (tid == 255) s_carry += lds[255];
    __syncthreads();
  }
  if (tid == 0) *offN = s_carry;
}

// phase 3: add chunk offsets; also re-zero cursor for the scatter pass
__global__ __launch_bounds__(256) void k_scan_add(int* __restrict__ off,
    const int* __restrict__ boff, int* __restrict__ cursor){
  int b = blockIdx.x;
  int i = b*256 + threadIdx.x;
  if (i < N_NODESC){ off[i] += boff[b]; cursor[i] = 0; }
}

__global__ __launch_bounds__(256) void k_scatter(const int* __restrict__ ei,
    const int* __restrict__ soff, int* __restrict__ cursor, int* __restrict__ ssorted){
  int e = blockIdx.x*256 + threadIdx.x;
  if (e >= E_TOT) return;
  int src = (e < N_EDGESC) ? ei[e]            : (e - N_EDGESC);
  int dst = (e < N_EDGESC) ? ei[N_EDGESC + e] : (e - N_EDGESC);
  if ((unsigned)dst >= N_NODESC || (unsigned)src >= N_NODESC) return;
  int pos = soff[dst] + atomicAdd(&cursor[dst], 1);
  if ((unsigned)pos < E_TOT) ssorted[pos] = src;
}

// ---------------- W transpose -> bf16 WT, all layers ----------------
__global__ __launch_bounds__(256) void k_transW(const void* __restrict__ W, u16* __restrict__ WT,
    const int* __restrict__ flagp){
  int f = *flagp;
  int l = blockIdx.y, n2 = blockIdx.x, k = threadIdx.x;
  WT[(l*HID + n2)*HID + k] = f2b(ldp(W, (size_t)(l*HID + k)*HID + n2, f));
}

// ---------------- GEMM: hh = h @ W, MFMA 16x16x32 bf16 ----------------
// A frag: lane holds A[m=lane&15][k=quad*8+j]
// B frag: lane holds B[k=quad*8+j][n=lane&15]  (from WT[n][k])
// D frag: col=lane&15, row=quad*4+reg
__global__ __launch_bounds__(256) void k_gemm(const u16* __restrict__ h,
    const u16* __restrict__ WT, u16* __restrict__ hh){
  int wid = threadIdx.x >> 6, lane = threadIdx.x & 63;
  int m = lane & 15, quad = lane >> 4;
  int r0 = blockIdx.x*64 + wid*16;
  int row = r0 + m;
  f32x4 acc[16];
  #pragma unroll
  for (int i = 0; i < 16; ++i) acc[i] = (f32x4){0.f,0.f,0.f,0.f};

  for (int ks = 0; ks < 8; ++ks){
    int kb = ks*32 + quad*8;
    short8 a;
    if (row < N_NODESC){
      a = *(const short8*)(h + (size_t)row*HID + kb);
    } else {
      #pragma unroll
      for (int j = 0; j < 8; ++j) a[j] = 0;
    }
    #pragma unroll
    for (int nt = 0; nt < 16; ++nt){
      const short8 b = *(const short8*)(WT + (nt*16 + m)*HID + kb);
      acc[nt] = __builtin_amdgcn_mfma_f32_16x16x32_bf16(a, b, acc[nt], 0, 0, 0);
    }
  }
  int orow0 = r0 + quad*4;
  #pragma unroll
  for (int nt = 0; nt < 16; ++nt){
    int col = nt*16 + m;
    #pragma unroll
    for (int r = 0; r < 4; ++r){
      int orow = orow0 + r;
      if (orow < N_NODESC) hh[(size_t)orow*HID + col] = f2b(acc[nt][r]);
    }
  }
}

// ---------------- per-head scores (block 0 also zeroes BN accumulators) ----------------
__global__ __launch_bounds__(256) void k_scores(const u16* __restrict__ hh,
    const void* __restrict__ asrc, const void* __restrict__ adst,
    float* __restrict__ ssrc, float* __restrict__ sdst, int H,
    const int* __restrict__ flagp, int loff,
    float* __restrict__ bnsum, float* __restrict__ bnsq){
  if (blockIdx.x == 0){ bnsum[threadIdx.x] = 0.f; bnsq[threadIdx.x] = 0.f; }
  int f = *flagp;
  int wid = threadIdx.x >> 6, lane = threadIdx.x & 63;
  int n = blockIdx.x*4 + wid;
  if (n >= N_NODESC) return;
  int f0 = lane*4;
  const u16x4 hv = *(const u16x4*)(hh + (size_t)n*HID + f0);
  float ps = 0.f, pd = 0.f;
  #pragma unroll
  for (int j = 0; j < 4; ++j){
    float hvf = b2f(hv[j]);
    ps += hvf * ldp(asrc, (size_t)loff + f0 + j, f);
    pd += hvf * ldp(adst, (size_t)loff + f0 + j, f);
  }
  if (H == 8){
    #pragma unroll
    for (int o = 1; o < 8; o <<= 1){ ps += __shfl_xor(ps, o); pd += __shfl_xor(pd, o); }
    if ((lane & 7) == 0){ ssrc[n*8 + (lane>>3)] = ps; sdst[n*8 + (lane>>3)] = pd; }
  } else {
    #pragma unroll
    for (int o = 1; o < 64; o <<= 1){ ps += __shfl_xor(ps, o); pd += __shfl_xor(pd, o); }
    if (lane == 0){ ssrc[n] = ps; sdst[n] = pd; }
  }
}

// ---------------- attention core: online softmax aggregate for node n ----------------
// gat_bias dropped: per-channel constant cancels exactly inside BatchNorm.
__device__ __forceinline__ void attn_node(int n, int lane, const u16* __restrict__ hh,
    const float* __restrict__ ssrc, const float* __restrict__ sdst,
    const int* __restrict__ soff, const int* __restrict__ ssorted, int H, float r[4]){
  int f0 = lane*4;
  int hl = (H == 8) ? (lane >> 3) : 0;
  float sd = sdst[n*H + hl];
  int beg = soff[n], end = soff[n+1];
  if (beg < 0) beg = 0;
  if (end > E_TOT) end = E_TOT;
  float mval = -1e30f, lval = 0.f;
  float o0 = 0.f, o1 = 0.f, o2 = 0.f, o3 = 0.f;
  for (int i = beg; i < end; ++i){
    int src = ssorted[i];
    if ((unsigned)src >= N_NODESC) continue;
    float ev = ssrc[src*H + hl] + sd;
    ev = (ev > 0.f) ? ev : NEG_SLOPE*ev;
    float nm = fmaxf(mval, ev);
    float sc = __expf(mval - nm);
    float wv = __expf(ev - nm);
    const u16x4 hvv = *(const u16x4*)(hh + (size_t)src*HID + f0);
    lval = lval*sc + wv;
    o0 = o0*sc + wv*b2f(hvv[0]);
    o1 = o1*sc + wv*b2f(hvv[1]);
    o2 = o2*sc + wv*b2f(hvv[2]);
    o3 = o3*sc + wv*b2f(hvv[3]);
    mval = nm;
  }
  float inv = (lval > 0.f) ? 1.f/lval : 0.f;
  r[0] = o0*inv; r[1] = o1*inv; r[2] = o2*inv; r[3] = o3*inv;
}

// Tier A: write gout (bf16)
__global__ __launch_bounds__(256) void k_attn_gout(const u16* __restrict__ hh,
    const float* __restrict__ ssrc, const float* __restrict__ sdst,
    const int* __restrict__ soff, const int* __restrict__ ssorted,
    u16* __restrict__ gout, int H){
  int wid = threadIdx.x >> 6, lane = threadIdx.x & 63;
  int n = blockIdx.x*4 + wid;
  if (n >= N_NODESC) return;
  float r[4];
  attn_node(n, lane, hh, ssrc, sdst, soff, ssorted, H, r);
  u16x4 o;
  #pragma unroll
  for (int j = 0; j < 4; ++j) o[j] = f2b(r[j]);
  *(u16x4*)(gout + (size_t)n*HID + lane*4) = o;
}

// Tier B pass 1: recompute attention, block-reduce BN stats
__global__ __launch_bounds__(256) void k_attn_stats(const u16* __restrict__ hh,
    const float* __restrict__ ssrc, const float* __restrict__ sdst,
    const int* __restrict__ soff, const int* __restrict__ ssorted,
    float* __restrict__ bnsum, float* __restrict__ bnsq, int H){
  __shared__ float lsum[4*HID];
  __shared__ float lsq[4*HID];
  int wid = threadIdx.x >> 6, lane = threadIdx.x & 63;
  int gw = blockIdx.x*4 + wid;
  int nw = gridDim.x*4;
  float s[4] = {0.f,0.f,0.f,0.f}, q[4] = {0.f,0.f,0.f,0.f};
  for (int n = gw; n < N_NODESC; n += nw){
    float r[4];
    attn_node(n, lane, hh, ssrc, sdst, soff, ssorted, H, r);
    #pragma unroll
    for (int j = 0; j < 4; ++j){ s[j] += r[j]; q[j] += r[j]*r[j]; }
  }
  int f0 = lane*4;
  #pragma unroll
  for (int j = 0; j < 4; ++j){ lsum[wid*HID + f0 + j] = s[j]; lsq[wid*HID + f0 + j] = q[j]; }
  __syncthreads();
  int c = threadIdx.x;
  float ts = lsum[c] + lsum[HID+c] + lsum[2*HID+c] + lsum[3*HID+c];
  float tq = lsq[c]  + lsq[HID+c]  + lsq[2*HID+c]  + lsq[3*HID+c];
  atomicAdd(&bnsum[c], ts);
  atomicAdd(&bnsq[c], tq);
}

// Tier B pass 2: recompute attention, fused BN+ReLU+residual into h
__global__ __launch_bounds__(256) void k_attn_apply(const u16* __restrict__ hh,
    const float* __restrict__ ssrc, const float* __restrict__ sdst,
    const int* __restrict__ soff, const int* __restrict__ ssorted,
    const float* __restrict__ scale, const float* __restrict__ shift,
    u16* __restrict__ h, int H){
  int wid = threadIdx.x >> 6, lane = threadIdx.x & 63;
  int n = blockIdx.x*4 + wid;
  if (n >= N_NODESC) return;
  float r[4];
  attn_node(n, lane, hh, ssrc, sdst, soff, ssorted, H, r);
  int f0 = lane*4;
  const f32x4 sc = *(const f32x4*)(scale + f0);
  const f32x4 sh = *(const f32x4*)(shift + f0);
  u16x4 hv = *(u16x4*)(h + (size_t)n*HID + f0);
  u16x4 o;
  #pragma unroll
  for (int j = 0; j < 4; ++j){
    float t = r[j]*sc[j] + sh[j];
    t = (t > 0.f) ? t : 0.f;
    o[j] = f2b(b2f(hv[j]) + t);
  }
  *(u16x4*)(h + (size_t)n*HID + f0) = o;
}

// ---------------- batchnorm (Tier A) ----------------
__global__ __launch_bounds__(256) void k_bn_stats(const u16* __restrict__ g,
    float* __restrict__ bnsum, float* __restrict__ bnsq){
  int c = threadIdx.x;
  float s = 0.f, q = 0.f;
  for (int r = blockIdx.x; r < N_NODESC; r += gridDim.x){
    float v = b2f(g[(size_t)r*HID + c]);
    s += v; q += v*v;
  }
  atomicAdd(&bnsum[c], s);
  atomicAdd(&bnsq[c], q);
}

__global__ __launch_bounds__(256) void k_bn_final(const float* __restrict__ bnsum,
    const float* __restrict__ bnsq, const void* __restrict__ gamma, const void* __restrict__ beta,
    float* __restrict__ scale, float* __restrict__ shift,
    const int* __restrict__ flagp, int loff){
  int f = *flagp;
  int c = threadIdx.x;
  float mu  = bnsum[c] * (1.f/N_NODESC);
  float var = bnsq[c]  * (1.f/N_NODESC) - mu*mu;
  if (!(var >= 0.f)) var = 0.f;   // also catches NaN
  float sc = ldp(gamma, (size_t)loff + c, f) * rsqrtf(var + BN_EPSC);
  scale[c] = sc;
  shift[c] = ldp(beta, (size_t)loff + c, f) - mu*sc;
}

// Tier A: h += relu(bn(gout))
__global__ __launch_bounds__(256) void k_bn_apply(const u16* __restrict__ g,
    const float* __restrict__ scale, const float* __restrict__ shift, u16* __restrict__ h){
  int idx = blockIdx.x*256 + threadIdx.x;           // N*HID/4 total
  int c4 = (idx & 63) * 4;
  const u16x4 gv = *(const u16x4*)(g + (size_t)idx*4);
  const f32x4 sc = *(const f32x4*)(scale + c4);
  const f32x4 sh = *(const f32x4*)(shift + c4);
  u16x4 hv = *(u16x4*)(h + (size_t)idx*4);
  u16x4 o;
  #pragma unroll
  for (int j = 0; j < 4; ++j){
    float t = b2f(gv[j])*sc[j] + sh[j];
    t = (t > 0.f) ? t : 0.f;
    o[j] = f2b(b2f(hv[j]) + t);
  }
  *(u16x4*)(h + (size_t)idx*4) = o;
}

// ---------------- mean pool per graph (batch sorted) ----------------
__global__ __launch_bounds__(256) void k_count(const int* __restrict__ batch, int* __restrict__ gcnt){
  int i = blockIdx.x*256 + threadIdx.x;
  if (i < N_NODESC){
    int b = batch[i];
    if ((unsigned)b < NGRAPHS) atomicAdd(&gcnt[b], 1);
  }
}

__global__ __launch_bounds__(256) void k_pool(const u16* __restrict__ h,
    const int* __restrict__ batch, float* __restrict__ gsum){
  int c = threadIdx.x;
  int r0 = blockIdx.x * 256;
  int r1 = min(r0 + 256, N_NODESC);
  if (r0 >= N_NODESC) return;
  int cur = batch[r0];
  float acc = 0.f;
  for (int r = r0; r < r1; ++r){
    int b = batch[r];
    if ((unsigned)b >= NGRAPHS) continue;
    if (b != cur){
      if ((unsigned)cur < NGRAPHS) atomicAdd(&gsum[cur*HID + c], acc);
      acc = 0.f; cur = b;
    }
    acc += b2f(h[(size_t)r*HID + c]);
  }
  if ((unsigned)cur < NGRAPHS) atomicAdd(&gsum[cur*HID + c], acc);
}

// ---------------- token predictors: 32 graphs/block, mean-div fused ----------------
__global__ __launch_bounds__(256) void k_pred(const float* __restrict__ g,
    const int* __restrict__ gcnt,
    const void* __restrict__ tokW, const void* __restrict__ tokb, void* __restrict__ out,
    const int* __restrict__ flagp){
  __shared__ float glds[32*HID];   // 32 KB
  __shared__ float cinv[32];
  int f = *flagp;
  int tid = threadIdx.x;
  int vt = blockIdx.x, gg = blockIdx.y, s = blockIdx.z;
  int g0 = gg*32;
  if (tid < 32){
    int cc = gcnt[g0 + tid]; if (cc < 1) cc = 1;
    cinv[tid] = 1.f/(float)cc;
  }
  __syncthreads();
  #pragma unroll
  for (int j = 0; j < 32; ++j) glds[j*HID + tid] = g[(size_t)(g0+j)*HID + tid] * cinv[j];
  __syncthreads();
  int v = vt*256 + tid;
  if (v >= VOCABC) return;
  float acc[32];
  #pragma unroll
  for (int j = 0; j < 32; ++j) acc[j] = 0.f;
  size_t wbase = (size_t)s*HID*VOCABC + v;
  for (int k = 0; k < HID; ++k){
    float w = ldp(tokW, wbase + (size_t)k*VOCABC, f);
    #pragma unroll
    for (int j = 0; j < 32; ++j) acc[j] += glds[j*HID + k] * w;
  }
  float bb = ldp(tokb, (size_t)s*VOCABC + v, f);
  #pragma unroll
  for (int j = 0; j < 32; ++j){
    float val = acc[j] + bb;
    size_t oi = ((size_t)(s*NGRAPHS + g0 + j)*VOCABC) + v;
    if (f) ((float*)out)[oi] = val;
    else   ((u16*)out)[oi]   = f2b(val);
  }
}

// ---------------- host launcher ----------------
extern "C" void kernel_launch(void* const* d_in, const int* in_sizes, int n_in,
                              void* d_out, int out_size, void* d_ws, size_t ws_size,
                              hipStream_t stream) {
  const int* x          = (const int*)d_in[0];
  const int* node_depth = (const int*)d_in[1];
  const int* edge_index = (const int*)d_in[2];
  const int* batch      = (const int*)d_in[3];
  const void* type_emb  = d_in[4];
  const void* attr_emb  = d_in[5];
  const void* depth_emb = d_in[6];
  const void* Ws        = d_in[7];
  const void* att_src   = d_in[8];
  const void* att_dst   = d_in[9];
  // d_in[10] = gat_bias: dropped (constant per channel cancels inside BatchNorm)
  const void* bn_gamma  = d_in[11];
  const void* bn_beta   = d_in[12];
  const void* tok_W     = d_in[13];
  const void* tok_b     = d_in[14];

  // ---- workspace carve ----
  char* base = (char*)d_ws;
  size_t off = 0;
  auto carve = [&](size_t bytes) -> void* {
    void* p = base + off;
    off += (bytes + 255) & ~(size_t)255;
    return p;
  };
  u16*   h     = (u16*)carve((size_t)N_NODESC*HID*2);     // 51.2 MB
  u16*   hh    = (u16*)carve((size_t)N_NODESC*HID*2);     // 51.2 MB
  float* ssrc  = (float*)carve((size_t)N_NODESC*8*4);     // 3.2 MB
  float* sdst  = (float*)carve((size_t)N_NODESC*8*4);     // 3.2 MB
  int*   soff  = (int*)carve((size_t)(N_NODESC+1)*4);
  int*   cursor= (int*)carve((size_t)N_NODESC*4);
  int*   ssorted=(int*)carve((size_t)E_TOT*4);            // 2.0 MB
  int*   btot  = (int*)carve((size_t)NCHUNK*4);
  int*   boff  = (int*)carve((size_t)NCHUNK*4);
  u16*   WT    = (u16*)carve((size_t)NLAYERS*HID*HID*2);  // 0.5 MB
  float* bnsum = (float*)carve(HID*4);
  float* bnsq  = (float*)carve(HID*4);
  float* bnscale=(float*)carve(HID*4);
  float* bnshift=(float*)carve(HID*4);
  float* gsum  = (float*)carve((size_t)NGRAPHS*HID*4);    // 128 KB (256B-aligned size)
  int*   gcnt  = (int*)carve((size_t)NGRAPHS*4);          // adjacent to gsum
  int*   dflag = (int*)carve(256);
  size_t common = off;
  u16*   gout  = (u16*)carve((size_t)N_NODESC*HID*2);     // +51.2 MB
  const bool useGout = (off <= ws_size);
  if (common > ws_size) return;  // cannot run at all

  const int EB  = (E_TOT + 255)/256;
  const int NB4 = (N_NODESC + 3)/4;      // wave-per-node kernels

  // dtype detection first
  k_detect<<<1, 64, 0, stream>>>(type_emb, dflag);

  // setup
  k_embed<<<N_NODESC, 256, 0, stream>>>(x, node_depth, type_emb, attr_emb, depth_emb, h, dflag);
  k_transW<<<dim3(256, NLAYERS), 256, 0, stream>>>(Ws, WT, dflag);
  k_zero<<<NCHUNK, 256, 0, stream>>>(cursor, N_NODESC);
  k_hist<<<EB, 256, 0, stream>>>(edge_index, cursor);
  k_scan_part<<<NCHUNK, 256, 0, stream>>>(cursor, soff, btot);
  k_scan_tot<<<1, 256, 0, stream>>>(btot, boff, soff + N_NODESC);
  k_scan_add<<<NCHUNK, 256, 0, stream>>>(soff, boff, cursor);   // also zeroes cursor
  k_scatter<<<EB, 256, 0, stream>>>(edge_index, soff, cursor, ssorted);

  // layers
  for (int l = 0; l < NLAYERS; ++l){
    int H = (l == NLAYERS-1) ? 1 : 8;
    k_gemm<<<(N_NODESC + 63)/64, 256, 0, stream>>>(h, WT + (size_t)l*HID*HID, hh);
    k_scores<<<NB4, 256, 0, stream>>>(hh, att_src, att_dst, ssrc, sdst, H, dflag, l*HID, bnsum, bnsq);
    if (useGout){
      k_attn_gout<<<NB4, 256, 0, stream>>>(hh, ssrc, sdst, soff, ssorted, gout, H);
      k_bn_stats<<<256, 256, 0, stream>>>(gout, bnsum, bnsq);
      k_bn_final<<<1, 256, 0, stream>>>(bnsum, bnsq, bn_gamma, bn_beta, bnscale, bnshift, dflag, l*HID);
      k_bn_apply<<<(N_NODESC*HID/4)/256, 256, 0, stream>>>(gout, bnscale, bnshift, h);
    } else {
      k_attn_stats<<<2048, 256, 0, stream>>>(hh, ssrc, sdst, soff, ssorted, bnsum, bnsq, H);
      k_bn_final<<<1, 256, 0, stream>>>(bnsum, bnsq, bn_gamma, bn_beta, bnscale, bnshift, dflag, l*HID);
      k_attn_apply<<<NB4, 256, 0, stream>>>(hh, ssrc, sdst, soff, ssorted, bnscale, bnshift, h, H);
    }
  }

  // pool (gsum+gcnt are adjacent in ws -> single zero launch)
  k_zero<<<(NGRAPHS*HID + NGRAPHS + 255)/256, 256, 0, stream>>>((int*)gsum, NGRAPHS*HID + NGRAPHS);
  k_count<<<NCHUNK, 256, 0, stream>>>(batch, gcnt);
  k_pool<<<NCHUNK, 256, 0, stream>>>(h, batch, gsum);

  // predictors (mean-div fused via gcnt)
  k_pred<<<dim3((VOCABC+255)/256, NGRAPHS/32, SEQLEN), 256, 0, stream>>>(gsum, gcnt, tok_W, tok_b, d_out, dflag);
}

// Round 6
// 1894.414 us; speedup vs baseline: 1.3649x; 1.1500x over previous
//
#include <hip/hip_runtime.h>
#include <stdint.h>

typedef uint16_t u16;
typedef uint32_t u32;

#define N_NODESC 100000
#define N_EDGESC 400000
#define E_TOT    500000   // edges + self loops
#define HID      256
#define NLAYERS  4
#define NGRAPHS  128
#define SEQLEN   5
#define VOCABC   5002
#define MAXDEPTH 20
#define NEG_SLOPE 0.2f
#define BN_EPSC  1e-5f
#define NCHUNK   ((N_NODESC + 255)/256)   // 391

typedef __attribute__((ext_vector_type(8))) short short8;
typedef __attribute__((ext_vector_type(4))) float f32x4;
typedef __attribute__((ext_vector_type(4))) unsigned short u16x4;

__device__ __forceinline__ float b2f(u16 u){
  union { u32 i; float f; } v; v.i = ((u32)u) << 16; return v.f;
}
__device__ __forceinline__ u16 f2b(float f){
  union { float f; u32 i; } v; v.f = f;
  u32 u = v.i;
  u += 0x7FFFu + ((u >> 16) & 1u);   // RNE
  return (u16)(u >> 16);
}
// dual-dtype parameter load: flag=1 -> f32, flag=0 -> bf16
__device__ __forceinline__ float ldp(const void* p, size_t i, int f){
  return f ? ((const float*)p)[i] : b2f(((const u16*)p)[i]);
}

// ---------------- dtype detector: sample type_emb both ways ----------------
__global__ __launch_bounds__(64) void k_detect(const void* temb, int* flag){
  int lane = threadIdx.x;
  const u32* w32 = (const u32*)temb;
  int sf = 0, sb = 0;
  for (int i = lane; i < 256; i += 64){
    u32 w = w32[i];
    union { u32 u; float f; } cf; cf.u = w;
    float af = fabsf(cf.f);
    if (cf.f == 0.0f || (af >= 1e-12f && af <= 4096.f)) sf++;
    float b0 = b2f((u16)(w & 0xFFFFu));
    float b1 = b2f((u16)(w >> 16));
    float a0 = fabsf(b0), a1 = fabsf(b1);
    if (b0 == 0.f || (a0 >= 1e-12f && a0 <= 4096.f)) sb++;
    if (b1 == 0.f || (a1 >= 1e-12f && a1 <= 4096.f)) sb++;
  }
  #pragma unroll
  for (int o = 1; o < 64; o <<= 1){ sf += __shfl_xor(sf, o); sb += __shfl_xor(sb, o); }
  if (lane == 0) *flag = (2*sf > sb) ? 1 : 0;
}

// ---------------- utility ----------------
__global__ __launch_bounds__(256) void k_zero(int* __restrict__ p, int n){
  int i = blockIdx.x*256 + threadIdx.x;
  if (i < n) p[i] = 0;
}

// ---------------- embedding (writes bf16 h; also zeroes cursor[n]) ----------------
__global__ __launch_bounds__(256) void k_embed(const int* __restrict__ x, const int* __restrict__ nd,
    const void* __restrict__ temb, const void* __restrict__ aemb, const void* __restrict__ demb,
    u16* __restrict__ h, const int* __restrict__ flagp, int* __restrict__ cursor){
  int f = *flagp;
  int n = blockIdx.x; int c = threadIdx.x;
  if (c == 0) cursor[n] = 0;   // histogram counter zero, ready before k_hist
  int t = x[n*2+0], a = x[n*2+1];
  if (t < 0) t = 0; if (t > 97) t = 97;
  if (a < 0) a = 0; if (a > 10029) a = 10029;
  int d = nd[n]; if (d > MAXDEPTH) d = MAXDEPTH; if (d < 0) d = 0;
  float v = ldp(temb, (size_t)t*HID+c, f) + ldp(aemb, (size_t)a*HID+c, f) + ldp(demb, (size_t)d*HID+c, f);
  h[(size_t)n*HID+c] = f2b(v);
}

// ---------------- edge sort by dst (counting sort) ----------------
__global__ __launch_bounds__(256) void k_hist(const int* __restrict__ ei, int* __restrict__ cnt){
  int e = blockIdx.x*256 + threadIdx.x;
  if (e >= E_TOT) return;
  int dst = (e < N_EDGESC) ? ei[N_EDGESC + e] : (e - N_EDGESC);
  if ((unsigned)dst >= N_NODESC) return;
  atomicAdd(&cnt[dst], 1);
}

// hierarchical scan, phase 1: per-256-chunk exclusive scan + chunk total
__global__ __launch_bounds__(256) void k_scan_part(const int* __restrict__ cnt,
    int* __restrict__ off, int* __restrict__ btot){
  __shared__ int lds[256];
  int b = blockIdx.x, tid = threadIdx.x;
  int i = b*256 + tid;
  int v = (i < N_NODESC) ? cnt[i] : 0;
  lds[tid] = v;
  __syncthreads();
  #pragma unroll
  for (int s = 1; s < 256; s <<= 1){
    int t = (tid >= s) ? lds[tid - s] : 0;
    __syncthreads();
    lds[tid] += t;
    __syncthreads();
  }
  if (i < N_NODESC) off[i] = lds[tid] - v;   // chunk-local exclusive
  if (tid == 255) btot[b] = lds[255];
}

// phase 2: scan the 391 chunk totals (1 block), write grand total to offN
__global__ __launch_bounds__(256) void k_scan_tot(const int* __restrict__ btot,
    int* __restrict__ boff, int* __restrict__ offN){
  __shared__ int lds[256];
  __shared__ int s_carry;
  int tid = threadIdx.x;
  if (tid == 0) s_carry = 0;
  __syncthreads();
  for (int base = 0; base < NCHUNK; base += 256){
    int i = base + tid;
    int v = (i < NCHUNK) ? btot[i] : 0;
    lds[tid] = v;
    __syncthreads();
    #pragma unroll
    for (int s = 1; s < 256; s <<= 1){
      int t = (tid >= s) ? lds[tid - s] : 0;
      __syncthreads();
      lds[tid] += t;
      __syncthreads();
    }
    if (i < NCHUNK) boff[i] = s_carry + lds[tid] - v;
    __syncthreads();
    if (tid == 255) s_carry += lds[255];
    __syncthreads();
  }
  if (tid == 0) *offN = s_carry;
}

// phase 3: add chunk offsets; also re-zero cursor for the scatter pass
__global__ __launch_bounds__(256) void k_scan_add(int* __restrict__ off,
    const int* __restrict__ boff, int* __restrict__ cursor){
  int b = blockIdx.x;
  int i = b*256 + threadIdx.x;
  if (i < N_NODESC){ off[i] += boff[b]; cursor[i] = 0; }
}

__global__ __launch_bounds__(256) void k_scatter(const int* __restrict__ ei,
    const int* __restrict__ soff, int* __restrict__ cursor, int* __restrict__ ssorted){
  int e = blockIdx.x*256 + threadIdx.x;
  if (e >= E_TOT) return;
  int src = (e < N_EDGESC) ? ei[e]            : (e - N_EDGESC);
  int dst = (e < N_EDGESC) ? ei[N_EDGESC + e] : (e - N_EDGESC);
  if ((unsigned)dst >= N_NODESC || (unsigned)src >= N_NODESC) return;
  int pos = soff[dst] + atomicAdd(&cursor[dst], 1);
  if ((unsigned)pos < E_TOT) ssorted[pos] = src;
}

// ---------------- W transpose -> bf16 WT, all layers ----------------
__global__ __launch_bounds__(256) void k_transW(const void* __restrict__ W, u16* __restrict__ WT,
    const int* __restrict__ flagp){
  int f = *flagp;
  int l = blockIdx.y, n2 = blockIdx.x, k = threadIdx.x;
  WT[(l*HID + n2)*HID + k] = f2b(ldp(W, (size_t)(l*HID + k)*HID + n2, f));
}

// ---------------- GEMM: hh = h @ W, MFMA 16x16x32 bf16 ----------------
// A frag: lane holds A[m=lane&15][k=quad*8+j]
// B frag: lane holds B[k=quad*8+j][n=lane&15]  (from WT[n][k])
// D frag: col=lane&15, row=quad*4+reg
__global__ __launch_bounds__(256) void k_gemm(const u16* __restrict__ h,
    const u16* __restrict__ WT, u16* __restrict__ hh){
  int wid = threadIdx.x >> 6, lane = threadIdx.x & 63;
  int m = lane & 15, quad = lane >> 4;
  int r0 = blockIdx.x*64 + wid*16;
  int row = r0 + m;
  f32x4 acc[16];
  #pragma unroll
  for (int i = 0; i < 16; ++i) acc[i] = (f32x4){0.f,0.f,0.f,0.f};

  for (int ks = 0; ks < 8; ++ks){
    int kb = ks*32 + quad*8;
    short8 a;
    if (row < N_NODESC){
      a = *(const short8*)(h + (size_t)row*HID + kb);
    } else {
      #pragma unroll
      for (int j = 0; j < 8; ++j) a[j] = 0;
    }
    #pragma unroll
    for (int nt = 0; nt < 16; ++nt){
      const short8 b = *(const short8*)(WT + (nt*16 + m)*HID + kb);
      acc[nt] = __builtin_amdgcn_mfma_f32_16x16x32_bf16(a, b, acc[nt], 0, 0, 0);
    }
  }
  int orow0 = r0 + quad*4;
  #pragma unroll
  for (int nt = 0; nt < 16; ++nt){
    int col = nt*16 + m;
    #pragma unroll
    for (int r = 0; r < 4; ++r){
      int orow = orow0 + r;
      if (orow < N_NODESC) hh[(size_t)orow*HID + col] = f2b(acc[nt][r]);
    }
  }
}

// ---------------- per-head scores (block 0 also zeroes BN accumulators) ----------------
__global__ __launch_bounds__(256) void k_scores(const u16* __restrict__ hh,
    const void* __restrict__ asrc, const void* __restrict__ adst,
    float* __restrict__ ssrc, float* __restrict__ sdst, int H,
    const int* __restrict__ flagp, int loff,
    float* __restrict__ bnsum, float* __restrict__ bnsq){
  if (blockIdx.x == 0){ bnsum[threadIdx.x] = 0.f; bnsq[threadIdx.x] = 0.f; }
  int f = *flagp;
  int wid = threadIdx.x >> 6, lane = threadIdx.x & 63;
  int n = blockIdx.x*4 + wid;
  if (n >= N_NODESC) return;
  int f0 = lane*4;
  const u16x4 hv = *(const u16x4*)(hh + (size_t)n*HID + f0);
  float ps = 0.f, pd = 0.f;
  #pragma unroll
  for (int j = 0; j < 4; ++j){
    float hvf = b2f(hv[j]);
    ps += hvf * ldp(asrc, (size_t)loff + f0 + j, f);
    pd += hvf * ldp(adst, (size_t)loff + f0 + j, f);
  }
  if (H == 8){
    #pragma unroll
    for (int o = 1; o < 8; o <<= 1){ ps += __shfl_xor(ps, o); pd += __shfl_xor(pd, o); }
    if ((lane & 7) == 0){ ssrc[n*8 + (lane>>3)] = ps; sdst[n*8 + (lane>>3)] = pd; }
  } else {
    #pragma unroll
    for (int o = 1; o < 64; o <<= 1){ ps += __shfl_xor(ps, o); pd += __shfl_xor(pd, o); }
    if (lane == 0){ ssrc[n] = ps; sdst[n] = pd; }
  }
}

// ---------------- attention core: online softmax aggregate for node n ----------------
// gat_bias dropped: per-channel constant cancels exactly inside BatchNorm.
__device__ __forceinline__ void attn_node(int n, int lane, const u16* __restrict__ hh,
    const float* __restrict__ ssrc, const float* __restrict__ sdst,
    const int* __restrict__ soff, const int* __restrict__ ssorted, int H, float r[4]){
  int f0 = lane*4;
  int hl = (H == 8) ? (lane >> 3) : 0;
  float sd = sdst[n*H + hl];
  int beg = soff[n], end = soff[n+1];
  if (beg < 0) beg = 0;
  if (end > E_TOT) end = E_TOT;
  float mval = -1e30f, lval = 0.f;
  float o0 = 0.f, o1 = 0.f, o2 = 0.f, o3 = 0.f;
  for (int i = beg; i < end; ++i){
    int src = ssorted[i];
    if ((unsigned)src >= N_NODESC) continue;
    float ev = ssrc[src*H + hl] + sd;
    ev = (ev > 0.f) ? ev : NEG_SLOPE*ev;
    float nm = fmaxf(mval, ev);
    float sc = __expf(mval - nm);
    float wv = __expf(ev - nm);
    const u16x4 hvv = *(const u16x4*)(hh + (size_t)src*HID + f0);
    lval = lval*sc + wv;
    o0 = o0*sc + wv*b2f(hvv[0]);
    o1 = o1*sc + wv*b2f(hvv[1]);
    o2 = o2*sc + wv*b2f(hvv[2]);
    o3 = o3*sc + wv*b2f(hvv[3]);
    mval = nm;
  }
  float inv = (lval > 0.f) ? 1.f/lval : 0.f;
  r[0] = o0*inv; r[1] = o1*inv; r[2] = o2*inv; r[3] = o3*inv;
}

// Tier A: write gout (bf16)
__global__ __launch_bounds__(256) void k_attn_gout(const u16* __restrict__ hh,
    const float* __restrict__ ssrc, const float* __restrict__ sdst,
    const int* __restrict__ soff, const int* __restrict__ ssorted,
    u16* __restrict__ gout, int H){
  int wid = threadIdx.x >> 6, lane = threadIdx.x & 63;
  int n = blockIdx.x*4 + wid;
  if (n >= N_NODESC) return;
  float r[4];
  attn_node(n, lane, hh, ssrc, sdst, soff, ssorted, H, r);
  u16x4 o;
  #pragma unroll
  for (int j = 0; j < 4; ++j) o[j] = f2b(r[j]);
  *(u16x4*)(gout + (size_t)n*HID + lane*4) = o;
}

// Tier B pass 1: recompute attention, block-reduce BN stats
__global__ __launch_bounds__(256) void k_attn_stats(const u16* __restrict__ hh,
    const float* __restrict__ ssrc, const float* __restrict__ sdst,
    const int* __restrict__ soff, const int* __restrict__ ssorted,
    float* __restrict__ bnsum, float* __restrict__ bnsq, int H){
  __shared__ float lsum[4*HID];
  __shared__ float lsq[4*HID];
  int wid = threadIdx.x >> 6, lane = threadIdx.x & 63;
  int gw = blockIdx.x*4 + wid;
  int nw = gridDim.x*4;
  float s[4] = {0.f,0.f,0.f,0.f}, q[4] = {0.f,0.f,0.f,0.f};
  for (int n = gw; n < N_NODESC; n += nw){
    float r[4];
    attn_node(n, lane, hh, ssrc, sdst, soff, ssorted, H, r);
    #pragma unroll
    for (int j = 0; j < 4; ++j){ s[j] += r[j]; q[j] += r[j]*r[j]; }
  }
  int f0 = lane*4;
  #pragma unroll
  for (int j = 0; j < 4; ++j){ lsum[wid*HID + f0 + j] = s[j]; lsq[wid*HID + f0 + j] = q[j]; }
  __syncthreads();
  int c = threadIdx.x;
  float ts = lsum[c] + lsum[HID+c] + lsum[2*HID+c] + lsum[3*HID+c];
  float tq = lsq[c]  + lsq[HID+c]  + lsq[2*HID+c]  + lsq[3*HID+c];
  atomicAdd(&bnsum[c], ts);
  atomicAdd(&bnsq[c], tq);
}

// Tier B pass 2: recompute attention, fused BN+ReLU+residual into h
__global__ __launch_bounds__(256) void k_attn_apply(const u16* __restrict__ hh,
    const float* __restrict__ ssrc, const float* __restrict__ sdst,
    const int* __restrict__ soff, const int* __restrict__ ssorted,
    const float* __restrict__ scale, const float* __restrict__ shift,
    u16* __restrict__ h, int H){
  int wid = threadIdx.x >> 6, lane = threadIdx.x & 63;
  int n = blockIdx.x*4 + wid;
  if (n >= N_NODESC) return;
  float r[4];
  attn_node(n, lane, hh, ssrc, sdst, soff, ssorted, H, r);
  int f0 = lane*4;
  const f32x4 sc = *(const f32x4*)(scale + f0);
  const f32x4 sh = *(const f32x4*)(shift + f0);
  u16x4 hv = *(u16x4*)(h + (size_t)n*HID + f0);
  u16x4 o;
  #pragma unroll
  for (int j = 0; j < 4; ++j){
    float t = r[j]*sc[j] + sh[j];
    t = (t > 0.f) ? t : 0.f;
    o[j] = f2b(b2f(hv[j]) + t);
  }
  *(u16x4*)(h + (size_t)n*HID + f0) = o;
}

// ---------------- batchnorm (Tier A) ----------------
__global__ __launch_bounds__(256) void k_bn_stats(const u16* __restrict__ g,
    float* __restrict__ bnsum, float* __restrict__ bnsq){
  int c = threadIdx.x;
  float s = 0.f, q = 0.f;
  for (int r = blockIdx.x; r < N_NODESC; r += gridDim.x){
    float v = b2f(g[(size_t)r*HID + c]);
    s += v; q += v*v;
  }
  atomicAdd(&bnsum[c], s);
  atomicAdd(&bnsq[c], q);
}

__global__ __launch_bounds__(256) void k_bn_final(const float* __restrict__ bnsum,
    const float* __restrict__ bnsq, const void* __restrict__ gamma, const void* __restrict__ beta,
    float* __restrict__ scale, float* __restrict__ shift,
    const int* __restrict__ flagp, int loff){
  int f = *flagp;
  int c = threadIdx.x;
  float mu  = bnsum[c] * (1.f/N_NODESC);
  float var = bnsq[c]  * (1.f/N_NODESC) - mu*mu;
  if (!(var >= 0.f)) var = 0.f;   // also catches NaN
  float sc = ldp(gamma, (size_t)loff + c, f) * rsqrtf(var + BN_EPSC);
  scale[c] = sc;
  shift[c] = ldp(beta, (size_t)loff + c, f) - mu*sc;
}

// Tier A: h += relu(bn(gout))
__global__ __launch_bounds__(256) void k_bn_apply(const u16* __restrict__ g,
    const float* __restrict__ scale, const float* __restrict__ shift, u16* __restrict__ h){
  int idx = blockIdx.x*256 + threadIdx.x;           // N*HID/4 total
  int c4 = (idx & 63) * 4;
  const u16x4 gv = *(const u16x4*)(g + (size_t)idx*4);
  const f32x4 sc = *(const f32x4*)(scale + c4);
  const f32x4 sh = *(const f32x4*)(shift + c4);
  u16x4 hv = *(u16x4*)(h + (size_t)idx*4);
  u16x4 o;
  #pragma unroll
  for (int j = 0; j < 4; ++j){
    float t = b2f(gv[j])*sc[j] + sh[j];
    t = (t > 0.f) ? t : 0.f;
    o[j] = f2b(b2f(hv[j]) + t);
  }
  *(u16x4*)(h + (size_t)idx*4) = o;
}

// ---------------- mean pool per graph (batch sorted; also counts nodes/graph) ----------------
__global__ __launch_bounds__(256) void k_pool(const u16* __restrict__ h,
    const int* __restrict__ batch, float* __restrict__ gsum, int* __restrict__ gcnt){
  int c = threadIdx.x;
  int r0 = blockIdx.x * 256;
  int r1 = min(r0 + 256, N_NODESC);
  if (r0 >= N_NODESC) return;
  int cur = batch[r0];
  float acc = 0.f;
  int nacc = 0;
  for (int r = r0; r < r1; ++r){
    int b = batch[r];
    if ((unsigned)b >= NGRAPHS) continue;
    if (b != cur){
      if ((unsigned)cur < NGRAPHS){
        atomicAdd(&gsum[cur*HID + c], acc);
        if (c == 0) atomicAdd(&gcnt[cur], nacc);
      }
      acc = 0.f; nacc = 0; cur = b;
    }
    acc += b2f(h[(size_t)r*HID + c]);
    nacc++;
  }
  if ((unsigned)cur < NGRAPHS){
    atomicAdd(&gsum[cur*HID + c], acc);
    if (c == 0) atomicAdd(&gcnt[cur], nacc);
  }
}

// ---------------- token predictors: 32 graphs/block, mean-div fused ----------------
__global__ __launch_bounds__(256) void k_pred(const float* __restrict__ g,
    const int* __restrict__ gcnt,
    const void* __restrict__ tokW, const void* __restrict__ tokb, void* __restrict__ out,
    const int* __restrict__ flagp){
  __shared__ float glds[32*HID];   // 32 KB
  __shared__ float cinv[32];
  int f = *flagp;
  int tid = threadIdx.x;
  int vt = blockIdx.x, gg = blockIdx.y, s = blockIdx.z;
  int g0 = gg*32;
  if (tid < 32){
    int cc = gcnt[g0 + tid]; if (cc < 1) cc = 1;
    cinv[tid] = 1.f/(float)cc;
  }
  __syncthreads();
  #pragma unroll
  for (int j = 0; j < 32; ++j) glds[j*HID + tid] = g[(size_t)(g0+j)*HID + tid] * cinv[j];
  __syncthreads();
  int v = vt*256 + tid;
  if (v >= VOCABC) return;
  float acc[32];
  #pragma unroll
  for (int j = 0; j < 32; ++j) acc[j] = 0.f;
  size_t wbase = (size_t)s*HID*VOCABC + v;
  for (int k = 0; k < HID; ++k){
    float w = ldp(tokW, wbase + (size_t)k*VOCABC, f);
    #pragma unroll
    for (int j = 0; j < 32; ++j) acc[j] += glds[j*HID + k] * w;
  }
  float bb = ldp(tokb, (size_t)s*VOCABC + v, f);
  #pragma unroll
  for (int j = 0; j < 32; ++j){
    float val = acc[j] + bb;
    size_t oi = ((size_t)(s*NGRAPHS + g0 + j)*VOCABC) + v;
    if (f) ((float*)out)[oi] = val;
    else   ((u16*)out)[oi]   = f2b(val);
  }
}

// ---------------- host launcher ----------------
extern "C" void kernel_launch(void* const* d_in, const int* in_sizes, int n_in,
                              void* d_out, int out_size, void* d_ws, size_t ws_size,
                              hipStream_t stream) {
  const int* x          = (const int*)d_in[0];
  const int* node_depth = (const int*)d_in[1];
  const int* edge_index = (const int*)d_in[2];
  const int* batch      = (const int*)d_in[3];
  const void* type_emb  = d_in[4];
  const void* attr_emb  = d_in[5];
  const void* depth_emb = d_in[6];
  const void* Ws        = d_in[7];
  const void* att_src   = d_in[8];
  const void* att_dst   = d_in[9];
  // d_in[10] = gat_bias: dropped (constant per channel cancels inside BatchNorm)
  const void* bn_gamma  = d_in[11];
  const void* bn_beta   = d_in[12];
  const void* tok_W     = d_in[13];
  const void* tok_b     = d_in[14];

  // ---- workspace carve ----
  char* base = (char*)d_ws;
  size_t off = 0;
  auto carve = [&](size_t bytes) -> void* {
    void* p = base + off;
    off += (bytes + 255) & ~(size_t)255;
    return p;
  };
  u16*   h     = (u16*)carve((size_t)N_NODESC*HID*2);     // 51.2 MB
  u16*   hh    = (u16*)carve((size_t)N_NODESC*HID*2);     // 51.2 MB
  float* ssrc  = (float*)carve((size_t)N_NODESC*8*4);     // 3.2 MB
  float* sdst  = (float*)carve((size_t)N_NODESC*8*4);     // 3.2 MB
  int*   soff  = (int*)carve((size_t)(N_NODESC+1)*4);
  int*   cursor= (int*)carve((size_t)N_NODESC*4);
  int*   ssorted=(int*)carve((size_t)E_TOT*4);            // 2.0 MB
  int*   btot  = (int*)carve((size_t)NCHUNK*4);
  int*   boff  = (int*)carve((size_t)NCHUNK*4);
  u16*   WT    = (u16*)carve((size_t)NLAYERS*HID*HID*2);  // 0.5 MB
  float* bnsum = (float*)carve(HID*4);
  float* bnsq  = (float*)carve(HID*4);
  float* bnscale=(float*)carve(HID*4);
  float* bnshift=(float*)carve(HID*4);
  float* gsum  = (float*)carve((size_t)NGRAPHS*HID*4);    // 128 KB
  int*   gcnt  = (int*)carve((size_t)NGRAPHS*4);          // adjacent to gsum
  int*   dflag = (int*)carve(256);
  size_t common = off;
  u16*   gout  = (u16*)carve((size_t)N_NODESC*HID*2);     // +51.2 MB
  const bool useGout = (off <= ws_size);
  if (common > ws_size) return;  // cannot run at all

  const int EB  = (E_TOT + 255)/256;
  const int NB4 = (N_NODESC + 3)/4;      // wave-per-node kernels

  // dtype detection first
  k_detect<<<1, 64, 0, stream>>>(type_emb, dflag);

  // setup (k_embed also zeroes cursor)
  k_embed<<<N_NODESC, 256, 0, stream>>>(x, node_depth, type_emb, attr_emb, depth_emb, h, dflag, cursor);
  k_transW<<<dim3(256, NLAYERS), 256, 0, stream>>>(Ws, WT, dflag);
  k_hist<<<EB, 256, 0, stream>>>(edge_index, cursor);
  k_scan_part<<<NCHUNK, 256, 0, stream>>>(cursor, soff, btot);
  k_scan_tot<<<1, 256, 0, stream>>>(btot, boff, soff + N_NODESC);
  k_scan_add<<<NCHUNK, 256, 0, stream>>>(soff, boff, cursor);   // also zeroes cursor
  k_scatter<<<EB, 256, 0, stream>>>(edge_index, soff, cursor, ssorted);

  // layers
  for (int l = 0; l < NLAYERS; ++l){
    int H = (l == NLAYERS-1) ? 1 : 8;
    k_gemm<<<(N_NODESC + 63)/64, 256, 0, stream>>>(h, WT + (size_t)l*HID*HID, hh);
    k_scores<<<NB4, 256, 0, stream>>>(hh, att_src, att_dst, ssrc, sdst, H, dflag, l*HID, bnsum, bnsq);
    if (useGout){
      k_attn_gout<<<NB4, 256, 0, stream>>>(hh, ssrc, sdst, soff, ssorted, gout, H);
      k_bn_stats<<<256, 256, 0, stream>>>(gout, bnsum, bnsq);
      k_bn_final<<<1, 256, 0, stream>>>(bnsum, bnsq, bn_gamma, bn_beta, bnscale, bnshift, dflag, l*HID);
      k_bn_apply<<<(N_NODESC*HID/4)/256, 256, 0, stream>>>(gout, bnscale, bnshift, h);
    } else {
      k_attn_stats<<<2048, 256, 0, stream>>>(hh, ssrc, sdst, soff, ssorted, bnsum, bnsq, H);
      k_bn_final<<<1, 256, 0, stream>>>(bnsum, bnsq, bn_gamma, bn_beta, bnscale, bnshift, dflag, l*HID);
      k_attn_apply<<<NB4, 256, 0, stream>>>(hh, ssrc, sdst, soff, ssorted, bnscale, bnshift, h, H);
    }
  }

  // pool (gsum+gcnt are adjacent in ws -> single zero launch; counting fused into k_pool)
  k_zero<<<(NGRAPHS*HID + NGRAPHS + 255)/256, 256, 0, stream>>>((int*)gsum, NGRAPHS*HID + NGRAPHS);
  k_pool<<<NCHUNK, 256, 0, stream>>>(h, batch, gsum, gcnt);

  // predictors (mean-div fused via gcnt)
  k_pred<<<dim3((VOCABC+255)/256, NGRAPHS/32, SEQLEN), 256, 0, stream>>>(gsum, gcnt, tok_W, tok_b, d_out, dflag);
}

// Round 7
// 1580.618 us; speedup vs baseline: 1.6358x; 1.1985x over previous
//
#include <hip/hip_runtime.h>
#include <stdint.h>

typedef uint16_t u16;
typedef uint32_t u32;

#define N_NODESC 100000
#define N_EDGESC 400000
#define E_TOT    500000   // edges + self loops
#define HID      256
#define NLAYERS  4
#define NGRAPHS  128
#define SEQLEN   5
#define VOCABC   5002
#define MAXDEPTH 20
#define NEG_SLOPE 0.2f
#define BN_EPSC  1e-5f
#define NCHUNK   ((N_NODESC + 255)/256)   // 391
#define NROWT    (N_NODESC/16)            // 6250 row tiles, exact

typedef __attribute__((ext_vector_type(8))) short short8;
typedef __attribute__((ext_vector_type(4))) float f32x4;
typedef __attribute__((ext_vector_type(4))) unsigned short u16x4;

__device__ __forceinline__ float b2f(u16 u){
  union { u32 i; float f; } v; v.i = ((u32)u) << 16; return v.f;
}
__device__ __forceinline__ u16 f2b(float f){
  union { float f; u32 i; } v; v.f = f;
  u32 u = v.i;
  u += 0x7FFFu + ((u >> 16) & 1u);   // RNE
  return (u16)(u >> 16);
}
// dual-dtype parameter load: flag=1 -> f32, flag=0 -> bf16
__device__ __forceinline__ float ldp(const void* p, size_t i, int f){
  return f ? ((const float*)p)[i] : b2f(((const u16*)p)[i]);
}

// ---------------- dtype detector: sample type_emb both ways ----------------
__global__ __launch_bounds__(64) void k_detect(const void* temb, int* flag){
  int lane = threadIdx.x;
  const u32* w32 = (const u32*)temb;
  int sf = 0, sb = 0;
  for (int i = lane; i < 256; i += 64){
    u32 w = w32[i];
    union { u32 u; float f; } cf; cf.u = w;
    float af = fabsf(cf.f);
    if (cf.f == 0.0f || (af >= 1e-12f && af <= 4096.f)) sf++;
    float b0 = b2f((u16)(w & 0xFFFFu));
    float b1 = b2f((u16)(w >> 16));
    float a0 = fabsf(b0), a1 = fabsf(b1);
    if (b0 == 0.f || (a0 >= 1e-12f && a0 <= 4096.f)) sb++;
    if (b1 == 0.f || (a1 >= 1e-12f && a1 <= 4096.f)) sb++;
  }
  #pragma unroll
  for (int o = 1; o < 64; o <<= 1){ sf += __shfl_xor(sf, o); sb += __shfl_xor(sb, o); }
  if (lane == 0) *flag = (2*sf > sb) ? 1 : 0;
}

// ---------------- utility ----------------
__global__ __launch_bounds__(256) void k_zero(int* __restrict__ p, int n){
  int i = blockIdx.x*256 + threadIdx.x;
  if (i < n) p[i] = 0;
}

// ---------------- embedding (writes bf16 h; also zeroes cursor[n]) ----------------
__global__ __launch_bounds__(256) void k_embed(const int* __restrict__ x, const int* __restrict__ nd,
    const void* __restrict__ temb, const void* __restrict__ aemb, const void* __restrict__ demb,
    u16* __restrict__ h, const int* __restrict__ flagp, int* __restrict__ cursor){
  int f = *flagp;
  int n = blockIdx.x; int c = threadIdx.x;
  if (c == 0) cursor[n] = 0;   // histogram counter zero, ready before k_hist
  int t = x[n*2+0], a = x[n*2+1];
  if (t < 0) t = 0; if (t > 97) t = 97;
  if (a < 0) a = 0; if (a > 10029) a = 10029;
  int d = nd[n]; if (d > MAXDEPTH) d = MAXDEPTH; if (d < 0) d = 0;
  float v = ldp(temb, (size_t)t*HID+c, f) + ldp(aemb, (size_t)a*HID+c, f) + ldp(demb, (size_t)d*HID+c, f);
  h[(size_t)n*HID+c] = f2b(v);
}

// ---------------- edge sort by dst (counting sort) ----------------
__global__ __launch_bounds__(256) void k_hist(const int* __restrict__ ei, int* __restrict__ cnt){
  int e = blockIdx.x*256 + threadIdx.x;
  if (e >= E_TOT) return;
  int dst = (e < N_EDGESC) ? ei[N_EDGESC + e] : (e - N_EDGESC);
  if ((unsigned)dst >= N_NODESC) return;
  atomicAdd(&cnt[dst], 1);
}

// hierarchical scan, phase 1: per-256-chunk exclusive scan + chunk total
__global__ __launch_bounds__(256) void k_scan_part(const int* __restrict__ cnt,
    int* __restrict__ off, int* __restrict__ btot){
  __shared__ int lds[256];
  int b = blockIdx.x, tid = threadIdx.x;
  int i = b*256 + tid;
  int v = (i < N_NODESC) ? cnt[i] : 0;
  lds[tid] = v;
  __syncthreads();
  #pragma unroll
  for (int s = 1; s < 256; s <<= 1){
    int t = (tid >= s) ? lds[tid - s] : 0;
    __syncthreads();
    lds[tid] += t;
    __syncthreads();
  }
  if (i < N_NODESC) off[i] = lds[tid] - v;   // chunk-local exclusive
  if (tid == 255) btot[b] = lds[255];
}

// phase 2: scan the 391 chunk totals (1 block), write grand total to offN
__global__ __launch_bounds__(256) void k_scan_tot(const int* __restrict__ btot,
    int* __restrict__ boff, int* __restrict__ offN){
  __shared__ int lds[256];
  __shared__ int s_carry;
  int tid = threadIdx.x;
  if (tid == 0) s_carry = 0;
  __syncthreads();
  for (int base = 0; base < NCHUNK; base += 256){
    int i = base + tid;
    int v = (i < NCHUNK) ? btot[i] : 0;
    lds[tid] = v;
    __syncthreads();
    #pragma unroll
    for (int s = 1; s < 256; s <<= 1){
      int t = (tid >= s) ? lds[tid - s] : 0;
      __syncthreads();
      lds[tid] += t;
      __syncthreads();
    }
    if (i < NCHUNK) boff[i] = s_carry + lds[tid] - v;
    __syncthreads();
    if (tid == 255) s_carry += lds[255];
    __syncthreads();
  }
  if (tid == 0) *offN = s_carry;
}

// phase 3: add chunk offsets; also re-zero cursor for the scatter pass
__global__ __launch_bounds__(256) void k_scan_add(int* __restrict__ off,
    const int* __restrict__ boff, int* __restrict__ cursor){
  int b = blockIdx.x;
  int i = b*256 + threadIdx.x;
  if (i < N_NODESC){ off[i] += boff[b]; cursor[i] = 0; }
}

__global__ __launch_bounds__(256) void k_scatter(const int* __restrict__ ei,
    const int* __restrict__ soff, int* __restrict__ cursor, int* __restrict__ ssorted){
  int e = blockIdx.x*256 + threadIdx.x;
  if (e >= E_TOT) return;
  int src = (e < N_EDGESC) ? ei[e]            : (e - N_EDGESC);
  int dst = (e < N_EDGESC) ? ei[N_EDGESC + e] : (e - N_EDGESC);
  if ((unsigned)dst >= N_NODESC || (unsigned)src >= N_NODESC) return;
  int pos = soff[dst] + atomicAdd(&cursor[dst], 1);
  if ((unsigned)pos < E_TOT) ssorted[pos] = src;
}

// ---------------- W transpose -> bf16 WT, all layers ----------------
__global__ __launch_bounds__(256) void k_transW(const void* __restrict__ W, u16* __restrict__ WT,
    const int* __restrict__ flagp){
  int f = *flagp;
  int l = blockIdx.y, n2 = blockIdx.x, k = threadIdx.x;
  WT[(l*HID + n2)*HID + k] = f2b(ldp(W, (size_t)(l*HID + k)*HID + n2, f));
}

// ---------------- GEMM: hh = h @ W, MFMA 16x16x32 bf16, register-resident B ----------------
// Each wave owns 4 n-tiles (64 cols); B frags for all 8 k-steps preloaded in VGPRs (128 regs).
// Grid-stride over 16-row tiles: 8 A loads -> 32 MFMAs -> 16 stores (4:1 MFMA:VMEM).
// A frag: lane holds A[m=lane&15][k=quad*8+j]; B frag: B[k=quad*8+j][n=lane&15];
// D frag: col=lane&15, row=quad*4+reg.  N_NODESC = 6250*16 exactly -> no row guards.
__global__ __launch_bounds__(256) void k_gemm(const u16* __restrict__ h,
    const u16* __restrict__ WT, u16* __restrict__ hh){
  int wave = threadIdx.x >> 6, lane = threadIdx.x & 63;
  int m = lane & 15, quad = lane >> 4;

  short8 B[4][8];
  #pragma unroll
  for (int j = 0; j < 4; ++j){
    const u16* wp = WT + (size_t)((wave*4 + j)*16 + m)*HID + quad*8;
    #pragma unroll
    for (int ks = 0; ks < 8; ++ks)
      B[j][ks] = *(const short8*)(wp + ks*32);
  }

  for (int t = blockIdx.x; t < NROWT; t += gridDim.x){
    int r0 = t*16;
    const u16* ap = h + (size_t)(r0 + m)*HID + quad*8;
    short8 A[8];
    #pragma unroll
    for (int ks = 0; ks < 8; ++ks)
      A[ks] = *(const short8*)(ap + ks*32);

    f32x4 acc[4];
    #pragma unroll
    for (int j = 0; j < 4; ++j) acc[j] = (f32x4){0.f,0.f,0.f,0.f};
    #pragma unroll
    for (int ks = 0; ks < 8; ++ks){
      #pragma unroll
      for (int j = 0; j < 4; ++j)
        acc[j] = __builtin_amdgcn_mfma_f32_16x16x32_bf16(A[ks], B[j][ks], acc[j], 0, 0, 0);
    }

    #pragma unroll
    for (int j = 0; j < 4; ++j){
      int col = (wave*4 + j)*16 + m;
      #pragma unroll
      for (int r = 0; r < 4; ++r){
        int orow = r0 + quad*4 + r;
        hh[(size_t)orow*HID + col] = f2b(acc[j][r]);
      }
    }
  }
}

// ---------------- per-head scores (block 0 also zeroes BN accumulators) ----------------
__global__ __launch_bounds__(256) void k_scores(const u16* __restrict__ hh,
    const void* __restrict__ asrc, const void* __restrict__ adst,
    float* __restrict__ ssrc, float* __restrict__ sdst, int H,
    const int* __restrict__ flagp, int loff,
    float* __restrict__ bnsum, float* __restrict__ bnsq){
  if (blockIdx.x == 0){ bnsum[threadIdx.x] = 0.f; bnsq[threadIdx.x] = 0.f; }
  int f = *flagp;
  int wid = threadIdx.x >> 6, lane = threadIdx.x & 63;
  int n = blockIdx.x*4 + wid;
  if (n >= N_NODESC) return;
  int f0 = lane*4;
  const u16x4 hv = *(const u16x4*)(hh + (size_t)n*HID + f0);
  float ps = 0.f, pd = 0.f;
  #pragma unroll
  for (int j = 0; j < 4; ++j){
    float hvf = b2f(hv[j]);
    ps += hvf * ldp(asrc, (size_t)loff + f0 + j, f);
    pd += hvf * ldp(adst, (size_t)loff + f0 + j, f);
  }
  if (H == 8){
    #pragma unroll
    for (int o = 1; o < 8; o <<= 1){ ps += __shfl_xor(ps, o); pd += __shfl_xor(pd, o); }
    if ((lane & 7) == 0){ ssrc[n*8 + (lane>>3)] = ps; sdst[n*8 + (lane>>3)] = pd; }
  } else {
    #pragma unroll
    for (int o = 1; o < 64; o <<= 1){ ps += __shfl_xor(ps, o); pd += __shfl_xor(pd, o); }
    if (lane == 0){ ssrc[n] = ps; sdst[n] = pd; }
  }
}

// ---------------- attention core: online softmax aggregate for node n ----------------
// gat_bias dropped: per-channel constant cancels exactly inside BatchNorm.
__device__ __forceinline__ void attn_node(int n, int lane, const u16* __restrict__ hh,
    const float* __restrict__ ssrc, const float* __restrict__ sdst,
    const int* __restrict__ soff, const int* __restrict__ ssorted, int H, float r[4]){
  int f0 = lane*4;
  int hl = (H == 8) ? (lane >> 3) : 0;
  float sd = sdst[n*H + hl];
  int beg = soff[n], end = soff[n+1];
  if (beg < 0) beg = 0;
  if (end > E_TOT) end = E_TOT;
  float mval = -1e30f, lval = 0.f;
  float o0 = 0.f, o1 = 0.f, o2 = 0.f, o3 = 0.f;
  for (int i = beg; i < end; ++i){
    int src = ssorted[i];
    if ((unsigned)src >= N_NODESC) continue;
    float ev = ssrc[src*H + hl] + sd;
    ev = (ev > 0.f) ? ev : NEG_SLOPE*ev;
    float nm = fmaxf(mval, ev);
    float sc = __expf(mval - nm);
    float wv = __expf(ev - nm);
    const u16x4 hvv = *(const u16x4*)(hh + (size_t)src*HID + f0);
    lval = lval*sc + wv;
    o0 = o0*sc + wv*b2f(hvv[0]);
    o1 = o1*sc + wv*b2f(hvv[1]);
    o2 = o2*sc + wv*b2f(hvv[2]);
    o3 = o3*sc + wv*b2f(hvv[3]);
    mval = nm;
  }
  float inv = (lval > 0.f) ? 1.f/lval : 0.f;
  r[0] = o0*inv; r[1] = o1*inv; r[2] = o2*inv; r[3] = o3*inv;
}

// Tier A: write gout (bf16)
__global__ __launch_bounds__(256) void k_attn_gout(const u16* __restrict__ hh,
    const float* __restrict__ ssrc, const float* __restrict__ sdst,
    const int* __restrict__ soff, const int* __restrict__ ssorted,
    u16* __restrict__ gout, int H){
  int wid = threadIdx.x >> 6, lane = threadIdx.x & 63;
  int n = blockIdx.x*4 + wid;
  if (n >= N_NODESC) return;
  float r[4];
  attn_node(n, lane, hh, ssrc, sdst, soff, ssorted, H, r);
  u16x4 o;
  #pragma unroll
  for (int j = 0; j < 4; ++j) o[j] = f2b(r[j]);
  *(u16x4*)(gout + (size_t)n*HID + lane*4) = o;
}

// Tier B pass 1: recompute attention, block-reduce BN stats
__global__ __launch_bounds__(256) void k_attn_stats(const u16* __restrict__ hh,
    const float* __restrict__ ssrc, const float* __restrict__ sdst,
    const int* __restrict__ soff, const int* __restrict__ ssorted,
    float* __restrict__ bnsum, float* __restrict__ bnsq, int H){
  __shared__ float lsum[4*HID];
  __shared__ float lsq[4*HID];
  int wid = threadIdx.x >> 6, lane = threadIdx.x & 63;
  int gw = blockIdx.x*4 + wid;
  int nw = gridDim.x*4;
  float s[4] = {0.f,0.f,0.f,0.f}, q[4] = {0.f,0.f,0.f,0.f};
  for (int n = gw; n < N_NODESC; n += nw){
    float r[4];
    attn_node(n, lane, hh, ssrc, sdst, soff, ssorted, H, r);
    #pragma unroll
    for (int j = 0; j < 4; ++j){ s[j] += r[j]; q[j] += r[j]*r[j]; }
  }
  int f0 = lane*4;
  #pragma unroll
  for (int j = 0; j < 4; ++j){ lsum[wid*HID + f0 + j] = s[j]; lsq[wid*HID + f0 + j] = q[j]; }
  __syncthreads();
  int c = threadIdx.x;
  float ts = lsum[c] + lsum[HID+c] + lsum[2*HID+c] + lsum[3*HID+c];
  float tq = lsq[c]  + lsq[HID+c]  + lsq[2*HID+c]  + lsq[3*HID+c];
  atomicAdd(&bnsum[c], ts);
  atomicAdd(&bnsq[c], tq);
}

// Tier B pass 2: recompute attention, fused BN+ReLU+residual into h
__global__ __launch_bounds__(256) void k_attn_apply(const u16* __restrict__ hh,
    const float* __restrict__ ssrc, const float* __restrict__ sdst,
    const int* __restrict__ soff, const int* __restrict__ ssorted,
    const float* __restrict__ scale, const float* __restrict__ shift,
    u16* __restrict__ h, int H){
  int wid = threadIdx.x >> 6, lane = threadIdx.x & 63;
  int n = blockIdx.x*4 + wid;
  if (n >= N_NODESC) return;
  float r[4];
  attn_node(n, lane, hh, ssrc, sdst, soff, ssorted, H, r);
  int f0 = lane*4;
  const f32x4 sc = *(const f32x4*)(scale + f0);
  const f32x4 sh = *(const f32x4*)(shift + f0);
  u16x4 hv = *(u16x4*)(h + (size_t)n*HID + f0);
  u16x4 o;
  #pragma unroll
  for (int j = 0; j < 4; ++j){
    float t = r[j]*sc[j] + sh[j];
    t = (t > 0.f) ? t : 0.f;
    o[j] = f2b(b2f(hv[j]) + t);
  }
  *(u16x4*)(h + (size_t)n*HID + f0) = o;
}

// ---------------- batchnorm (Tier A) ----------------
__global__ __launch_bounds__(256) void k_bn_stats(const u16* __restrict__ g,
    float* __restrict__ bnsum, float* __restrict__ bnsq){
  int c = threadIdx.x;
  float s = 0.f, q = 0.f;
  for (int r = blockIdx.x; r < N_NODESC; r += gridDim.x){
    float v = b2f(g[(size_t)r*HID + c]);
    s += v; q += v*v;
  }
  atomicAdd(&bnsum[c], s);
  atomicAdd(&bnsq[c], q);
}

__global__ __launch_bounds__(256) void k_bn_final(const float* __restrict__ bnsum,
    const float* __restrict__ bnsq, const void* __restrict__ gamma, const void* __restrict__ beta,
    float* __restrict__ scale, float* __restrict__ shift,
    const int* __restrict__ flagp, int loff){
  int f = *flagp;
  int c = threadIdx.x;
  float mu  = bnsum[c] * (1.f/N_NODESC);
  float var = bnsq[c]  * (1.f/N_NODESC) - mu*mu;
  if (!(var >= 0.f)) var = 0.f;   // also catches NaN
  float sc = ldp(gamma, (size_t)loff + c, f) * rsqrtf(var + BN_EPSC);
  scale[c] = sc;
  shift[c] = ldp(beta, (size_t)loff + c, f) - mu*sc;
}

// Tier A: h += relu(bn(gout))
__global__ __launch_bounds__(256) void k_bn_apply(const u16* __restrict__ g,
    const float* __restrict__ scale, const float* __restrict__ shift, u16* __restrict__ h){
  int idx = blockIdx.x*256 + threadIdx.x;           // N*HID/4 total
  int c4 = (idx & 63) * 4;
  const u16x4 gv = *(const u16x4*)(g + (size_t)idx*4);
  const f32x4 sc = *(const f32x4*)(scale + c4);
  const f32x4 sh = *(const f32x4*)(shift + c4);
  u16x4 hv = *(u16x4*)(h + (size_t)idx*4);
  u16x4 o;
  #pragma unroll
  for (int j = 0; j < 4; ++j){
    float t = b2f(gv[j])*sc[j] + sh[j];
    t = (t > 0.f) ? t : 0.f;
    o[j] = f2b(b2f(hv[j]) + t);
  }
  *(u16x4*)(h + (size_t)idx*4) = o;
}

// ---------------- mean pool per graph (batch sorted; also counts nodes/graph) ----------------
__global__ __launch_bounds__(256) void k_pool(const u16* __restrict__ h,
    const int* __restrict__ batch, float* __restrict__ gsum, int* __restrict__ gcnt){
  int c = threadIdx.x;
  int r0 = blockIdx.x * 256;
  int r1 = min(r0 + 256, N_NODESC);
  if (r0 >= N_NODESC) return;
  int cur = batch[r0];
  float acc = 0.f;
  int nacc = 0;
  for (int r = r0; r < r1; ++r){
    int b = batch[r];
    if ((unsigned)b >= NGRAPHS) continue;
    if (b != cur){
      if ((unsigned)cur < NGRAPHS){
        atomicAdd(&gsum[cur*HID + c], acc);
        if (c == 0) atomicAdd(&gcnt[cur], nacc);
      }
      acc = 0.f; nacc = 0; cur = b;
    }
    acc += b2f(h[(size_t)r*HID + c]);
    nacc++;
  }
  if ((unsigned)cur < NGRAPHS){
    atomicAdd(&gsum[cur*HID + c], acc);
    if (c == 0) atomicAdd(&gcnt[cur], nacc);
  }
}

// ---------------- token predictors: 32 graphs/block, mean-div fused ----------------
__global__ __launch_bounds__(256) void k_pred(const float* __restrict__ g,
    const int* __restrict__ gcnt,
    const void* __restrict__ tokW, const void* __restrict__ tokb, void* __restrict__ out,
    const int* __restrict__ flagp){
  __shared__ float glds[32*HID];   // 32 KB
  __shared__ float cinv[32];
  int f = *flagp;
  int tid = threadIdx.x;
  int vt = blockIdx.x, gg = blockIdx.y, s = blockIdx.z;
  int g0 = gg*32;
  if (tid < 32){
    int cc = gcnt[g0 + tid]; if (cc < 1) cc = 1;
    cinv[tid] = 1.f/(float)cc;
  }
  __syncthreads();
  #pragma unroll
  for (int j = 0; j < 32; ++j) glds[j*HID + tid] = g[(size_t)(g0+j)*HID + tid] * cinv[j];
  __syncthreads();
  int v = vt*256 + tid;
  if (v >= VOCABC) return;
  float acc[32];
  #pragma unroll
  for (int j = 0; j < 32; ++j) acc[j] = 0.f;
  size_t wbase = (size_t)s*HID*VOCABC + v;
  for (int k = 0; k < HID; ++k){
    float w = ldp(tokW, wbase + (size_t)k*VOCABC, f);
    #pragma unroll
    for (int j = 0; j < 32; ++j) acc[j] += glds[j*HID + k] * w;
  }
  float bb = ldp(tokb, (size_t)s*VOCABC + v, f);
  #pragma unroll
  for (int j = 0; j < 32; ++j){
    float val = acc[j] + bb;
    size_t oi = ((size_t)(s*NGRAPHS + g0 + j)*VOCABC) + v;
    if (f) ((float*)out)[oi] = val;
    else   ((u16*)out)[oi]   = f2b(val);
  }
}

// ---------------- host launcher ----------------
extern "C" void kernel_launch(void* const* d_in, const int* in_sizes, int n_in,
                              void* d_out, int out_size, void* d_ws, size_t ws_size,
                              hipStream_t stream) {
  const int* x          = (const int*)d_in[0];
  const int* node_depth = (const int*)d_in[1];
  const int* edge_index = (const int*)d_in[2];
  const int* batch      = (const int*)d_in[3];
  const void* type_emb  = d_in[4];
  const void* attr_emb  = d_in[5];
  const void* depth_emb = d_in[6];
  const void* Ws        = d_in[7];
  const void* att_src   = d_in[8];
  const void* att_dst   = d_in[9];
  // d_in[10] = gat_bias: dropped (constant per channel cancels inside BatchNorm)
  const void* bn_gamma  = d_in[11];
  const void* bn_beta   = d_in[12];
  const void* tok_W     = d_in[13];
  const void* tok_b     = d_in[14];

  // ---- workspace carve ----
  char* base = (char*)d_ws;
  size_t off = 0;
  auto carve = [&](size_t bytes) -> void* {
    void* p = base + off;
    off += (bytes + 255) & ~(size_t)255;
    return p;
  };
  u16*   h     = (u16*)carve((size_t)N_NODESC*HID*2);     // 51.2 MB
  u16*   hh    = (u16*)carve((size_t)N_NODESC*HID*2);     // 51.2 MB
  float* ssrc  = (float*)carve((size_t)N_NODESC*8*4);     // 3.2 MB
  float* sdst  = (float*)carve((size_t)N_NODESC*8*4);     // 3.2 MB
  int*   soff  = (int*)carve((size_t)(N_NODESC+1)*4);
  int*   cursor= (int*)carve((size_t)N_NODESC*4);
  int*   ssorted=(int*)carve((size_t)E_TOT*4);            // 2.0 MB
  int*   btot  = (int*)carve((size_t)NCHUNK*4);
  int*   boff  = (int*)carve((size_t)NCHUNK*4);
  u16*   WT    = (u16*)carve((size_t)NLAYERS*HID*HID*2);  // 0.5 MB
  float* bnsum = (float*)carve(HID*4);
  float* bnsq  = (float*)carve(HID*4);
  float* bnscale=(float*)carve(HID*4);
  float* bnshift=(float*)carve(HID*4);
  float* gsum  = (float*)carve((size_t)NGRAPHS*HID*4);    // 128 KB
  int*   gcnt  = (int*)carve((size_t)NGRAPHS*4);          // adjacent to gsum
  int*   dflag = (int*)carve(256);
  size_t common = off;
  u16*   gout  = (u16*)carve((size_t)N_NODESC*HID*2);     // +51.2 MB
  const bool useGout = (off <= ws_size);
  if (common > ws_size) return;  // cannot run at all

  const int EB  = (E_TOT + 255)/256;
  const int NB4 = (N_NODESC + 3)/4;      // wave-per-node kernels

  // dtype detection first
  k_detect<<<1, 64, 0, stream>>>(type_emb, dflag);

  // setup (k_embed also zeroes cursor)
  k_embed<<<N_NODESC, 256, 0, stream>>>(x, node_depth, type_emb, attr_emb, depth_emb, h, dflag, cursor);
  k_transW<<<dim3(256, NLAYERS), 256, 0, stream>>>(Ws, WT, dflag);
  k_hist<<<EB, 256, 0, stream>>>(edge_index, cursor);
  k_scan_part<<<NCHUNK, 256, 0, stream>>>(cursor, soff, btot);
  k_scan_tot<<<1, 256, 0, stream>>>(btot, boff, soff + N_NODESC);
  k_scan_add<<<NCHUNK, 256, 0, stream>>>(soff, boff, cursor);   // also zeroes cursor
  k_scatter<<<EB, 256, 0, stream>>>(edge_index, soff, cursor, ssorted);

  // layers
  for (int l = 0; l < NLAYERS; ++l){
    int H = (l == NLAYERS-1) ? 1 : 8;
    k_gemm<<<1024, 256, 0, stream>>>(h, WT + (size_t)l*HID*HID, hh);
    k_scores<<<NB4, 256, 0, stream>>>(hh, att_src, att_dst, ssrc, sdst, H, dflag, l*HID, bnsum, bnsq);
    if (useGout){
      k_attn_gout<<<NB4, 256, 0, stream>>>(hh, ssrc, sdst, soff, ssorted, gout, H);
      k_bn_stats<<<256, 256, 0, stream>>>(gout, bnsum, bnsq);
      k_bn_final<<<1, 256, 0, stream>>>(bnsum, bnsq, bn_gamma, bn_beta, bnscale, bnshift, dflag, l*HID);
      k_bn_apply<<<(N_NODESC*HID/4)/256, 256, 0, stream>>>(gout, bnscale, bnshift, h);
    } else {
      k_attn_stats<<<2048, 256, 0, stream>>>(hh, ssrc, sdst, soff, ssorted, bnsum, bnsq, H);
      k_bn_final<<<1, 256, 0, stream>>>(bnsum, bnsq, bn_gamma, bn_beta, bnscale, bnshift, dflag, l*HID);
      k_attn_apply<<<NB4, 256, 0, stream>>>(hh, ssrc, sdst, soff, ssorted, bnscale, bnshift, h, H);
    }
  }

  // pool (gsum+gcnt adjacent -> single zero launch; counting fused into k_pool)
  k_zero<<<(NGRAPHS*HID + NGRAPHS + 255)/256, 256, 0, stream>>>((int*)gsum, NGRAPHS*HID + NGRAPHS);
  k_pool<<<NCHUNK, 256, 0, stream>>>(h, batch, gsum, gcnt);

  // predictors (mean-div fused via gcnt)
  k_pred<<<dim3((VOCABC+255)/256, NGRAPHS/32, SEQLEN), 256, 0, stream>>>(gsum, gcnt, tok_W, tok_b, d_out, dflag);
}

// Round 8
// 1246.678 us; speedup vs baseline: 2.0740x; 1.2679x over previous
//
#include <hip/hip_runtime.h>
#include <stdint.h>

typedef uint16_t u16;
typedef uint32_t u32;

#define N_NODESC 100000
#define N_EDGESC 400000
#define E_TOT    500000   // edges + self loops
#define HID      256
#define NLAYERS  4
#define NGRAPHS  128
#define SEQLEN   5
#define VOCABC   5002
#define MAXDEPTH 20
#define NEG_SLOPE 0.2f
#define BN_EPSC  1e-5f
#define NCHUNK   ((N_NODESC + 255)/256)   // 391
#define NROWT    (N_NODESC/16)            // 6250 row tiles, exact
#define NPART    64                       // BN partial rows (each 512 floats: 256 sum + 256 sq)

typedef __attribute__((ext_vector_type(8))) short short8;
typedef __attribute__((ext_vector_type(4))) float f32x4;
typedef __attribute__((ext_vector_type(4))) unsigned short u16x4;

__device__ __forceinline__ float b2f(u16 u){
  union { u32 i; float f; } v; v.i = ((u32)u) << 16; return v.f;
}
__device__ __forceinline__ u16 f2b(float f){
  union { float f; u32 i; } v; v.f = f;
  u32 u = v.i;
  u += 0x7FFFu + ((u >> 16) & 1u);   // RNE
  return (u16)(u >> 16);
}
// dual-dtype parameter load: flag=1 -> f32, flag=0 -> bf16
__device__ __forceinline__ float ldp(const void* p, size_t i, int f){
  return f ? ((const float*)p)[i] : b2f(((const u16*)p)[i]);
}

// ---------------- dtype detector: sample type_emb both ways ----------------
__global__ __launch_bounds__(64) void k_detect(const void* temb, int* flag){
  int lane = threadIdx.x;
  const u32* w32 = (const u32*)temb;
  int sf = 0, sb = 0;
  for (int i = lane; i < 256; i += 64){
    u32 w = w32[i];
    union { u32 u; float f; } cf; cf.u = w;
    float af = fabsf(cf.f);
    if (cf.f == 0.0f || (af >= 1e-12f && af <= 4096.f)) sf++;
    float b0 = b2f((u16)(w & 0xFFFFu));
    float b1 = b2f((u16)(w >> 16));
    float a0 = fabsf(b0), a1 = fabsf(b1);
    if (b0 == 0.f || (a0 >= 1e-12f && a0 <= 4096.f)) sb++;
    if (b1 == 0.f || (a1 >= 1e-12f && a1 <= 4096.f)) sb++;
  }
  #pragma unroll
  for (int o = 1; o < 64; o <<= 1){ sf += __shfl_xor(sf, o); sb += __shfl_xor(sb, o); }
  if (lane == 0) *flag = (2*sf > sb) ? 1 : 0;
}

// ---------------- utility ----------------
__global__ __launch_bounds__(256) void k_zero(int* __restrict__ p, int n){
  int i = blockIdx.x*256 + threadIdx.x;
  if (i < n) p[i] = 0;
}

// ---------------- embedding (writes bf16 h; also zeroes cursor[n]) ----------------
__global__ __launch_bounds__(256) void k_embed(const int* __restrict__ x, const int* __restrict__ nd,
    const void* __restrict__ temb, const void* __restrict__ aemb, const void* __restrict__ demb,
    u16* __restrict__ h, const int* __restrict__ flagp, int* __restrict__ cursor){
  int f = *flagp;
  int n = blockIdx.x; int c = threadIdx.x;
  if (c == 0) cursor[n] = 0;   // histogram counter zero, ready before k_hist
  int t = x[n*2+0], a = x[n*2+1];
  if (t < 0) t = 0; if (t > 97) t = 97;
  if (a < 0) a = 0; if (a > 10029) a = 10029;
  int d = nd[n]; if (d > MAXDEPTH) d = MAXDEPTH; if (d < 0) d = 0;
  float v = ldp(temb, (size_t)t*HID+c, f) + ldp(aemb, (size_t)a*HID+c, f) + ldp(demb, (size_t)d*HID+c, f);
  h[(size_t)n*HID+c] = f2b(v);
}

// ---------------- edge sort by dst (counting sort) ----------------
__global__ __launch_bounds__(256) void k_hist(const int* __restrict__ ei, int* __restrict__ cnt){
  int e = blockIdx.x*256 + threadIdx.x;
  if (e >= E_TOT) return;
  int dst = (e < N_EDGESC) ? ei[N_EDGESC + e] : (e - N_EDGESC);
  if ((unsigned)dst >= N_NODESC) return;
  atomicAdd(&cnt[dst], 1);
}

// hierarchical scan, phase 1: per-256-chunk exclusive scan + chunk total
__global__ __launch_bounds__(256) void k_scan_part(const int* __restrict__ cnt,
    int* __restrict__ off, int* __restrict__ btot){
  __shared__ int lds[256];
  int b = blockIdx.x, tid = threadIdx.x;
  int i = b*256 + tid;
  int v = (i < N_NODESC) ? cnt[i] : 0;
  lds[tid] = v;
  __syncthreads();
  #pragma unroll
  for (int s = 1; s < 256; s <<= 1){
    int t = (tid >= s) ? lds[tid - s] : 0;
    __syncthreads();
    lds[tid] += t;
    __syncthreads();
  }
  if (i < N_NODESC) off[i] = lds[tid] - v;   // chunk-local exclusive
  if (tid == 255) btot[b] = lds[255];
}

// phase 2: scan the 391 chunk totals (1 block), write grand total to offN
__global__ __launch_bounds__(256) void k_scan_tot(const int* __restrict__ btot,
    int* __restrict__ boff, int* __restrict__ offN){
  __shared__ int lds[256];
  __shared__ int s_carry;
  int tid = threadIdx.x;
  if (tid == 0) s_carry = 0;
  __syncthreads();
  for (int base = 0; base < NCHUNK; base += 256){
    int i = base + tid;
    int v = (i < NCHUNK) ? btot[i] : 0;
    lds[tid] = v;
    __syncthreads();
    #pragma unroll
    for (int s = 1; s < 256; s <<= 1){
      int t = (tid >= s) ? lds[tid - s] : 0;
      __syncthreads();
      lds[tid] += t;
      __syncthreads();
    }
    if (i < NCHUNK) boff[i] = s_carry + lds[tid] - v;
    __syncthreads();
    if (tid == 255) s_carry += lds[255];
    __syncthreads();
  }
  if (tid == 0) *offN = s_carry;
}

// phase 3: add chunk offsets; also re-zero cursor for the scatter pass
__global__ __launch_bounds__(256) void k_scan_add(int* __restrict__ off,
    const int* __restrict__ boff, int* __restrict__ cursor){
  int b = blockIdx.x;
  int i = b*256 + threadIdx.x;
  if (i < N_NODESC){ off[i] += boff[b]; cursor[i] = 0; }
}

__global__ __launch_bounds__(256) void k_scatter(const int* __restrict__ ei,
    const int* __restrict__ soff, int* __restrict__ cursor, int* __restrict__ ssorted){
  int e = blockIdx.x*256 + threadIdx.x;
  if (e >= E_TOT) return;
  int src = (e < N_EDGESC) ? ei[e]            : (e - N_EDGESC);
  int dst = (e < N_EDGESC) ? ei[N_EDGESC + e] : (e - N_EDGESC);
  if ((unsigned)dst >= N_NODESC || (unsigned)src >= N_NODESC) return;
  int pos = soff[dst] + atomicAdd(&cursor[dst], 1);
  if ((unsigned)pos < E_TOT) ssorted[pos] = src;
}

// ---------------- W transpose -> bf16 WT, all layers ----------------
__global__ __launch_bounds__(256) void k_transW(const void* __restrict__ W, u16* __restrict__ WT,
    const int* __restrict__ flagp){
  int f = *flagp;
  int l = blockIdx.y, n2 = blockIdx.x, k = threadIdx.x;
  WT[(l*HID + n2)*HID + k] = f2b(ldp(W, (size_t)(l*HID + k)*HID + n2, f));
}

// ---------------- GEMM: hh = h @ W, MFMA 16x16x32 bf16, register-resident B ----------------
__global__ __launch_bounds__(256) void k_gemm(const u16* __restrict__ h,
    const u16* __restrict__ WT, u16* __restrict__ hh){
  int wave = threadIdx.x >> 6, lane = threadIdx.x & 63;
  int m = lane & 15, quad = lane >> 4;

  short8 B[4][8];
  #pragma unroll
  for (int j = 0; j < 4; ++j){
    const u16* wp = WT + (size_t)((wave*4 + j)*16 + m)*HID + quad*8;
    #pragma unroll
    for (int ks = 0; ks < 8; ++ks)
      B[j][ks] = *(const short8*)(wp + ks*32);
  }

  for (int t = blockIdx.x; t < NROWT; t += gridDim.x){
    int r0 = t*16;
    const u16* ap = h + (size_t)(r0 + m)*HID + quad*8;
    short8 A[8];
    #pragma unroll
    for (int ks = 0; ks < 8; ++ks)
      A[ks] = *(const short8*)(ap + ks*32);

    f32x4 acc[4];
    #pragma unroll
    for (int j = 0; j < 4; ++j) acc[j] = (f32x4){0.f,0.f,0.f,0.f};
    #pragma unroll
    for (int ks = 0; ks < 8; ++ks){
      #pragma unroll
      for (int j = 0; j < 4; ++j)
        acc[j] = __builtin_amdgcn_mfma_f32_16x16x32_bf16(A[ks], B[j][ks], acc[j], 0, 0, 0);
    }

    #pragma unroll
    for (int j = 0; j < 4; ++j){
      int col = (wave*4 + j)*16 + m;
      #pragma unroll
      for (int r = 0; r < 4; ++r){
        int orow = r0 + quad*4 + r;
        hh[(size_t)orow*HID + col] = f2b(acc[j][r]);
      }
    }
  }
}

// ---------------- per-head scores (blocks 0..127 also zero BN partials) ----------------
__global__ __launch_bounds__(256) void k_scores(const u16* __restrict__ hh,
    const void* __restrict__ asrc, const void* __restrict__ adst,
    float* __restrict__ ssrc, float* __restrict__ sdst, int H,
    const int* __restrict__ flagp, int loff,
    float* __restrict__ bnpart){
  if (blockIdx.x < NPART*2) bnpart[blockIdx.x*256 + threadIdx.x] = 0.f;  // 64*512 floats
  int f = *flagp;
  int wid = threadIdx.x >> 6, lane = threadIdx.x & 63;
  int n = blockIdx.x*4 + wid;
  if (n >= N_NODESC) return;
  int f0 = lane*4;
  const u16x4 hv = *(const u16x4*)(hh + (size_t)n*HID + f0);
  float ps = 0.f, pd = 0.f;
  #pragma unroll
  for (int j = 0; j < 4; ++j){
    float hvf = b2f(hv[j]);
    ps += hvf * ldp(asrc, (size_t)loff + f0 + j, f);
    pd += hvf * ldp(adst, (size_t)loff + f0 + j, f);
  }
  if (H == 8){
    #pragma unroll
    for (int o = 1; o < 8; o <<= 1){ ps += __shfl_xor(ps, o); pd += __shfl_xor(pd, o); }
    if ((lane & 7) == 0){ ssrc[n*8 + (lane>>3)] = ps; sdst[n*8 + (lane>>3)] = pd; }
  } else {
    #pragma unroll
    for (int o = 1; o < 64; o <<= 1){ ps += __shfl_xor(ps, o); pd += __shfl_xor(pd, o); }
    if (lane == 0){ ssrc[n] = ps; sdst[n] = pd; }
  }
}

// ---------------- attention core: online softmax aggregate for node n ----------------
// gat_bias dropped: per-channel constant cancels exactly inside BatchNorm.
__device__ __forceinline__ void attn_node(int n, int lane, const u16* __restrict__ hh,
    const float* __restrict__ ssrc, const float* __restrict__ sdst,
    const int* __restrict__ soff, const int* __restrict__ ssorted, int H, float r[4]){
  int f0 = lane*4;
  int hl = (H == 8) ? (lane >> 3) : 0;
  float sd = sdst[n*H + hl];
  int beg = soff[n], end = soff[n+1];
  if (beg < 0) beg = 0;
  if (end > E_TOT) end = E_TOT;
  float mval = -1e30f, lval = 0.f;
  float o0 = 0.f, o1 = 0.f, o2 = 0.f, o3 = 0.f;
  for (int i = beg; i < end; ++i){
    int src = ssorted[i];
    if ((unsigned)src >= N_NODESC) continue;
    float ev = ssrc[src*H + hl] + sd;
    ev = (ev > 0.f) ? ev : NEG_SLOPE*ev;
    float nm = fmaxf(mval, ev);
    float sc = __expf(mval - nm);
    float wv = __expf(ev - nm);
    const u16x4 hvv = *(const u16x4*)(hh + (size_t)src*HID + f0);
    lval = lval*sc + wv;
    o0 = o0*sc + wv*b2f(hvv[0]);
    o1 = o1*sc + wv*b2f(hvv[1]);
    o2 = o2*sc + wv*b2f(hvv[2]);
    o3 = o3*sc + wv*b2f(hvv[3]);
    mval = nm;
  }
  float inv = (lval > 0.f) ? 1.f/lval : 0.f;
  r[0] = o0*inv; r[1] = o1*inv; r[2] = o2*inv; r[3] = o3*inv;
}

// Tier A: write gout (bf16) + fused BN partial stats (lane owns channels lane*4..+3)
__global__ __launch_bounds__(256) void k_attn_gout(const u16* __restrict__ hh,
    const float* __restrict__ ssrc, const float* __restrict__ sdst,
    const int* __restrict__ soff, const int* __restrict__ ssorted,
    u16* __restrict__ gout, int H, float* __restrict__ bnpart){
  __shared__ float lsum[4*HID];
  __shared__ float lsq[4*HID];
  int wid = threadIdx.x >> 6, lane = threadIdx.x & 63;
  int n = blockIdx.x*4 + wid;
  int f0 = lane*4;
  float r[4] = {0.f,0.f,0.f,0.f};
  if (n < N_NODESC){
    attn_node(n, lane, hh, ssrc, sdst, soff, ssorted, H, r);
    u16x4 o;
    #pragma unroll
    for (int j = 0; j < 4; ++j) o[j] = f2b(r[j]);
    *(u16x4*)(gout + (size_t)n*HID + f0) = o;
  }
  #pragma unroll
  for (int j = 0; j < 4; ++j){
    lsum[wid*HID + f0 + j] = r[j];
    lsq [wid*HID + f0 + j] = r[j]*r[j];
  }
  __syncthreads();
  int c = threadIdx.x;
  float ts = lsum[c] + lsum[HID+c] + lsum[2*HID+c] + lsum[3*HID+c];
  float tq = lsq[c]  + lsq[HID+c]  + lsq[2*HID+c]  + lsq[3*HID+c];
  float* prow = bnpart + (size_t)(blockIdx.x & (NPART-1))*512;
  atomicAdd(&prow[c], ts);
  atomicAdd(&prow[HID + c], tq);
}

// Tier B pass 1: recompute attention, block-reduce BN stats into partials
__global__ __launch_bounds__(256) void k_attn_stats(const u16* __restrict__ hh,
    const float* __restrict__ ssrc, const float* __restrict__ sdst,
    const int* __restrict__ soff, const int* __restrict__ ssorted,
    float* __restrict__ bnpart, int H){
  __shared__ float lsum[4*HID];
  __shared__ float lsq[4*HID];
  int wid = threadIdx.x >> 6, lane = threadIdx.x & 63;
  int gw = blockIdx.x*4 + wid;
  int nw = gridDim.x*4;
  float s[4] = {0.f,0.f,0.f,0.f}, q[4] = {0.f,0.f,0.f,0.f};
  for (int n = gw; n < N_NODESC; n += nw){
    float r[4];
    attn_node(n, lane, hh, ssrc, sdst, soff, ssorted, H, r);
    #pragma unroll
    for (int j = 0; j < 4; ++j){ s[j] += r[j]; q[j] += r[j]*r[j]; }
  }
  int f0 = lane*4;
  #pragma unroll
  for (int j = 0; j < 4; ++j){ lsum[wid*HID + f0 + j] = s[j]; lsq[wid*HID + f0 + j] = q[j]; }
  __syncthreads();
  int c = threadIdx.x;
  float ts = lsum[c] + lsum[HID+c] + lsum[2*HID+c] + lsum[3*HID+c];
  float tq = lsq[c]  + lsq[HID+c]  + lsq[2*HID+c]  + lsq[3*HID+c];
  float* prow = bnpart + (size_t)(blockIdx.x & (NPART-1))*512;
  atomicAdd(&prow[c], ts);
  atomicAdd(&prow[HID + c], tq);
}

// Tier B pass 2: recompute attention, fused BN+ReLU+residual into h
__global__ __launch_bounds__(256) void k_attn_apply(const u16* __restrict__ hh,
    const float* __restrict__ ssrc, const float* __restrict__ sdst,
    const int* __restrict__ soff, const int* __restrict__ ssorted,
    const float* __restrict__ scale, const float* __restrict__ shift,
    u16* __restrict__ h, int H){
  int wid = threadIdx.x >> 6, lane = threadIdx.x & 63;
  int n = blockIdx.x*4 + wid;
  if (n >= N_NODESC) return;
  float r[4];
  attn_node(n, lane, hh, ssrc, sdst, soff, ssorted, H, r);
  int f0 = lane*4;
  const f32x4 sc = *(const f32x4*)(scale + f0);
  const f32x4 sh = *(const f32x4*)(shift + f0);
  u16x4 hv = *(u16x4*)(h + (size_t)n*HID + f0);
  u16x4 o;
  #pragma unroll
  for (int j = 0; j < 4; ++j){
    float t = r[j]*sc[j] + sh[j];
    t = (t > 0.f) ? t : 0.f;
    o[j] = f2b(b2f(hv[j]) + t);
  }
  *(u16x4*)(h + (size_t)n*HID + f0) = o;
}

// ---------------- BN finalize: reduce 64 partial rows -> scale/shift ----------------
__global__ __launch_bounds__(256) void k_bn_final(const float* __restrict__ bnpart,
    const void* __restrict__ gamma, const void* __restrict__ beta,
    float* __restrict__ scale, float* __restrict__ shift,
    const int* __restrict__ flagp, int loff){
  int f = *flagp;
  int c = threadIdx.x;
  float s = 0.f, q = 0.f;
  #pragma unroll 4
  for (int p = 0; p < NPART; ++p){
    s += bnpart[(size_t)p*512 + c];
    q += bnpart[(size_t)p*512 + HID + c];
  }
  float mu  = s * (1.f/N_NODESC);
  float var = q * (1.f/N_NODESC) - mu*mu;
  if (!(var >= 0.f)) var = 0.f;   // also catches NaN
  float sc = ldp(gamma, (size_t)loff + c, f) * rsqrtf(var + BN_EPSC);
  scale[c] = sc;
  shift[c] = ldp(beta, (size_t)loff + c, f) - mu*sc;
}

// Tier A: h += relu(bn(gout))
__global__ __launch_bounds__(256) void k_bn_apply(const u16* __restrict__ g,
    const float* __restrict__ scale, const float* __restrict__ shift, u16* __restrict__ h){
  int idx = blockIdx.x*256 + threadIdx.x;           // N*HID/4 total
  int c4 = (idx & 63) * 4;
  const u16x4 gv = *(const u16x4*)(g + (size_t)idx*4);
  const f32x4 sc = *(const f32x4*)(scale + c4);
  const f32x4 sh = *(const f32x4*)(shift + c4);
  u16x4 hv = *(u16x4*)(h + (size_t)idx*4);
  u16x4 o;
  #pragma unroll
  for (int j = 0; j < 4; ++j){
    float t = b2f(gv[j])*sc[j] + sh[j];
    t = (t > 0.f) ? t : 0.f;
    o[j] = f2b(b2f(hv[j]) + t);
  }
  *(u16x4*)(h + (size_t)idx*4) = o;
}

// ---------------- mean pool per graph (batch sorted; also counts nodes/graph) ----------------
__global__ __launch_bounds__(256) void k_pool(const u16* __restrict__ h,
    const int* __restrict__ batch, float* __restrict__ gsum, int* __restrict__ gcnt){
  int c = threadIdx.x;
  int r0 = blockIdx.x * 256;
  int r1 = min(r0 + 256, N_NODESC);
  if (r0 >= N_NODESC) return;
  int cur = batch[r0];
  float acc = 0.f;
  int nacc = 0;
  for (int r = r0; r < r1; ++r){
    int b = batch[r];
    if ((unsigned)b >= NGRAPHS) continue;
    if (b != cur){
      if ((unsigned)cur < NGRAPHS){
        atomicAdd(&gsum[cur*HID + c], acc);
        if (c == 0) atomicAdd(&gcnt[cur], nacc);
      }
      acc = 0.f; nacc = 0; cur = b;
    }
    acc += b2f(h[(size_t)r*HID + c]);
    nacc++;
  }
  if ((unsigned)cur < NGRAPHS){
    atomicAdd(&gsum[cur*HID + c], acc);
    if (c == 0) atomicAdd(&gcnt[cur], nacc);
  }
}

// ---------------- token predictors: 32 graphs/block, mean-div fused ----------------
__global__ __launch_bounds__(256) void k_pred(const float* __restrict__ g,
    const int* __restrict__ gcnt,
    const void* __restrict__ tokW, const void* __restrict__ tokb, void* __restrict__ out,
    const int* __restrict__ flagp){
  __shared__ float glds[32*HID];   // 32 KB
  __shared__ float cinv[32];
  int f = *flagp;
  int tid = threadIdx.x;
  int vt = blockIdx.x, gg = blockIdx.y, s = blockIdx.z;
  int g0 = gg*32;
  if (tid < 32){
    int cc = gcnt[g0 + tid]; if (cc < 1) cc = 1;
    cinv[tid] = 1.f/(float)cc;
  }
  __syncthreads();
  #pragma unroll
  for (int j = 0; j < 32; ++j) glds[j*HID + tid] = g[(size_t)(g0+j)*HID + tid] * cinv[j];
  __syncthreads();
  int v = vt*256 + tid;
  if (v >= VOCABC) return;
  float acc[32];
  #pragma unroll
  for (int j = 0; j < 32; ++j) acc[j] = 0.f;
  size_t wbase = (size_t)s*HID*VOCABC + v;
  for (int k = 0; k < HID; ++k){
    float w = ldp(tokW, wbase + (size_t)k*VOCABC, f);
    #pragma unroll
    for (int j = 0; j < 32; ++j) acc[j] += glds[j*HID + k] * w;
  }
  float bb = ldp(tokb, (size_t)s*VOCABC + v, f);
  #pragma unroll
  for (int j = 0; j < 32; ++j){
    float val = acc[j] + bb;
    size_t oi = ((size_t)(s*NGRAPHS + g0 + j)*VOCABC) + v;
    if (f) ((float*)out)[oi] = val;
    else   ((u16*)out)[oi]   = f2b(val);
  }
}

// ---------------- host launcher ----------------
extern "C" void kernel_launch(void* const* d_in, const int* in_sizes, int n_in,
                              void* d_out, int out_size, void* d_ws, size_t ws_size,
                              hipStream_t stream) {
  const int* x          = (const int*)d_in[0];
  const int* node_depth = (const int*)d_in[1];
  const int* edge_index = (const int*)d_in[2];
  const int* batch      = (const int*)d_in[3];
  const void* type_emb  = d_in[4];
  const void* attr_emb  = d_in[5];
  const void* depth_emb = d_in[6];
  const void* Ws        = d_in[7];
  const void* att_src   = d_in[8];
  const void* att_dst   = d_in[9];
  // d_in[10] = gat_bias: dropped (constant per channel cancels inside BatchNorm)
  const void* bn_gamma  = d_in[11];
  const void* bn_beta   = d_in[12];
  const void* tok_W     = d_in[13];
  const void* tok_b     = d_in[14];

  // ---- workspace carve ----
  char* base = (char*)d_ws;
  size_t off = 0;
  auto carve = [&](size_t bytes) -> void* {
    void* p = base + off;
    off += (bytes + 255) & ~(size_t)255;
    return p;
  };
  u16*   h     = (u16*)carve((size_t)N_NODESC*HID*2);     // 51.2 MB
  u16*   hh    = (u16*)carve((size_t)N_NODESC*HID*2);     // 51.2 MB
  float* ssrc  = (float*)carve((size_t)N_NODESC*8*4);     // 3.2 MB
  float* sdst  = (float*)carve((size_t)N_NODESC*8*4);     // 3.2 MB
  int*   soff  = (int*)carve((size_t)(N_NODESC+1)*4);
  int*   cursor= (int*)carve((size_t)N_NODESC*4);
  int*   ssorted=(int*)carve((size_t)E_TOT*4);            // 2.0 MB
  int*   btot  = (int*)carve((size_t)NCHUNK*4);
  int*   boff  = (int*)carve((size_t)NCHUNK*4);
  u16*   WT    = (u16*)carve((size_t)NLAYERS*HID*HID*2);  // 0.5 MB
  float* bnpart= (float*)carve((size_t)NPART*512*4);      // 128 KB BN partials
  float* bnscale=(float*)carve(HID*4);
  float* bnshift=(float*)carve(HID*4);
  float* gsum  = (float*)carve((size_t)NGRAPHS*HID*4);    // 128 KB
  int*   gcnt  = (int*)carve((size_t)NGRAPHS*4);          // adjacent to gsum
  int*   dflag = (int*)carve(256);
  size_t common = off;
  u16*   gout  = (u16*)carve((size_t)N_NODESC*HID*2);     // +51.2 MB
  const bool useGout = (off <= ws_size);
  if (common > ws_size) return;  // cannot run at all

  const int EB  = (E_TOT + 255)/256;
  const int NB4 = (N_NODESC + 3)/4;      // wave-per-node kernels

  // dtype detection first
  k_detect<<<1, 64, 0, stream>>>(type_emb, dflag);

  // setup (k_embed also zeroes cursor)
  k_embed<<<N_NODESC, 256, 0, stream>>>(x, node_depth, type_emb, attr_emb, depth_emb, h, dflag, cursor);
  k_transW<<<dim3(256, NLAYERS), 256, 0, stream>>>(Ws, WT, dflag);
  k_hist<<<EB, 256, 0, stream>>>(edge_index, cursor);
  k_scan_part<<<NCHUNK, 256, 0, stream>>>(cursor, soff, btot);
  k_scan_tot<<<1, 256, 0, stream>>>(btot, boff, soff + N_NODESC);
  k_scan_add<<<NCHUNK, 256, 0, stream>>>(soff, boff, cursor);   // also zeroes cursor
  k_scatter<<<EB, 256, 0, stream>>>(edge_index, soff, cursor, ssorted);

  // layers
  for (int l = 0; l < NLAYERS; ++l){
    int H = (l == NLAYERS-1) ? 1 : 8;
    k_gemm<<<1024, 256, 0, stream>>>(h, WT + (size_t)l*HID*HID, hh);
    k_scores<<<NB4, 256, 0, stream>>>(hh, att_src, att_dst, ssrc, sdst, H, dflag, l*HID, bnpart);
    if (useGout){
      k_attn_gout<<<NB4, 256, 0, stream>>>(hh, ssrc, sdst, soff, ssorted, gout, H, bnpart);
      k_bn_final<<<1, 256, 0, stream>>>(bnpart, bn_gamma, bn_beta, bnscale, bnshift, dflag, l*HID);
      k_bn_apply<<<(N_NODESC*HID/4)/256, 256, 0, stream>>>(gout, bnscale, bnshift, h);
    } else {
      k_attn_stats<<<2048, 256, 0, stream>>>(hh, ssrc, sdst, soff, ssorted, bnpart, H);
      k_bn_final<<<1, 256, 0, stream>>>(bnpart, bn_gamma, bn_beta, bnscale, bnshift, dflag, l*HID);
      k_attn_apply<<<NB4, 256, 0, stream>>>(hh, ssrc, sdst, soff, ssorted, bnscale, bnshift, h, H);
    }
  }

  // pool (gsum+gcnt adjacent -> single zero launch; counting fused into k_pool)
  k_zero<<<(NGRAPHS*HID + NGRAPHS + 255)/256, 256, 0, stream>>>((int*)gsum, NGRAPHS*HID + NGRAPHS);
  k_pool<<<NCHUNK, 256, 0, stream>>>(h, batch, gsum, gcnt);

  // predictors (mean-div fused via gcnt)
  k_pred<<<dim3((VOCABC+255)/256, NGRAPHS/32, SEQLEN), 256, 0, stream>>>(gsum, gcnt, tok_W, tok_b, d_out, dflag);
}

// Round 9
// 1200.541 us; speedup vs baseline: 2.1537x; 1.0384x over previous
//
#include <hip/hip_runtime.h>
#include <stdint.h>

typedef uint16_t u16;
typedef uint32_t u32;

#define N_NODESC 100000
#define N_EDGESC 400000
#define E_TOT    500000   // edges + self loops
#define HID      256
#define NLAYERS  4
#define NGRAPHS  128
#define SEQLEN   5
#define VOCABC   5002
#define MAXDEPTH 20
#define NEG_SLOPE 0.2f
#define BN_EPSC  1e-5f
#define NCHUNK   ((N_NODESC + 255)/256)   // 391
#define NROWT    (N_NODESC/16)            // 6250 row tiles, exact
#define NPART    64                       // BN partial rows (each 512 floats: 256 sum + 256 sq)
#define NVQ      ((VOCABC + 63)/64)       // 79 vocab quads for k_pred

typedef __attribute__((ext_vector_type(8))) short short8;
typedef __attribute__((ext_vector_type(4))) float f32x4;
typedef __attribute__((ext_vector_type(4))) unsigned short u16x4;

__device__ __forceinline__ float b2f(u16 u){
  union { u32 i; float f; } v; v.i = ((u32)u) << 16; return v.f;
}
__device__ __forceinline__ u16 f2b(float f){
  union { float f; u32 i; } v; v.f = f;
  u32 u = v.i;
  u += 0x7FFFu + ((u >> 16) & 1u);   // RNE
  return (u16)(u >> 16);
}
// dual-dtype parameter load: flag=1 -> f32, flag=0 -> bf16
__device__ __forceinline__ float ldp(const void* p, size_t i, int f){
  return f ? ((const float*)p)[i] : b2f(((const u16*)p)[i]);
}

// ---------------- dtype detector: sample type_emb both ways ----------------
__global__ __launch_bounds__(64) void k_detect(const void* temb, int* flag){
  int lane = threadIdx.x;
  const u32* w32 = (const u32*)temb;
  int sf = 0, sb = 0;
  for (int i = lane; i < 256; i += 64){
    u32 w = w32[i];
    union { u32 u; float f; } cf; cf.u = w;
    float af = fabsf(cf.f);
    if (cf.f == 0.0f || (af >= 1e-12f && af <= 4096.f)) sf++;
    float b0 = b2f((u16)(w & 0xFFFFu));
    float b1 = b2f((u16)(w >> 16));
    float a0 = fabsf(b0), a1 = fabsf(b1);
    if (b0 == 0.f || (a0 >= 1e-12f && a0 <= 4096.f)) sb++;
    if (b1 == 0.f || (a1 >= 1e-12f && a1 <= 4096.f)) sb++;
  }
  #pragma unroll
  for (int o = 1; o < 64; o <<= 1){ sf += __shfl_xor(sf, o); sb += __shfl_xor(sb, o); }
  if (lane == 0) *flag = (2*sf > sb) ? 1 : 0;
}

// ---------------- utility ----------------
__global__ __launch_bounds__(256) void k_zero(int* __restrict__ p, int n){
  int i = blockIdx.x*256 + threadIdx.x;
  if (i < n) p[i] = 0;
}

// ---------------- embedding (writes bf16 h; also zeroes cursor[n]) ----------------
__global__ __launch_bounds__(256) void k_embed(const int* __restrict__ x, const int* __restrict__ nd,
    const void* __restrict__ temb, const void* __restrict__ aemb, const void* __restrict__ demb,
    u16* __restrict__ h, const int* __restrict__ flagp, int* __restrict__ cursor){
  int f = *flagp;
  int n = blockIdx.x; int c = threadIdx.x;
  if (c == 0) cursor[n] = 0;   // histogram counter zero, ready before k_hist
  int t = x[n*2+0], a = x[n*2+1];
  if (t < 0) t = 0; if (t > 97) t = 97;
  if (a < 0) a = 0; if (a > 10029) a = 10029;
  int d = nd[n]; if (d > MAXDEPTH) d = MAXDEPTH; if (d < 0) d = 0;
  float v = ldp(temb, (size_t)t*HID+c, f) + ldp(aemb, (size_t)a*HID+c, f) + ldp(demb, (size_t)d*HID+c, f);
  h[(size_t)n*HID+c] = f2b(v);
}

// ---------------- edge sort by dst (counting sort) ----------------
__global__ __launch_bounds__(256) void k_hist(const int* __restrict__ ei, int* __restrict__ cnt){
  int e = blockIdx.x*256 + threadIdx.x;
  if (e >= E_TOT) return;
  int dst = (e < N_EDGESC) ? ei[N_EDGESC + e] : (e - N_EDGESC);
  if ((unsigned)dst >= N_NODESC) return;
  atomicAdd(&cnt[dst], 1);
}

// hierarchical scan, phase 1: per-256-chunk exclusive scan + chunk total
__global__ __launch_bounds__(256) void k_scan_part(const int* __restrict__ cnt,
    int* __restrict__ off, int* __restrict__ btot){
  __shared__ int lds[256];
  int b = blockIdx.x, tid = threadIdx.x;
  int i = b*256 + tid;
  int v = (i < N_NODESC) ? cnt[i] : 0;
  lds[tid] = v;
  __syncthreads();
  #pragma unroll
  for (int s = 1; s < 256; s <<= 1){
    int t = (tid >= s) ? lds[tid - s] : 0;
    __syncthreads();
    lds[tid] += t;
    __syncthreads();
  }
  if (i < N_NODESC) off[i] = lds[tid] - v;   // chunk-local exclusive
  if (tid == 255) btot[b] = lds[255];
}

// phase 2: scan the 391 chunk totals (1 block), write grand total to offN
__global__ __launch_bounds__(256) void k_scan_tot(const int* __restrict__ btot,
    int* __restrict__ boff, int* __restrict__ offN){
  __shared__ int lds[256];
  __shared__ int s_carry;
  int tid = threadIdx.x;
  if (tid == 0) s_carry = 0;
  __syncthreads();
  for (int base = 0; base < NCHUNK; base += 256){
    int i = base + tid;
    int v = (i < NCHUNK) ? btot[i] : 0;
    lds[tid] = v;
    __syncthreads();
    #pragma unroll
    for (int s = 1; s < 256; s <<= 1){
      int t = (tid >= s) ? lds[tid - s] : 0;
      __syncthreads();
      lds[tid] += t;
      __syncthreads();
    }
    if (i < NCHUNK) boff[i] = s_carry + lds[tid] - v;
    __syncthreads();
    if (tid == 255) s_carry += lds[255];
    __syncthreads();
  }
  if (tid == 0) *offN = s_carry;
}

// phase 3: add chunk offsets; also re-zero cursor for the scatter pass
__global__ __launch_bounds__(256) void k_scan_add(int* __restrict__ off,
    const int* __restrict__ boff, int* __restrict__ cursor){
  int b = blockIdx.x;
  int i = b*256 + threadIdx.x;
  if (i < N_NODESC){ off[i] += boff[b]; cursor[i] = 0; }
}

__global__ __launch_bounds__(256) void k_scatter(const int* __restrict__ ei,
    const int* __restrict__ soff, int* __restrict__ cursor, int* __restrict__ ssorted){
  int e = blockIdx.x*256 + threadIdx.x;
  if (e >= E_TOT) return;
  int src = (e < N_EDGESC) ? ei[e]            : (e - N_EDGESC);
  int dst = (e < N_EDGESC) ? ei[N_EDGESC + e] : (e - N_EDGESC);
  if ((unsigned)dst >= N_NODESC || (unsigned)src >= N_NODESC) return;
  int pos = soff[dst] + atomicAdd(&cursor[dst], 1);
  if ((unsigned)pos < E_TOT) ssorted[pos] = src;
}

// ---------------- W transpose -> bf16 WT, all layers ----------------
__global__ __launch_bounds__(256) void k_transW(const void* __restrict__ W, u16* __restrict__ WT,
    const int* __restrict__ flagp){
  int f = *flagp;
  int l = blockIdx.y, n2 = blockIdx.x, k = threadIdx.x;
  WT[(l*HID + n2)*HID + k] = f2b(ldp(W, (size_t)(l*HID + k)*HID + n2, f));
}

// ---------------- GEMM: hh = h @ W, MFMA 16x16x32 bf16, register-resident B ----------------
__global__ __launch_bounds__(256) void k_gemm(const u16* __restrict__ h,
    const u16* __restrict__ WT, u16* __restrict__ hh){
  int wave = threadIdx.x >> 6, lane = threadIdx.x & 63;
  int m = lane & 15, quad = lane >> 4;

  short8 B[4][8];
  #pragma unroll
  for (int j = 0; j < 4; ++j){
    const u16* wp = WT + (size_t)((wave*4 + j)*16 + m)*HID + quad*8;
    #pragma unroll
    for (int ks = 0; ks < 8; ++ks)
      B[j][ks] = *(const short8*)(wp + ks*32);
  }

  for (int t = blockIdx.x; t < NROWT; t += gridDim.x){
    int r0 = t*16;
    const u16* ap = h + (size_t)(r0 + m)*HID + quad*8;
    short8 A[8];
    #pragma unroll
    for (int ks = 0; ks < 8; ++ks)
      A[ks] = *(const short8*)(ap + ks*32);

    f32x4 acc[4];
    #pragma unroll
    for (int j = 0; j < 4; ++j) acc[j] = (f32x4){0.f,0.f,0.f,0.f};
    #pragma unroll
    for (int ks = 0; ks < 8; ++ks){
      #pragma unroll
      for (int j = 0; j < 4; ++j)
        acc[j] = __builtin_amdgcn_mfma_f32_16x16x32_bf16(A[ks], B[j][ks], acc[j], 0, 0, 0);
    }

    #pragma unroll
    for (int j = 0; j < 4; ++j){
      int col = (wave*4 + j)*16 + m;
      #pragma unroll
      for (int r = 0; r < 4; ++r){
        int orow = r0 + quad*4 + r;
        hh[(size_t)orow*HID + col] = f2b(acc[j][r]);
      }
    }
  }
}

// ---------------- per-head scores (blocks 0..127 also zero BN partials) ----------------
__global__ __launch_bounds__(256) void k_scores(const u16* __restrict__ hh,
    const void* __restrict__ asrc, const void* __restrict__ adst,
    float* __restrict__ ssrc, float* __restrict__ sdst, int H,
    const int* __restrict__ flagp, int loff,
    float* __restrict__ bnpart){
  if (blockIdx.x < NPART*2) bnpart[blockIdx.x*256 + threadIdx.x] = 0.f;  // 64*512 floats
  int f = *flagp;
  int wid = threadIdx.x >> 6, lane = threadIdx.x & 63;
  int n = blockIdx.x*4 + wid;
  if (n >= N_NODESC) return;
  int f0 = lane*4;
  const u16x4 hv = *(const u16x4*)(hh + (size_t)n*HID + f0);
  float ps = 0.f, pd = 0.f;
  #pragma unroll
  for (int j = 0; j < 4; ++j){
    float hvf = b2f(hv[j]);
    ps += hvf * ldp(asrc, (size_t)loff + f0 + j, f);
    pd += hvf * ldp(adst, (size_t)loff + f0 + j, f);
  }
  if (H == 8){
    #pragma unroll
    for (int o = 1; o < 8; o <<= 1){ ps += __shfl_xor(ps, o); pd += __shfl_xor(pd, o); }
    if ((lane & 7) == 0){ ssrc[n*8 + (lane>>3)] = ps; sdst[n*8 + (lane>>3)] = pd; }
  } else {
    #pragma unroll
    for (int o = 1; o < 64; o <<= 1){ ps += __shfl_xor(ps, o); pd += __shfl_xor(pd, o); }
    if (lane == 0){ ssrc[n] = ps; sdst[n] = pd; }
  }
}

// ---------------- attention core: online softmax aggregate for node n ----------------
// gat_bias dropped: per-channel constant cancels exactly inside BatchNorm.
__device__ __forceinline__ void attn_node(int n, int lane, const u16* __restrict__ hh,
    const float* __restrict__ ssrc, const float* __restrict__ sdst,
    const int* __restrict__ soff, const int* __restrict__ ssorted, int H, float r[4]){
  int f0 = lane*4;
  int hl = (H == 8) ? (lane >> 3) : 0;
  float sd = sdst[n*H + hl];
  int beg = soff[n], end = soff[n+1];
  if (beg < 0) beg = 0;
  if (end > E_TOT) end = E_TOT;
  float mval = -1e30f, lval = 0.f;
  float o0 = 0.f, o1 = 0.f, o2 = 0.f, o3 = 0.f;
  for (int i = beg; i < end; ++i){
    int src = ssorted[i];
    if ((unsigned)src >= N_NODESC) continue;
    float ev = ssrc[src*H + hl] + sd;
    ev = (ev > 0.f) ? ev : NEG_SLOPE*ev;
    float nm = fmaxf(mval, ev);
    float sc = __expf(mval - nm);
    float wv = __expf(ev - nm);
    const u16x4 hvv = *(const u16x4*)(hh + (size_t)src*HID + f0);
    lval = lval*sc + wv;
    o0 = o0*sc + wv*b2f(hvv[0]);
    o1 = o1*sc + wv*b2f(hvv[1]);
    o2 = o2*sc + wv*b2f(hvv[2]);
    o3 = o3*sc + wv*b2f(hvv[3]);
    mval = nm;
  }
  float inv = (lval > 0.f) ? 1.f/lval : 0.f;
  r[0] = o0*inv; r[1] = o1*inv; r[2] = o2*inv; r[3] = o3*inv;
}

// Tier A: write gout (bf16) + fused BN partial stats (lane owns channels lane*4..+3)
__global__ __launch_bounds__(256) void k_attn_gout(const u16* __restrict__ hh,
    const float* __restrict__ ssrc, const float* __restrict__ sdst,
    const int* __restrict__ soff, const int* __restrict__ ssorted,
    u16* __restrict__ gout, int H, float* __restrict__ bnpart){
  __shared__ float lsum[4*HID];
  __shared__ float lsq[4*HID];
  int wid = threadIdx.x >> 6, lane = threadIdx.x & 63;
  int n = blockIdx.x*4 + wid;
  int f0 = lane*4;
  float r[4] = {0.f,0.f,0.f,0.f};
  if (n < N_NODESC){
    attn_node(n, lane, hh, ssrc, sdst, soff, ssorted, H, r);
    u16x4 o;
    #pragma unroll
    for (int j = 0; j < 4; ++j) o[j] = f2b(r[j]);
    *(u16x4*)(gout + (size_t)n*HID + f0) = o;
  }
  #pragma unroll
  for (int j = 0; j < 4; ++j){
    lsum[wid*HID + f0 + j] = r[j];
    lsq [wid*HID + f0 + j] = r[j]*r[j];
  }
  __syncthreads();
  int c = threadIdx.x;
  float ts = lsum[c] + lsum[HID+c] + lsum[2*HID+c] + lsum[3*HID+c];
  float tq = lsq[c]  + lsq[HID+c]  + lsq[2*HID+c]  + lsq[3*HID+c];
  float* prow = bnpart + (size_t)(blockIdx.x & (NPART-1))*512;
  atomicAdd(&prow[c], ts);
  atomicAdd(&prow[HID + c], tq);
}

// Tier B pass 1: recompute attention, block-reduce BN stats into partials
__global__ __launch_bounds__(256) void k_attn_stats(const u16* __restrict__ hh,
    const float* __restrict__ ssrc, const float* __restrict__ sdst,
    const int* __restrict__ soff, const int* __restrict__ ssorted,
    float* __restrict__ bnpart, int H){
  __shared__ float lsum[4*HID];
  __shared__ float lsq[4*HID];
  int wid = threadIdx.x >> 6, lane = threadIdx.x & 63;
  int gw = blockIdx.x*4 + wid;
  int nw = gridDim.x*4;
  float s[4] = {0.f,0.f,0.f,0.f}, q[4] = {0.f,0.f,0.f,0.f};
  for (int n = gw; n < N_NODESC; n += nw){
    float r[4];
    attn_node(n, lane, hh, ssrc, sdst, soff, ssorted, H, r);
    #pragma unroll
    for (int j = 0; j < 4; ++j){ s[j] += r[j]; q[j] += r[j]*r[j]; }
  }
  int f0 = lane*4;
  #pragma unroll
  for (int j = 0; j < 4; ++j){ lsum[wid*HID + f0 + j] = s[j]; lsq[wid*HID + f0 + j] = q[j]; }
  __syncthreads();
  int c = threadIdx.x;
  float ts = lsum[c] + lsum[HID+c] + lsum[2*HID+c] + lsum[3*HID+c];
  float tq = lsq[c]  + lsq[HID+c]  + lsq[2*HID+c]  + lsq[3*HID+c];
  float* prow = bnpart + (size_t)(blockIdx.x & (NPART-1))*512;
  atomicAdd(&prow[c], ts);
  atomicAdd(&prow[HID + c], tq);
}

// Tier B pass 2: recompute attention, fused BN+ReLU+residual into h
__global__ __launch_bounds__(256) void k_attn_apply(const u16* __restrict__ hh,
    const float* __restrict__ ssrc, const float* __restrict__ sdst,
    const int* __restrict__ soff, const int* __restrict__ ssorted,
    const float* __restrict__ scale, const float* __restrict__ shift,
    u16* __restrict__ h, int H){
  int wid = threadIdx.x >> 6, lane = threadIdx.x & 63;
  int n = blockIdx.x*4 + wid;
  if (n >= N_NODESC) return;
  float r[4];
  attn_node(n, lane, hh, ssrc, sdst, soff, ssorted, H, r);
  int f0 = lane*4;
  const f32x4 sc = *(const f32x4*)(scale + f0);
  const f32x4 sh = *(const f32x4*)(shift + f0);
  u16x4 hv = *(u16x4*)(h + (size_t)n*HID + f0);
  u16x4 o;
  #pragma unroll
  for (int j = 0; j < 4; ++j){
    float t = r[j]*sc[j] + sh[j];
    t = (t > 0.f) ? t : 0.f;
    o[j] = f2b(b2f(hv[j]) + t);
  }
  *(u16x4*)(h + (size_t)n*HID + f0) = o;
}

// ---------------- BN finalize: reduce 64 partial rows -> scale/shift ----------------
__global__ __launch_bounds__(256) void k_bn_final(const float* __restrict__ bnpart,
    const void* __restrict__ gamma, const void* __restrict__ beta,
    float* __restrict__ scale, float* __restrict__ shift,
    const int* __restrict__ flagp, int loff){
  int f = *flagp;
  int c = threadIdx.x;
  float s = 0.f, q = 0.f;
  #pragma unroll 4
  for (int p = 0; p < NPART; ++p){
    s += bnpart[(size_t)p*512 + c];
    q += bnpart[(size_t)p*512 + HID + c];
  }
  float mu  = s * (1.f/N_NODESC);
  float var = q * (1.f/N_NODESC) - mu*mu;
  if (!(var >= 0.f)) var = 0.f;   // also catches NaN
  float sc = ldp(gamma, (size_t)loff + c, f) * rsqrtf(var + BN_EPSC);
  scale[c] = sc;
  shift[c] = ldp(beta, (size_t)loff + c, f) - mu*sc;
}

// Tier A: h += relu(bn(gout))
__global__ __launch_bounds__(256) void k_bn_apply(const u16* __restrict__ g,
    const float* __restrict__ scale, const float* __restrict__ shift, u16* __restrict__ h){
  int idx = blockIdx.x*256 + threadIdx.x;           // N*HID/4 total
  int c4 = (idx & 63) * 4;
  const u16x4 gv = *(const u16x4*)(g + (size_t)idx*4);
  const f32x4 sc = *(const f32x4*)(scale + c4);
  const f32x4 sh = *(const f32x4*)(shift + c4);
  u16x4 hv = *(u16x4*)(h + (size_t)idx*4);
  u16x4 o;
  #pragma unroll
  for (int j = 0; j < 4; ++j){
    float t = b2f(gv[j])*sc[j] + sh[j];
    t = (t > 0.f) ? t : 0.f;
    o[j] = f2b(b2f(hv[j]) + t);
  }
  *(u16x4*)(h + (size_t)idx*4) = o;
}

// ---------------- mean pool per graph (batch sorted; also counts nodes/graph) ----------------
__global__ __launch_bounds__(256) void k_pool(const u16* __restrict__ h,
    const int* __restrict__ batch, float* __restrict__ gsum, int* __restrict__ gcnt){
  int c = threadIdx.x;
  int r0 = blockIdx.x * 256;
  int r1 = min(r0 + 256, N_NODESC);
  if (r0 >= N_NODESC) return;
  int cur = batch[r0];
  float acc = 0.f;
  int nacc = 0;
  for (int r = r0; r < r1; ++r){
    int b = batch[r];
    if ((unsigned)b >= NGRAPHS) continue;
    if (b != cur){
      if ((unsigned)cur < NGRAPHS){
        atomicAdd(&gsum[cur*HID + c], acc);
        if (c == 0) atomicAdd(&gcnt[cur], nacc);
      }
      acc = 0.f; nacc = 0; cur = b;
    }
    acc += b2f(h[(size_t)r*HID + c]);
    nacc++;
  }
  if ((unsigned)cur < NGRAPHS){
    atomicAdd(&gsum[cur*HID + c], acc);
    if (c == 0) atomicAdd(&gcnt[cur], nacc);
  }
}

// ---------------- G prep: mean-divide and convert to bf16 (64 KB, L2-resident) ----------------
__global__ __launch_bounds__(256) void k_gprep(const float* __restrict__ gsum,
    const int* __restrict__ gcnt, u16* __restrict__ gbf){
  int g = blockIdx.x, c = threadIdx.x;
  int cc = gcnt[g]; if (cc < 1) cc = 1;
  gbf[g*HID + c] = f2b(gsum[(size_t)g*HID + c] * (1.f/(float)cc));
}

// ---------------- token predictors: MFMA GEMM  preds[s] = G[128,256] @ W_s[256,5002] ----------------
// Wave owns a 16-v strip x all 8 m-tiles. A frag from L2-hot gbf; B frag from tokW (f2b on the fly).
// A: lane holds G[m0 + (lane&15)][kb + quad*8 + j]; B: lane holds W[kb+quad*8+j][v0 + (lane&15)];
// D: col=lane&15 (v), row=quad*4+r (g within m-tile).
__global__ __launch_bounds__(256) void k_pred(const u16* __restrict__ gbf,
    const void* __restrict__ tokW, const void* __restrict__ tokb, void* __restrict__ out,
    const int* __restrict__ flagp){
  int f = *flagp;
  int wave = threadIdx.x >> 6, lane = threadIdx.x & 63;
  int m = lane & 15, quad = lane >> 4;
  int s = blockIdx.y;
  int v = blockIdx.x*64 + wave*16 + m;       // this lane's vocab column
  bool vok = (v < VOCABC);

  f32x4 acc[8];
  #pragma unroll
  for (int t = 0; t < 8; ++t) acc[t] = (f32x4){0.f,0.f,0.f,0.f};

  const size_t wrow = (size_t)s*HID*VOCABC + v;
  #pragma unroll
  for (int ks = 0; ks < 8; ++ks){
    int kb = ks*32 + quad*8;
    // B frag: 8 strided loads along k (coalesced across lanes), convert to bf16
    short8 b;
    #pragma unroll
    for (int j = 0; j < 8; ++j)
      b[j] = vok ? (short)f2b(ldp(tokW, wrow + (size_t)(kb + j)*VOCABC, f)) : (short)0;
    // A frags: one 16B load per m-tile from L2-hot gbf
    #pragma unroll
    for (int t = 0; t < 8; ++t){
      const short8 a = *(const short8*)(gbf + (size_t)(t*16 + m)*HID + kb);
      acc[t] = __builtin_amdgcn_mfma_f32_16x16x32_bf16(a, b, acc[t], 0, 0, 0);
    }
  }

  float bb = vok ? ldp(tokb, (size_t)s*VOCABC + v, f) : 0.f;
  if (!vok) return;
  #pragma unroll
  for (int t = 0; t < 8; ++t){
    #pragma unroll
    for (int r = 0; r < 4; ++r){
      int grow = t*16 + quad*4 + r;
      float val = acc[t][r] + bb;
      size_t oi = ((size_t)(s*NGRAPHS + grow)*VOCABC) + v;
      if (f) ((float*)out)[oi] = val;
      else   ((u16*)out)[oi]   = f2b(val);
    }
  }
}

// ---------------- host launcher ----------------
extern "C" void kernel_launch(void* const* d_in, const int* in_sizes, int n_in,
                              void* d_out, int out_size, void* d_ws, size_t ws_size,
                              hipStream_t stream) {
  const int* x          = (const int*)d_in[0];
  const int* node_depth = (const int*)d_in[1];
  const int* edge_index = (const int*)d_in[2];
  const int* batch      = (const int*)d_in[3];
  const void* type_emb  = d_in[4];
  const void* attr_emb  = d_in[5];
  const void* depth_emb = d_in[6];
  const void* Ws        = d_in[7];
  const void* att_src   = d_in[8];
  const void* att_dst   = d_in[9];
  // d_in[10] = gat_bias: dropped (constant per channel cancels inside BatchNorm)
  const void* bn_gamma  = d_in[11];
  const void* bn_beta   = d_in[12];
  const void* tok_W     = d_in[13];
  const void* tok_b     = d_in[14];

  // ---- workspace carve ----
  char* base = (char*)d_ws;
  size_t off = 0;
  auto carve = [&](size_t bytes) -> void* {
    void* p = base + off;
    off += (bytes + 255) & ~(size_t)255;
    return p;
  };
  u16*   h     = (u16*)carve((size_t)N_NODESC*HID*2);     // 51.2 MB
  u16*   hh    = (u16*)carve((size_t)N_NODESC*HID*2);     // 51.2 MB
  float* ssrc  = (float*)carve((size_t)N_NODESC*8*4);     // 3.2 MB
  float* sdst  = (float*)carve((size_t)N_NODESC*8*4);     // 3.2 MB
  int*   soff  = (int*)carve((size_t)(N_NODESC+1)*4);
  int*   cursor= (int*)carve((size_t)N_NODESC*4);
  int*   ssorted=(int*)carve((size_t)E_TOT*4);            // 2.0 MB
  int*   btot  = (int*)carve((size_t)NCHUNK*4);
  int*   boff  = (int*)carve((size_t)NCHUNK*4);
  u16*   WT    = (u16*)carve((size_t)NLAYERS*HID*HID*2);  // 0.5 MB
  float* bnpart= (float*)carve((size_t)NPART*512*4);      // 128 KB BN partials
  float* bnscale=(float*)carve(HID*4);
  float* bnshift=(float*)carve(HID*4);
  float* gsum  = (float*)carve((size_t)NGRAPHS*HID*4);    // 128 KB
  int*   gcnt  = (int*)carve((size_t)NGRAPHS*4);          // adjacent to gsum
  u16*   gbf   = (u16*)carve((size_t)NGRAPHS*HID*2);      // 64 KB bf16 pooled graphs
  int*   dflag = (int*)carve(256);
  size_t common = off;
  u16*   gout  = (u16*)carve((size_t)N_NODESC*HID*2);     // +51.2 MB
  const bool useGout = (off <= ws_size);
  if (common > ws_size) return;  // cannot run at all

  const int EB  = (E_TOT + 255)/256;
  const int NB4 = (N_NODESC + 3)/4;      // wave-per-node kernels

  // dtype detection first
  k_detect<<<1, 64, 0, stream>>>(type_emb, dflag);

  // setup (k_embed also zeroes cursor)
  k_embed<<<N_NODESC, 256, 0, stream>>>(x, node_depth, type_emb, attr_emb, depth_emb, h, dflag, cursor);
  k_transW<<<dim3(256, NLAYERS), 256, 0, stream>>>(Ws, WT, dflag);
  k_hist<<<EB, 256, 0, stream>>>(edge_index, cursor);
  k_scan_part<<<NCHUNK, 256, 0, stream>>>(cursor, soff, btot);
  k_scan_tot<<<1, 256, 0, stream>>>(btot, boff, soff + N_NODESC);
  k_scan_add<<<NCHUNK, 256, 0, stream>>>(soff, boff, cursor);   // also zeroes cursor
  k_scatter<<<EB, 256, 0, stream>>>(edge_index, soff, cursor, ssorted);

  // layers
  for (int l = 0; l < NLAYERS; ++l){
    int H = (l == NLAYERS-1) ? 1 : 8;
    k_gemm<<<1024, 256, 0, stream>>>(h, WT + (size_t)l*HID*HID, hh);
    k_scores<<<NB4, 256, 0, stream>>>(hh, att_src, att_dst, ssrc, sdst, H, dflag, l*HID, bnpart);
    if (useGout){
      k_attn_gout<<<NB4, 256, 0, stream>>>(hh, ssrc, sdst, soff, ssorted, gout, H, bnpart);
      k_bn_final<<<1, 256, 0, stream>>>(bnpart, bn_gamma, bn_beta, bnscale, bnshift, dflag, l*HID);
      k_bn_apply<<<(N_NODESC*HID/4)/256, 256, 0, stream>>>(gout, bnscale, bnshift, h);
    } else {
      k_attn_stats<<<2048, 256, 0, stream>>>(hh, ssrc, sdst, soff, ssorted, bnpart, H);
      k_bn_final<<<1, 256, 0, stream>>>(bnpart, bn_gamma, bn_beta, bnscale, bnshift, dflag, l*HID);
      k_attn_apply<<<NB4, 256, 0, stream>>>(hh, ssrc, sdst, soff, ssorted, bnscale, bnshift, h, H);
    }
  }

  // pool (gsum+gcnt adjacent -> single zero launch; counting fused into k_pool)
  k_zero<<<(NGRAPHS*HID + NGRAPHS + 255)/256, 256, 0, stream>>>((int*)gsum, NGRAPHS*HID + NGRAPHS);
  k_pool<<<NCHUNK, 256, 0, stream>>>(h, batch, gsum, gcnt);
  k_gprep<<<NGRAPHS, 256, 0, stream>>>(gsum, gcnt, gbf);

  // predictors (MFMA GEMM)
  k_pred<<<dim3(NVQ, SEQLEN), 256, 0, stream>>>(gbf, tok_W, tok_b, d_out, dflag);
}

// Round 10
// 1062.454 us; speedup vs baseline: 2.4337x; 1.1300x over previous
//
#include <hip/hip_runtime.h>
#include <stdint.h>

typedef uint16_t u16;
typedef uint32_t u32;

#define N_NODESC 100000
#define N_EDGESC 400000
#define E_TOT    500000   // edges + self loops
#define HID      256
#define NLAYERS  4
#define NGRAPHS  128
#define SEQLEN   5
#define VOCABC   5002
#define MAXDEPTH 20
#define NEG_SLOPE 0.2f
#define BN_EPSC  1e-5f
#define NCHUNK   ((N_NODESC + 255)/256)   // 391
#define NROWT    (N_NODESC/16)            // 6250 row tiles, exact
#define NPART    64                       // BN partial rows (each 512 floats: 256 sum + 256 sq)
#define NVQ      ((VOCABC + 63)/64)       // 79 vocab quads for k_pred
#define ATTNB    2048                     // grid for k_attn_gout

typedef __attribute__((ext_vector_type(8))) short short8;
typedef __attribute__((ext_vector_type(4))) float f32x4;
typedef __attribute__((ext_vector_type(4))) unsigned short u16x4;

__device__ __forceinline__ float b2f(u16 u){
  union { u32 i; float f; } v; v.i = ((u32)u) << 16; return v.f;
}
__device__ __forceinline__ u16 f2b(float f){
  union { float f; u32 i; } v; v.f = f;
  u32 u = v.i;
  u += 0x7FFFu + ((u >> 16) & 1u);   // RNE
  return (u16)(u >> 16);
}
// dual-dtype parameter load: flag=1 -> f32, flag=0 -> bf16
__device__ __forceinline__ float ldp(const void* p, size_t i, int f){
  return f ? ((const float*)p)[i] : b2f(((const u16*)p)[i]);
}

// ---------------- dtype detector: sample type_emb both ways ----------------
__global__ __launch_bounds__(64) void k_detect(const void* temb, int* flag){
  int lane = threadIdx.x;
  const u32* w32 = (const u32*)temb;
  int sf = 0, sb = 0;
  for (int i = lane; i < 256; i += 64){
    u32 w = w32[i];
    union { u32 u; float f; } cf; cf.u = w;
    float af = fabsf(cf.f);
    if (cf.f == 0.0f || (af >= 1e-12f && af <= 4096.f)) sf++;
    float b0 = b2f((u16)(w & 0xFFFFu));
    float b1 = b2f((u16)(w >> 16));
    float a0 = fabsf(b0), a1 = fabsf(b1);
    if (b0 == 0.f || (a0 >= 1e-12f && a0 <= 4096.f)) sb++;
    if (b1 == 0.f || (a1 >= 1e-12f && a1 <= 4096.f)) sb++;
  }
  #pragma unroll
  for (int o = 1; o < 64; o <<= 1){ sf += __shfl_xor(sf, o); sb += __shfl_xor(sb, o); }
  if (lane == 0) *flag = (2*sf > sb) ? 1 : 0;
}

// ---------------- utility ----------------
__global__ __launch_bounds__(256) void k_zero(int* __restrict__ p, int n){
  int i = blockIdx.x*256 + threadIdx.x;
  if (i < n) p[i] = 0;
}

// ---------------- embedding (writes bf16 h; also zeroes cursor[n]) ----------------
__global__ __launch_bounds__(256) void k_embed(const int* __restrict__ x, const int* __restrict__ nd,
    const void* __restrict__ temb, const void* __restrict__ aemb, const void* __restrict__ demb,
    u16* __restrict__ h, const int* __restrict__ flagp, int* __restrict__ cursor){
  int f = *flagp;
  int n = blockIdx.x; int c = threadIdx.x;
  if (c == 0) cursor[n] = 0;   // histogram counter zero, ready before k_hist
  int t = x[n*2+0], a = x[n*2+1];
  if (t < 0) t = 0; if (t > 97) t = 97;
  if (a < 0) a = 0; if (a > 10029) a = 10029;
  int d = nd[n]; if (d > MAXDEPTH) d = MAXDEPTH; if (d < 0) d = 0;
  float v = ldp(temb, (size_t)t*HID+c, f) + ldp(aemb, (size_t)a*HID+c, f) + ldp(demb, (size_t)d*HID+c, f);
  h[(size_t)n*HID+c] = f2b(v);
}

// ---------------- edge sort by dst (counting sort) ----------------
__global__ __launch_bounds__(256) void k_hist(const int* __restrict__ ei, int* __restrict__ cnt){
  int e = blockIdx.x*256 + threadIdx.x;
  if (e >= E_TOT) return;
  int dst = (e < N_EDGESC) ? ei[N_EDGESC + e] : (e - N_EDGESC);
  if ((unsigned)dst >= N_NODESC) return;
  atomicAdd(&cnt[dst], 1);
}

// hierarchical scan, phase 1: per-256-chunk exclusive scan + chunk total
__global__ __launch_bounds__(256) void k_scan_part(const int* __restrict__ cnt,
    int* __restrict__ off, int* __restrict__ btot){
  __shared__ int lds[256];
  int b = blockIdx.x, tid = threadIdx.x;
  int i = b*256 + tid;
  int v = (i < N_NODESC) ? cnt[i] : 0;
  lds[tid] = v;
  __syncthreads();
  #pragma unroll
  for (int s = 1; s < 256; s <<= 1){
    int t = (tid >= s) ? lds[tid - s] : 0;
    __syncthreads();
    lds[tid] += t;
    __syncthreads();
  }
  if (i < N_NODESC) off[i] = lds[tid] - v;   // chunk-local exclusive
  if (tid == 255) btot[b] = lds[255];
}

// phase 2: scan the 391 chunk totals (1 block), write grand total to offN
__global__ __launch_bounds__(256) void k_scan_tot(const int* __restrict__ btot,
    int* __restrict__ boff, int* __restrict__ offN){
  __shared__ int lds[256];
  __shared__ int s_carry;
  int tid = threadIdx.x;
  if (tid == 0) s_carry = 0;
  __syncthreads();
  for (int base = 0; base < NCHUNK; base += 256){
    int i = base + tid;
    int v = (i < NCHUNK) ? btot[i] : 0;
    lds[tid] = v;
    __syncthreads();
    #pragma unroll
    for (int s = 1; s < 256; s <<= 1){
      int t = (tid >= s) ? lds[tid - s] : 0;
      __syncthreads();
      lds[tid] += t;
      __syncthreads();
    }
    if (i < NCHUNK) boff[i] = s_carry + lds[tid] - v;
    __syncthreads();
    if (tid == 255) s_carry += lds[255];
    __syncthreads();
  }
  if (tid == 0) *offN = s_carry;
}

// phase 3: add chunk offsets; also re-zero cursor for the scatter pass
__global__ __launch_bounds__(256) void k_scan_add(int* __restrict__ off,
    const int* __restrict__ boff, int* __restrict__ cursor){
  int b = blockIdx.x;
  int i = b*256 + threadIdx.x;
  if (i < N_NODESC){ off[i] += boff[b]; cursor[i] = 0; }
}

__global__ __launch_bounds__(256) void k_scatter(const int* __restrict__ ei,
    const int* __restrict__ soff, int* __restrict__ cursor, int* __restrict__ ssorted){
  int e = blockIdx.x*256 + threadIdx.x;
  if (e >= E_TOT) return;
  int src = (e < N_EDGESC) ? ei[e]            : (e - N_EDGESC);
  int dst = (e < N_EDGESC) ? ei[N_EDGESC + e] : (e - N_EDGESC);
  if ((unsigned)dst >= N_NODESC || (unsigned)src >= N_NODESC) return;
  int pos = soff[dst] + atomicAdd(&cursor[dst], 1);
  if ((unsigned)pos < E_TOT) ssorted[pos] = src;
}

// ---------------- W transpose -> bf16 WT, all layers ----------------
__global__ __launch_bounds__(256) void k_transW(const void* __restrict__ W, u16* __restrict__ WT,
    const int* __restrict__ flagp){
  int f = *flagp;
  int l = blockIdx.y, n2 = blockIdx.x, k = threadIdx.x;
  WT[(l*HID + n2)*HID + k] = f2b(ldp(W, (size_t)(l*HID + k)*HID + n2, f));
}

// ---------------- GEMM: hh = h @ W, MFMA 16x16x32 bf16, register-resident B ----------------
__global__ __launch_bounds__(256) void k_gemm(const u16* __restrict__ h,
    const u16* __restrict__ WT, u16* __restrict__ hh){
  int wave = threadIdx.x >> 6, lane = threadIdx.x & 63;
  int m = lane & 15, quad = lane >> 4;

  short8 B[4][8];
  #pragma unroll
  for (int j = 0; j < 4; ++j){
    const u16* wp = WT + (size_t)((wave*4 + j)*16 + m)*HID + quad*8;
    #pragma unroll
    for (int ks = 0; ks < 8; ++ks)
      B[j][ks] = *(const short8*)(wp + ks*32);
  }

  for (int t = blockIdx.x; t < NROWT; t += gridDim.x){
    int r0 = t*16;
    const u16* ap = h + (size_t)(r0 + m)*HID + quad*8;
    short8 A[8];
    #pragma unroll
    for (int ks = 0; ks < 8; ++ks)
      A[ks] = *(const short8*)(ap + ks*32);

    f32x4 acc[4];
    #pragma unroll
    for (int j = 0; j < 4; ++j) acc[j] = (f32x4){0.f,0.f,0.f,0.f};
    #pragma unroll
    for (int ks = 0; ks < 8; ++ks){
      #pragma unroll
      for (int j = 0; j < 4; ++j)
        acc[j] = __builtin_amdgcn_mfma_f32_16x16x32_bf16(A[ks], B[j][ks], acc[j], 0, 0, 0);
    }

    #pragma unroll
    for (int j = 0; j < 4; ++j){
      int col = (wave*4 + j)*16 + m;
      #pragma unroll
      for (int r = 0; r < 4; ++r){
        int orow = r0 + quad*4 + r;
        hh[(size_t)orow*HID + col] = f2b(acc[j][r]);
      }
    }
  }
}

// ---------------- per-head scores (blocks 0..127 also zero BN partials) ----------------
__global__ __launch_bounds__(256) void k_scores(const u16* __restrict__ hh,
    const void* __restrict__ asrc, const void* __restrict__ adst,
    float* __restrict__ ssrc, float* __restrict__ sdst, int H,
    const int* __restrict__ flagp, int loff,
    float* __restrict__ bnpart){
  if (blockIdx.x < NPART*2) bnpart[blockIdx.x*256 + threadIdx.x] = 0.f;  // 64*512 floats
  int f = *flagp;
  int wid = threadIdx.x >> 6, lane = threadIdx.x & 63;
  int n = blockIdx.x*4 + wid;
  if (n >= N_NODESC) return;
  int f0 = lane*4;
  const u16x4 hv = *(const u16x4*)(hh + (size_t)n*HID + f0);
  float ps = 0.f, pd = 0.f;
  #pragma unroll
  for (int j = 0; j < 4; ++j){
    float hvf = b2f(hv[j]);
    ps += hvf * ldp(asrc, (size_t)loff + f0 + j, f);
    pd += hvf * ldp(adst, (size_t)loff + f0 + j, f);
  }
  if (H == 8){
    #pragma unroll
    for (int o = 1; o < 8; o <<= 1){ ps += __shfl_xor(ps, o); pd += __shfl_xor(pd, o); }
    if ((lane & 7) == 0){ ssrc[n*8 + (lane>>3)] = ps; sdst[n*8 + (lane>>3)] = pd; }
  } else {
    #pragma unroll
    for (int o = 1; o < 64; o <<= 1){ ps += __shfl_xor(ps, o); pd += __shfl_xor(pd, o); }
    if (lane == 0){ ssrc[n] = ps; sdst[n] = pd; }
  }
}

// ---------------- attention core: online softmax aggregate, 1-deep prefetch pipeline ----------------
// gat_bias dropped: per-channel constant cancels exactly inside BatchNorm.
__device__ __forceinline__ void attn_node(int n, int lane, const u16* __restrict__ hh,
    const float* __restrict__ ssrc, const float* __restrict__ sdst,
    const int* __restrict__ soff, const int* __restrict__ ssorted, int H, float r[4]){
  int f0 = lane*4;
  int hl = (H == 8) ? (lane >> 3) : 0;
  float sd = sdst[n*H + hl];
  int beg = soff[n], end = soff[n+1];
  if (beg < 0) beg = 0;
  if (end > E_TOT) end = E_TOT;
  r[0] = r[1] = r[2] = r[3] = 0.f;
  if (beg >= end) return;
  int src = ssorted[beg];
  if ((unsigned)src >= N_NODESC) src = n;   // poison guard (unreachable in practice)
  u16x4 hvv = *(const u16x4*)(hh + (size_t)src*HID + f0);
  float es = ssrc[src*H + hl];
  float mval = -1e30f, lval = 0.f;
  float o0 = 0.f, o1 = 0.f, o2 = 0.f, o3 = 0.f;
  for (int i = beg; i < end; ++i){
    int nsrc = src;
    if (i + 1 < end){
      nsrc = ssorted[i+1];
      if ((unsigned)nsrc >= N_NODESC) nsrc = src;
    }
    const u16x4 nh = *(const u16x4*)(hh + (size_t)nsrc*HID + f0);   // prefetch next row
    const float nes = ssrc[nsrc*H + hl];
    float ev = es + sd;
    ev = (ev > 0.f) ? ev : NEG_SLOPE*ev;
    float nm = fmaxf(mval, ev);
    float scv = __expf(mval - nm);
    float wv = __expf(ev - nm);
    lval = lval*scv + wv;
    o0 = o0*scv + wv*b2f(hvv[0]);
    o1 = o1*scv + wv*b2f(hvv[1]);
    o2 = o2*scv + wv*b2f(hvv[2]);
    o3 = o3*scv + wv*b2f(hvv[3]);
    mval = nm;
    hvv = nh; es = nes;
  }
  float inv = (lval > 0.f) ? 1.f/lval : 0.f;
  r[0] = o0*inv; r[1] = o1*inv; r[2] = o2*inv; r[3] = o3*inv;
}

// Tier A: grid-stride attention, gout write + register-accumulated BN stats (1 atomic set/block)
__global__ __launch_bounds__(256) void k_attn_gout(const u16* __restrict__ hh,
    const float* __restrict__ ssrc, const float* __restrict__ sdst,
    const int* __restrict__ soff, const int* __restrict__ ssorted,
    u16* __restrict__ gout, int H, float* __restrict__ bnpart){
  __shared__ float lsum[4*HID];
  __shared__ float lsq[4*HID];
  int wid = threadIdx.x >> 6, lane = threadIdx.x & 63;
  int f0 = lane*4;
  float s[4] = {0.f,0.f,0.f,0.f}, q[4] = {0.f,0.f,0.f,0.f};
  int gw = blockIdx.x*4 + wid;
  int nw = gridDim.x*4;
  for (int n = gw; n < N_NODESC; n += nw){
    float r[4];
    attn_node(n, lane, hh, ssrc, sdst, soff, ssorted, H, r);
    u16x4 o;
    #pragma unroll
    for (int j = 0; j < 4; ++j){
      o[j] = f2b(r[j]);
      s[j] += r[j];
      q[j] += r[j]*r[j];
    }
    *(u16x4*)(gout + (size_t)n*HID + f0) = o;
  }
  #pragma unroll
  for (int j = 0; j < 4; ++j){
    lsum[wid*HID + f0 + j] = s[j];
    lsq [wid*HID + f0 + j] = q[j];
  }
  __syncthreads();
  int c = threadIdx.x;
  float ts = lsum[c] + lsum[HID+c] + lsum[2*HID+c] + lsum[3*HID+c];
  float tq = lsq[c]  + lsq[HID+c]  + lsq[2*HID+c]  + lsq[3*HID+c];
  float* prow = bnpart + (size_t)(blockIdx.x & (NPART-1))*512;
  atomicAdd(&prow[c], ts);
  atomicAdd(&prow[HID + c], tq);
}

// Tier B pass 1: recompute attention, block-reduce BN stats into partials
__global__ __launch_bounds__(256) void k_attn_stats(const u16* __restrict__ hh,
    const float* __restrict__ ssrc, const float* __restrict__ sdst,
    const int* __restrict__ soff, const int* __restrict__ ssorted,
    float* __restrict__ bnpart, int H){
  __shared__ float lsum[4*HID];
  __shared__ float lsq[4*HID];
  int wid = threadIdx.x >> 6, lane = threadIdx.x & 63;
  int gw = blockIdx.x*4 + wid;
  int nw = gridDim.x*4;
  float s[4] = {0.f,0.f,0.f,0.f}, q[4] = {0.f,0.f,0.f,0.f};
  for (int n = gw; n < N_NODESC; n += nw){
    float r[4];
    attn_node(n, lane, hh, ssrc, sdst, soff, ssorted, H, r);
    #pragma unroll
    for (int j = 0; j < 4; ++j){ s[j] += r[j]; q[j] += r[j]*r[j]; }
  }
  int f0 = lane*4;
  #pragma unroll
  for (int j = 0; j < 4; ++j){ lsum[wid*HID + f0 + j] = s[j]; lsq[wid*HID + f0 + j] = q[j]; }
  __syncthreads();
  int c = threadIdx.x;
  float ts = lsum[c] + lsum[HID+c] + lsum[2*HID+c] + lsum[3*HID+c];
  float tq = lsq[c]  + lsq[HID+c]  + lsq[2*HID+c]  + lsq[3*HID+c];
  float* prow = bnpart + (size_t)(blockIdx.x & (NPART-1))*512;
  atomicAdd(&prow[c], ts);
  atomicAdd(&prow[HID + c], tq);
}

// Tier B pass 2: recompute attention, fused BN+ReLU+residual into h
__global__ __launch_bounds__(256) void k_attn_apply(const u16* __restrict__ hh,
    const float* __restrict__ ssrc, const float* __restrict__ sdst,
    const int* __restrict__ soff, const int* __restrict__ ssorted,
    const float* __restrict__ scale, const float* __restrict__ shift,
    u16* __restrict__ h, int H){
  int wid = threadIdx.x >> 6, lane = threadIdx.x & 63;
  int n = blockIdx.x*4 + wid;
  if (n >= N_NODESC) return;
  float r[4];
  attn_node(n, lane, hh, ssrc, sdst, soff, ssorted, H, r);
  int f0 = lane*4;
  const f32x4 sc = *(const f32x4*)(scale + f0);
  const f32x4 sh = *(const f32x4*)(shift + f0);
  u16x4 hv = *(u16x4*)(h + (size_t)n*HID + f0);
  u16x4 o;
  #pragma unroll
  for (int j = 0; j < 4; ++j){
    float t = r[j]*sc[j] + sh[j];
    t = (t > 0.f) ? t : 0.f;
    o[j] = f2b(b2f(hv[j]) + t);
  }
  *(u16x4*)(h + (size_t)n*HID + f0) = o;
}

// ---------------- BN finalize: reduce 64 partial rows -> scale/shift ----------------
__global__ __launch_bounds__(256) void k_bn_final(const float* __restrict__ bnpart,
    const void* __restrict__ gamma, const void* __restrict__ beta,
    float* __restrict__ scale, float* __restrict__ shift,
    const int* __restrict__ flagp, int loff){
  int f = *flagp;
  int c = threadIdx.x;
  float s = 0.f, q = 0.f;
  #pragma unroll 4
  for (int p = 0; p < NPART; ++p){
    s += bnpart[(size_t)p*512 + c];
    q += bnpart[(size_t)p*512 + HID + c];
  }
  float mu  = s * (1.f/N_NODESC);
  float var = q * (1.f/N_NODESC) - mu*mu;
  if (!(var >= 0.f)) var = 0.f;   // also catches NaN
  float sc = ldp(gamma, (size_t)loff + c, f) * rsqrtf(var + BN_EPSC);
  scale[c] = sc;
  shift[c] = ldp(beta, (size_t)loff + c, f) - mu*sc;
}

// Tier A: h += relu(bn(gout))  (layers 0..2; layer 3 fused into k_pool_fused)
__global__ __launch_bounds__(256) void k_bn_apply(const u16* __restrict__ g,
    const float* __restrict__ scale, const float* __restrict__ shift, u16* __restrict__ h){
  int idx = blockIdx.x*256 + threadIdx.x;           // N*HID/4 total
  int c4 = (idx & 63) * 4;
  const u16x4 gv = *(const u16x4*)(g + (size_t)idx*4);
  const f32x4 sc = *(const f32x4*)(scale + c4);
  const f32x4 sh = *(const f32x4*)(shift + c4);
  u16x4 hv = *(u16x4*)(h + (size_t)idx*4);
  u16x4 o;
  #pragma unroll
  for (int j = 0; j < 4; ++j){
    float t = b2f(gv[j])*sc[j] + sh[j];
    t = (t > 0.f) ? t : 0.f;
    o[j] = f2b(b2f(hv[j]) + t);
  }
  *(u16x4*)(h + (size_t)idx*4) = o;
}

// ---------------- mean pool per graph (Tier B; batch sorted, counts fused) ----------------
__global__ __launch_bounds__(256) void k_pool(const u16* __restrict__ h,
    const int* __restrict__ batch, float* __restrict__ gsum, int* __restrict__ gcnt){
  int c = threadIdx.x;
  int r0 = blockIdx.x * 256;
  int r1 = min(r0 + 256, N_NODESC);
  if (r0 >= N_NODESC) return;
  int cur = batch[r0];
  float acc = 0.f;
  int nacc = 0;
  for (int r = r0; r < r1; ++r){
    int b = batch[r];
    if ((unsigned)b >= NGRAPHS) continue;
    if (b != cur){
      if ((unsigned)cur < NGRAPHS){
        atomicAdd(&gsum[cur*HID + c], acc);
        if (c == 0) atomicAdd(&gcnt[cur], nacc);
      }
      acc = 0.f; nacc = 0; cur = b;
    }
    acc += b2f(h[(size_t)r*HID + c]);
    nacc++;
  }
  if ((unsigned)cur < NGRAPHS){
    atomicAdd(&gsum[cur*HID + c], acc);
    if (c == 0) atomicAdd(&gcnt[cur], nacc);
  }
}

// Tier A: pool fused with last layer's BN+ReLU+residual (h_final never materialized)
__global__ __launch_bounds__(256) void k_pool_fused(const u16* __restrict__ h,
    const u16* __restrict__ gout, const float* __restrict__ scale, const float* __restrict__ shift,
    const int* __restrict__ batch, float* __restrict__ gsum, int* __restrict__ gcnt){
  int c = threadIdx.x;
  int r0 = blockIdx.x * 256;
  int r1 = min(r0 + 256, N_NODESC);
  if (r0 >= N_NODESC) return;
  float sc = scale[c], sh = shift[c];
  int cur = batch[r0];
  float acc = 0.f;
  int nacc = 0;
  for (int r = r0; r < r1; ++r){
    int b = batch[r];
    if ((unsigned)b >= NGRAPHS) continue;
    if (b != cur){
      if ((unsigned)cur < NGRAPHS){
        atomicAdd(&gsum[cur*HID + c], acc);
        if (c == 0) atomicAdd(&gcnt[cur], nacc);
      }
      acc = 0.f; nacc = 0; cur = b;
    }
    float t = b2f(gout[(size_t)r*HID + c])*sc + sh;
    t = (t > 0.f) ? t : 0.f;
    acc += b2f(h[(size_t)r*HID + c]) + t;
    nacc++;
  }
  if ((unsigned)cur < NGRAPHS){
    atomicAdd(&gsum[cur*HID + c], acc);
    if (c == 0) atomicAdd(&gcnt[cur], nacc);
  }
}

// ---------------- G prep: mean-divide and convert to bf16 (64 KB, L2-resident) ----------------
__global__ __launch_bounds__(256) void k_gprep(const float* __restrict__ gsum,
    const int* __restrict__ gcnt, u16* __restrict__ gbf){
  int g = blockIdx.x, c = threadIdx.x;
  int cc = gcnt[g]; if (cc < 1) cc = 1;
  gbf[g*HID + c] = f2b(gsum[(size_t)g*HID + c] * (1.f/(float)cc));
}

// ---------------- token predictors: MFMA GEMM  preds[s] = G[128,256] @ W_s[256,5002] ----------------
__global__ __launch_bounds__(256) void k_pred(const u16* __restrict__ gbf,
    const void* __restrict__ tokW, const void* __restrict__ tokb, void* __restrict__ out,
    const int* __restrict__ flagp){
  int f = *flagp;
  int wave = threadIdx.x >> 6, lane = threadIdx.x & 63;
  int m = lane & 15, quad = lane >> 4;
  int s = blockIdx.y;
  int v = blockIdx.x*64 + wave*16 + m;       // this lane's vocab column
  bool vok = (v < VOCABC);

  f32x4 acc[8];
  #pragma unroll
  for (int t = 0; t < 8; ++t) acc[t] = (f32x4){0.f,0.f,0.f,0.f};

  const size_t wrow = (size_t)s*HID*VOCABC + v;
  #pragma unroll
  for (int ks = 0; ks < 8; ++ks){
    int kb = ks*32 + quad*8;
    short8 b;
    #pragma unroll
    for (int j = 0; j < 8; ++j)
      b[j] = vok ? (short)f2b(ldp(tokW, wrow + (size_t)(kb + j)*VOCABC, f)) : (short)0;
    #pragma unroll
    for (int t = 0; t < 8; ++t){
      const short8 a = *(const short8*)(gbf + (size_t)(t*16 + m)*HID + kb);
      acc[t] = __builtin_amdgcn_mfma_f32_16x16x32_bf16(a, b, acc[t], 0, 0, 0);
    }
  }

  float bb = vok ? ldp(tokb, (size_t)s*VOCABC + v, f) : 0.f;
  if (!vok) return;
  #pragma unroll
  for (int t = 0; t < 8; ++t){
    #pragma unroll
    for (int r = 0; r < 4; ++r){
      int grow = t*16 + quad*4 + r;
      float val = acc[t][r] + bb;
      size_t oi = ((size_t)(s*NGRAPHS + grow)*VOCABC) + v;
      if (f) ((float*)out)[oi] = val;
      else   ((u16*)out)[oi]   = f2b(val);
    }
  }
}

// ---------------- host launcher ----------------
extern "C" void kernel_launch(void* const* d_in, const int* in_sizes, int n_in,
                              void* d_out, int out_size, void* d_ws, size_t ws_size,
                              hipStream_t stream) {
  const int* x          = (const int*)d_in[0];
  const int* node_depth = (const int*)d_in[1];
  const int* edge_index = (const int*)d_in[2];
  const int* batch      = (const int*)d_in[3];
  const void* type_emb  = d_in[4];
  const void* attr_emb  = d_in[5];
  const void* depth_emb = d_in[6];
  const void* Ws        = d_in[7];
  const void* att_src   = d_in[8];
  const void* att_dst   = d_in[9];
  // d_in[10] = gat_bias: dropped (constant per channel cancels inside BatchNorm)
  const void* bn_gamma  = d_in[11];
  const void* bn_beta   = d_in[12];
  const void* tok_W     = d_in[13];
  const void* tok_b     = d_in[14];

  // ---- workspace carve ----
  char* base = (char*)d_ws;
  size_t off = 0;
  auto carve = [&](size_t bytes) -> void* {
    void* p = base + off;
    off += (bytes + 255) & ~(size_t)255;
    return p;
  };
  u16*   h     = (u16*)carve((size_t)N_NODESC*HID*2);     // 51.2 MB
  u16*   hh    = (u16*)carve((size_t)N_NODESC*HID*2);     // 51.2 MB
  float* ssrc  = (float*)carve((size_t)N_NODESC*8*4);     // 3.2 MB
  float* sdst  = (float*)carve((size_t)N_NODESC*8*4);     // 3.2 MB
  int*   soff  = (int*)carve((size_t)(N_NODESC+1)*4);
  int*   cursor= (int*)carve((size_t)N_NODESC*4);
  int*   ssorted=(int*)carve((size_t)E_TOT*4);            // 2.0 MB
  int*   btot  = (int*)carve((size_t)NCHUNK*4);
  int*   boff  = (int*)carve((size_t)NCHUNK*4);
  u16*   WT    = (u16*)carve((size_t)NLAYERS*HID*HID*2);  // 0.5 MB
  float* bnpart= (float*)carve((size_t)NPART*512*4);      // 128 KB BN partials
  float* bnscale=(float*)carve(HID*4);
  float* bnshift=(float*)carve(HID*4);
  float* gsum  = (float*)carve((size_t)NGRAPHS*HID*4);    // 128 KB
  int*   gcnt  = (int*)carve((size_t)NGRAPHS*4);          // adjacent to gsum
  u16*   gbf   = (u16*)carve((size_t)NGRAPHS*HID*2);      // 64 KB bf16 pooled graphs
  int*   dflag = (int*)carve(256);
  size_t common = off;
  u16*   gout  = (u16*)carve((size_t)N_NODESC*HID*2);     // +51.2 MB
  const bool useGout = (off <= ws_size);
  if (common > ws_size) return;  // cannot run at all

  const int EB  = (E_TOT + 255)/256;
  const int NB4 = (N_NODESC + 3)/4;      // wave-per-node kernels

  // dtype detection first
  k_detect<<<1, 64, 0, stream>>>(type_emb, dflag);

  // setup (k_embed also zeroes cursor)
  k_embed<<<N_NODESC, 256, 0, stream>>>(x, node_depth, type_emb, attr_emb, depth_emb, h, dflag, cursor);
  k_transW<<<dim3(256, NLAYERS), 256, 0, stream>>>(Ws, WT, dflag);
  k_hist<<<EB, 256, 0, stream>>>(edge_index, cursor);
  k_scan_part<<<NCHUNK, 256, 0, stream>>>(cursor, soff, btot);
  k_scan_tot<<<1, 256, 0, stream>>>(btot, boff, soff + N_NODESC);
  k_scan_add<<<NCHUNK, 256, 0, stream>>>(soff, boff, cursor);   // also zeroes cursor
  k_scatter<<<EB, 256, 0, stream>>>(edge_index, soff, cursor, ssorted);

  // layers
  for (int l = 0; l < NLAYERS; ++l){
    int H = (l == NLAYERS-1) ? 1 : 8;
    k_gemm<<<1024, 256, 0, stream>>>(h, WT + (size_t)l*HID*HID, hh);
    k_scores<<<NB4, 256, 0, stream>>>(hh, att_src, att_dst, ssrc, sdst, H, dflag, l*HID, bnpart);
    if (useGout){
      k_attn_gout<<<ATTNB, 256, 0, stream>>>(hh, ssrc, sdst, soff, ssorted, gout, H, bnpart);
      k_bn_final<<<1, 256, 0, stream>>>(bnpart, bn_gamma, bn_beta, bnscale, bnshift, dflag, l*HID);
      if (l < NLAYERS-1)
        k_bn_apply<<<(N_NODESC*HID/4)/256, 256, 0, stream>>>(gout, bnscale, bnshift, h);
    } else {
      k_attn_stats<<<2048, 256, 0, stream>>>(hh, ssrc, sdst, soff, ssorted, bnpart, H);
      k_bn_final<<<1, 256, 0, stream>>>(bnpart, bn_gamma, bn_beta, bnscale, bnshift, dflag, l*HID);
      k_attn_apply<<<NB4, 256, 0, stream>>>(hh, ssrc, sdst, soff, ssorted, bnscale, bnshift, h, H);
    }
  }

  // pool (gsum+gcnt adjacent -> single zero launch)
  k_zero<<<(NGRAPHS*HID + NGRAPHS + 255)/256, 256, 0, stream>>>((int*)gsum, NGRAPHS*HID + NGRAPHS);
  if (useGout)
    k_pool_fused<<<NCHUNK, 256, 0, stream>>>(h, gout, bnscale, bnshift, batch, gsum, gcnt);
  else
    k_pool<<<NCHUNK, 256, 0, stream>>>(h, batch, gsum, gcnt);
  k_gprep<<<NGRAPHS, 256, 0, stream>>>(gsum, gcnt, gbf);

  // predictors (MFMA GEMM)
  k_pred<<<dim3(NVQ, SEQLEN), 256, 0, stream>>>(gbf, tok_W, tok_b, d_out, dflag);
}

// Round 11
// 985.506 us; speedup vs baseline: 2.6237x; 1.0781x over previous
//
#include <hip/hip_runtime.h>
#include <stdint.h>

typedef uint16_t u16;
typedef uint32_t u32;

#define N_NODESC 100000
#define N_EDGESC 400000
#define E_TOT    500000   // edges + self loops
#define HID      256
#define NLAYERS  4
#define NGRAPHS  128
#define SEQLEN   5
#define VOCABC   5002
#define MAXDEPTH 20
#define NEG_SLOPE 0.2f
#define BN_EPSC  1e-5f
#define NCHUNK   ((N_NODESC + 255)/256)   // 391
#define NCH64    ((N_NODESC + 63)/64)     // 1563 (64-row chunks)
#define NROWT    (N_NODESC/16)            // 6250 row tiles, exact
#define NPART    64                       // BN partial rows (each 512 floats: 256 sum + 256 sq)
#define NVQ      ((VOCABC + 63)/64)       // 79 vocab quads for k_pred
#define ATTNB    2048                     // grid for k_attn_gout

typedef __attribute__((ext_vector_type(8))) short short8;
typedef __attribute__((ext_vector_type(4))) float f32x4;
typedef __attribute__((ext_vector_type(4))) unsigned short u16x4;

__device__ __forceinline__ float b2f(u16 u){
  union { u32 i; float f; } v; v.i = ((u32)u) << 16; return v.f;
}
__device__ __forceinline__ u16 f2b(float f){
  union { float f; u32 i; } v; v.f = f;
  u32 u = v.i;
  u += 0x7FFFu + ((u >> 16) & 1u);   // RNE
  return (u16)(u >> 16);
}
// dual-dtype parameter load: flag=1 -> f32, flag=0 -> bf16
__device__ __forceinline__ float ldp(const void* p, size_t i, int f){
  return f ? ((const float*)p)[i] : b2f(((const u16*)p)[i]);
}
// 4-wide dual-dtype load (i must be 4-element aligned)
__device__ __forceinline__ f32x4 ld4(const void* p, size_t i, int f){
  f32x4 r;
  if (f){
    r = *(const f32x4*)((const float*)p + i);
  } else {
    const u16x4 u = *(const u16x4*)((const u16*)p + i);
    r[0] = b2f(u[0]); r[1] = b2f(u[1]); r[2] = b2f(u[2]); r[3] = b2f(u[3]);
  }
  return r;
}

// ---------------- dtype detector: sample type_emb both ways ----------------
__global__ __launch_bounds__(64) void k_detect(const void* temb, int* flag){
  int lane = threadIdx.x;
  const u32* w32 = (const u32*)temb;
  int sf = 0, sb = 0;
  for (int i = lane; i < 256; i += 64){
    u32 w = w32[i];
    union { u32 u; float f; } cf; cf.u = w;
    float af = fabsf(cf.f);
    if (cf.f == 0.0f || (af >= 1e-12f && af <= 4096.f)) sf++;
    float b0 = b2f((u16)(w & 0xFFFFu));
    float b1 = b2f((u16)(w >> 16));
    float a0 = fabsf(b0), a1 = fabsf(b1);
    if (b0 == 0.f || (a0 >= 1e-12f && a0 <= 4096.f)) sb++;
    if (b1 == 0.f || (a1 >= 1e-12f && a1 <= 4096.f)) sb++;
  }
  #pragma unroll
  for (int o = 1; o < 64; o <<= 1){ sf += __shfl_xor(sf, o); sb += __shfl_xor(sb, o); }
  if (lane == 0) *flag = (2*sf > sb) ? 1 : 0;
}

// ---------------- utility ----------------
__global__ __launch_bounds__(256) void k_zero(int* __restrict__ p, int n){
  int i = blockIdx.x*256 + threadIdx.x;
  if (i < n) p[i] = 0;
}

// ---------------- embedding: 64-node chunks, lane owns 4 channels; zeroes cursor ----------------
__global__ __launch_bounds__(256) void k_embed(const int* __restrict__ x, const int* __restrict__ nd,
    const void* __restrict__ temb, const void* __restrict__ aemb, const void* __restrict__ demb,
    u16* __restrict__ h, const int* __restrict__ flagp, int* __restrict__ cursor){
  int f = *flagp;
  int tid = threadIdx.x;
  int r0 = blockIdx.x*64;
  if (tid < 64 && r0 + tid < N_NODESC) cursor[r0 + tid] = 0;
  int wid = tid >> 6, lane = tid & 63;
  int c4 = lane*4;
  #pragma unroll 4
  for (int k = 0; k < 16; ++k){
    int n = r0 + wid*16 + k;
    if (n >= N_NODESC) break;
    int t = x[n*2+0], a = x[n*2+1];
    if (t < 0) t = 0; if (t > 97) t = 97;
    if (a < 0) a = 0; if (a > 10029) a = 10029;
    int d = nd[n]; if (d > MAXDEPTH) d = MAXDEPTH; if (d < 0) d = 0;
    const f32x4 vt = ld4(temb, (size_t)t*HID + c4, f);
    const f32x4 va = ld4(aemb, (size_t)a*HID + c4, f);
    const f32x4 vd = ld4(demb, (size_t)d*HID + c4, f);
    u16x4 o;
    #pragma unroll
    for (int j = 0; j < 4; ++j) o[j] = f2b(vt[j] + va[j] + vd[j]);
    *(u16x4*)(h + (size_t)n*HID + c4) = o;
  }
}

// ---------------- edge sort by dst (counting sort) ----------------
__global__ __launch_bounds__(256) void k_hist(const int* __restrict__ ei, int* __restrict__ cnt){
  int e = blockIdx.x*256 + threadIdx.x;
  if (e >= E_TOT) return;
  int dst = (e < N_EDGESC) ? ei[N_EDGESC + e] : (e - N_EDGESC);
  if ((unsigned)dst >= N_NODESC) return;
  atomicAdd(&cnt[dst], 1);
}

// hierarchical scan, phase 1: per-256-chunk exclusive scan + chunk total
__global__ __launch_bounds__(256) void k_scan_part(const int* __restrict__ cnt,
    int* __restrict__ off, int* __restrict__ btot){
  __shared__ int lds[256];
  int b = blockIdx.x, tid = threadIdx.x;
  int i = b*256 + tid;
  int v = (i < N_NODESC) ? cnt[i] : 0;
  lds[tid] = v;
  __syncthreads();
  #pragma unroll
  for (int s = 1; s < 256; s <<= 1){
    int t = (tid >= s) ? lds[tid - s] : 0;
    __syncthreads();
    lds[tid] += t;
    __syncthreads();
  }
  if (i < N_NODESC) off[i] = lds[tid] - v;   // chunk-local exclusive
  if (tid == 255) btot[b] = lds[255];
}

// phase 2: scan the 391 chunk totals (1 block), write grand total to offN
__global__ __launch_bounds__(256) void k_scan_tot(const int* __restrict__ btot,
    int* __restrict__ boff, int* __restrict__ offN){
  __shared__ int lds[256];
  __shared__ int s_carry;
  int tid = threadIdx.x;
  if (tid == 0) s_carry = 0;
  __syncthreads();
  for (int base = 0; base < NCHUNK; base += 256){
    int i = base + tid;
    int v = (i < NCHUNK) ? btot[i] : 0;
    lds[tid] = v;
    __syncthreads();
    #pragma unroll
    for (int s = 1; s < 256; s <<= 1){
      int t = (tid >= s) ? lds[tid - s] : 0;
      __syncthreads();
      lds[tid] += t;
      __syncthreads();
    }
    if (i < NCHUNK) boff[i] = s_carry + lds[tid] - v;
    __syncthreads();
    if (tid == 255) s_carry += lds[255];
    __syncthreads();
  }
  if (tid == 0) *offN = s_carry;
}

// phase 3: add chunk offsets; also re-zero cursor for the scatter pass
__global__ __launch_bounds__(256) void k_scan_add(int* __restrict__ off,
    const int* __restrict__ boff, int* __restrict__ cursor){
  int b = blockIdx.x;
  int i = b*256 + threadIdx.x;
  if (i < N_NODESC){ off[i] += boff[b]; cursor[i] = 0; }
}

__global__ __launch_bounds__(256) void k_scatter(const int* __restrict__ ei,
    const int* __restrict__ soff, int* __restrict__ cursor, int* __restrict__ ssorted){
  int e = blockIdx.x*256 + threadIdx.x;
  if (e >= E_TOT) return;
  int src = (e < N_EDGESC) ? ei[e]            : (e - N_EDGESC);
  int dst = (e < N_EDGESC) ? ei[N_EDGESC + e] : (e - N_EDGESC);
  if ((unsigned)dst >= N_NODESC || (unsigned)src >= N_NODESC) return;
  int pos = soff[dst] + atomicAdd(&cursor[dst], 1);
  if ((unsigned)pos < E_TOT) ssorted[pos] = src;
}

// ---------------- W transpose -> bf16 WT, all layers ----------------
__global__ __launch_bounds__(256) void k_transW(const void* __restrict__ W, u16* __restrict__ WT,
    const int* __restrict__ flagp){
  int f = *flagp;
  int l = blockIdx.y, n2 = blockIdx.x, k = threadIdx.x;
  WT[(l*HID + n2)*HID + k] = f2b(ldp(W, (size_t)(l*HID + k)*HID + n2, f));
}

// ---------------- GEMM: hh = h @ W, MFMA 16x16x32 bf16, register-resident B ----------------
__global__ __launch_bounds__(256) void k_gemm(const u16* __restrict__ h,
    const u16* __restrict__ WT, u16* __restrict__ hh){
  int wave = threadIdx.x >> 6, lane = threadIdx.x & 63;
  int m = lane & 15, quad = lane >> 4;

  short8 B[4][8];
  #pragma unroll
  for (int j = 0; j < 4; ++j){
    const u16* wp = WT + (size_t)((wave*4 + j)*16 + m)*HID + quad*8;
    #pragma unroll
    for (int ks = 0; ks < 8; ++ks)
      B[j][ks] = *(const short8*)(wp + ks*32);
  }

  for (int t = blockIdx.x; t < NROWT; t += gridDim.x){
    int r0 = t*16;
    const u16* ap = h + (size_t)(r0 + m)*HID + quad*8;
    short8 A[8];
    #pragma unroll
    for (int ks = 0; ks < 8; ++ks)
      A[ks] = *(const short8*)(ap + ks*32);

    f32x4 acc[4];
    #pragma unroll
    for (int j = 0; j < 4; ++j) acc[j] = (f32x4){0.f,0.f,0.f,0.f};
    #pragma unroll
    for (int ks = 0; ks < 8; ++ks){
      #pragma unroll
      for (int j = 0; j < 4; ++j)
        acc[j] = __builtin_amdgcn_mfma_f32_16x16x32_bf16(A[ks], B[j][ks], acc[j], 0, 0, 0);
    }

    #pragma unroll
    for (int j = 0; j < 4; ++j){
      int col = (wave*4 + j)*16 + m;
      #pragma unroll
      for (int r = 0; r < 4; ++r){
        int orow = r0 + quad*4 + r;
        hh[(size_t)orow*HID + col] = f2b(acc[j][r]);
      }
    }
  }
}

// ---------------- per-head scores (blocks 0..127 also zero BN partials) ----------------
__global__ __launch_bounds__(256) void k_scores(const u16* __restrict__ hh,
    const void* __restrict__ asrc, const void* __restrict__ adst,
    float* __restrict__ ssrc, float* __restrict__ sdst, int H,
    const int* __restrict__ flagp, int loff,
    float* __restrict__ bnpart){
  if (blockIdx.x < NPART*2) bnpart[blockIdx.x*256 + threadIdx.x] = 0.f;  // 64*512 floats
  int f = *flagp;
  int wid = threadIdx.x >> 6, lane = threadIdx.x & 63;
  int n = blockIdx.x*4 + wid;
  if (n >= N_NODESC) return;
  int f0 = lane*4;
  const u16x4 hv = *(const u16x4*)(hh + (size_t)n*HID + f0);
  float ps = 0.f, pd = 0.f;
  #pragma unroll
  for (int j = 0; j < 4; ++j){
    float hvf = b2f(hv[j]);
    ps += hvf * ldp(asrc, (size_t)loff + f0 + j, f);
    pd += hvf * ldp(adst, (size_t)loff + f0 + j, f);
  }
  if (H == 8){
    #pragma unroll
    for (int o = 1; o < 8; o <<= 1){ ps += __shfl_xor(ps, o); pd += __shfl_xor(pd, o); }
    if ((lane & 7) == 0){ ssrc[n*8 + (lane>>3)] = ps; sdst[n*8 + (lane>>3)] = pd; }
  } else {
    #pragma unroll
    for (int o = 1; o < 64; o <<= 1){ ps += __shfl_xor(ps, o); pd += __shfl_xor(pd, o); }
    if (lane == 0){ ssrc[n] = ps; sdst[n] = pd; }
  }
}

// ---------------- attention core: online softmax aggregate, 1-deep prefetch pipeline ----------------
// gat_bias dropped: per-channel constant cancels exactly inside BatchNorm.
__device__ __forceinline__ void attn_node(int n, int lane, const u16* __restrict__ hh,
    const float* __restrict__ ssrc, const float* __restrict__ sdst,
    const int* __restrict__ soff, const int* __restrict__ ssorted, int H, float r[4]){
  int f0 = lane*4;
  int hl = (H == 8) ? (lane >> 3) : 0;
  float sd = sdst[n*H + hl];
  int beg = soff[n], end = soff[n+1];
  if (beg < 0) beg = 0;
  if (end > E_TOT) end = E_TOT;
  r[0] = r[1] = r[2] = r[3] = 0.f;
  if (beg >= end) return;
  int src = ssorted[beg];
  if ((unsigned)src >= N_NODESC) src = n;   // poison guard (unreachable in practice)
  u16x4 hvv = *(const u16x4*)(hh + (size_t)src*HID + f0);
  float es = ssrc[src*H + hl];
  float mval = -1e30f, lval = 0.f;
  float o0 = 0.f, o1 = 0.f, o2 = 0.f, o3 = 0.f;
  for (int i = beg; i < end; ++i){
    int nsrc = src;
    if (i + 1 < end){
      nsrc = ssorted[i+1];
      if ((unsigned)nsrc >= N_NODESC) nsrc = src;
    }
    const u16x4 nh = *(const u16x4*)(hh + (size_t)nsrc*HID + f0);   // prefetch next row
    const float nes = ssrc[nsrc*H + hl];
    float ev = es + sd;
    ev = (ev > 0.f) ? ev : NEG_SLOPE*ev;
    float nm = fmaxf(mval, ev);
    float scv = __expf(mval - nm);
    float wv = __expf(ev - nm);
    lval = lval*scv + wv;
    o0 = o0*scv + wv*b2f(hvv[0]);
    o1 = o1*scv + wv*b2f(hvv[1]);
    o2 = o2*scv + wv*b2f(hvv[2]);
    o3 = o3*scv + wv*b2f(hvv[3]);
    mval = nm;
    hvv = nh; es = nes;
  }
  float inv = (lval > 0.f) ? 1.f/lval : 0.f;
  r[0] = o0*inv; r[1] = o1*inv; r[2] = o2*inv; r[3] = o3*inv;
}

// Tier A: grid-stride attention, gout write + register-accumulated BN stats (1 atomic set/block)
__global__ __launch_bounds__(256) void k_attn_gout(const u16* __restrict__ hh,
    const float* __restrict__ ssrc, const float* __restrict__ sdst,
    const int* __restrict__ soff, const int* __restrict__ ssorted,
    u16* __restrict__ gout, int H, float* __restrict__ bnpart){
  __shared__ float lsum[4*HID];
  __shared__ float lsq[4*HID];
  int wid = threadIdx.x >> 6, lane = threadIdx.x & 63;
  int f0 = lane*4;
  float s[4] = {0.f,0.f,0.f,0.f}, q[4] = {0.f,0.f,0.f,0.f};
  int gw = blockIdx.x*4 + wid;
  int nw = gridDim.x*4;
  for (int n = gw; n < N_NODESC; n += nw){
    float r[4];
    attn_node(n, lane, hh, ssrc, sdst, soff, ssorted, H, r);
    u16x4 o;
    #pragma unroll
    for (int j = 0; j < 4; ++j){
      o[j] = f2b(r[j]);
      s[j] += r[j];
      q[j] += r[j]*r[j];
    }
    *(u16x4*)(gout + (size_t)n*HID + f0) = o;
  }
  #pragma unroll
  for (int j = 0; j < 4; ++j){
    lsum[wid*HID + f0 + j] = s[j];
    lsq [wid*HID + f0 + j] = q[j];
  }
  __syncthreads();
  int c = threadIdx.x;
  float ts = lsum[c] + lsum[HID+c] + lsum[2*HID+c] + lsum[3*HID+c];
  float tq = lsq[c]  + lsq[HID+c]  + lsq[2*HID+c]  + lsq[3*HID+c];
  float* prow = bnpart + (size_t)(blockIdx.x & (NPART-1))*512;
  atomicAdd(&prow[c], ts);
  atomicAdd(&prow[HID + c], tq);
}

// Tier B pass 1: recompute attention, block-reduce BN stats into partials
__global__ __launch_bounds__(256) void k_attn_stats(const u16* __restrict__ hh,
    const float* __restrict__ ssrc, const float* __restrict__ sdst,
    const int* __restrict__ soff, const int* __restrict__ ssorted,
    float* __restrict__ bnpart, int H){
  __shared__ float lsum[4*HID];
  __shared__ float lsq[4*HID];
  int wid = threadIdx.x >> 6, lane = threadIdx.x & 63;
  int gw = blockIdx.x*4 + wid;
  int nw = gridDim.x*4;
  float s[4] = {0.f,0.f,0.f,0.f}, q[4] = {0.f,0.f,0.f,0.f};
  for (int n = gw; n < N_NODESC; n += nw){
    float r[4];
    attn_node(n, lane, hh, ssrc, sdst, soff, ssorted, H, r);
    #pragma unroll
    for (int j = 0; j < 4; ++j){ s[j] += r[j]; q[j] += r[j]*r[j]; }
  }
  int f0 = lane*4;
  #pragma unroll
  for (int j = 0; j < 4; ++j){ lsum[wid*HID + f0 + j] = s[j]; lsq[wid*HID + f0 + j] = q[j]; }
  __syncthreads();
  int c = threadIdx.x;
  float ts = lsum[c] + lsum[HID+c] + lsum[2*HID+c] + lsum[3*HID+c];
  float tq = lsq[c]  + lsq[HID+c]  + lsq[2*HID+c]  + lsq[3*HID+c];
  float* prow = bnpart + (size_t)(blockIdx.x & (NPART-1))*512;
  atomicAdd(&prow[c], ts);
  atomicAdd(&prow[HID + c], tq);
}

// Tier B pass 2: recompute attention, fused BN+ReLU+residual into h
__global__ __launch_bounds__(256) void k_attn_apply(const u16* __restrict__ hh,
    const float* __restrict__ ssrc, const float* __restrict__ sdst,
    const int* __restrict__ soff, const int* __restrict__ ssorted,
    const float* __restrict__ scale, const float* __restrict__ shift,
    u16* __restrict__ h, int H){
  int wid = threadIdx.x >> 6, lane = threadIdx.x & 63;
  int n = blockIdx.x*4 + wid;
  if (n >= N_NODESC) return;
  float r[4];
  attn_node(n, lane, hh, ssrc, sdst, soff, ssorted, H, r);
  int f0 = lane*4;
  const f32x4 sc = *(const f32x4*)(scale + f0);
  const f32x4 sh = *(const f32x4*)(shift + f0);
  u16x4 hv = *(u16x4*)(h + (size_t)n*HID + f0);
  u16x4 o;
  #pragma unroll
  for (int j = 0; j < 4; ++j){
    float t = r[j]*sc[j] + sh[j];
    t = (t > 0.f) ? t : 0.f;
    o[j] = f2b(b2f(hv[j]) + t);
  }
  *(u16x4*)(h + (size_t)n*HID + f0) = o;
}

// ---------------- BN finalize: reduce 64 partial rows -> scale/shift ----------------
__global__ __launch_bounds__(256) void k_bn_final(const float* __restrict__ bnpart,
    const void* __restrict__ gamma, const void* __restrict__ beta,
    float* __restrict__ scale, float* __restrict__ shift,
    const int* __restrict__ flagp, int loff){
  int f = *flagp;
  int c = threadIdx.x;
  float s = 0.f, q = 0.f;
  #pragma unroll 4
  for (int p = 0; p < NPART; ++p){
    s += bnpart[(size_t)p*512 + c];
    q += bnpart[(size_t)p*512 + HID + c];
  }
  float mu  = s * (1.f/N_NODESC);
  float var = q * (1.f/N_NODESC) - mu*mu;
  if (!(var >= 0.f)) var = 0.f;   // also catches NaN
  float sc = ldp(gamma, (size_t)loff + c, f) * rsqrtf(var + BN_EPSC);
  scale[c] = sc;
  shift[c] = ldp(beta, (size_t)loff + c, f) - mu*sc;
}

// Tier A: h += relu(bn(gout))  (layers 0..2; layer 3 fused into k_pool_fused)
__global__ __launch_bounds__(256) void k_bn_apply(const u16* __restrict__ g,
    const float* __restrict__ scale, const float* __restrict__ shift, u16* __restrict__ h){
  int idx = blockIdx.x*256 + threadIdx.x;           // N*HID/4 total
  int c4 = (idx & 63) * 4;
  const u16x4 gv = *(const u16x4*)(g + (size_t)idx*4);
  const f32x4 sc = *(const f32x4*)(scale + c4);
  const f32x4 sh = *(const f32x4*)(shift + c4);
  u16x4 hv = *(u16x4*)(h + (size_t)idx*4);
  u16x4 o;
  #pragma unroll
  for (int j = 0; j < 4; ++j){
    float t = b2f(gv[j])*sc[j] + sh[j];
    t = (t > 0.f) ? t : 0.f;
    o[j] = f2b(b2f(hv[j]) + t);
  }
  *(u16x4*)(h + (size_t)idx*4) = o;
}

// ---------------- mean pool per graph (Tier B; batch sorted, counts fused) ----------------
__global__ __launch_bounds__(256) void k_pool(const u16* __restrict__ h,
    const int* __restrict__ batch, float* __restrict__ gsum, int* __restrict__ gcnt){
  int c = threadIdx.x;
  int r0 = blockIdx.x * 256;
  int r1 = min(r0 + 256, N_NODESC);
  if (r0 >= N_NODESC) return;
  int cur = batch[r0];
  float acc = 0.f;
  int nacc = 0;
  for (int r = r0; r < r1; ++r){
    int b = batch[r];
    if ((unsigned)b >= NGRAPHS) continue;
    if (b != cur){
      if ((unsigned)cur < NGRAPHS){
        atomicAdd(&gsum[cur*HID + c], acc);
        if (c == 0) atomicAdd(&gcnt[cur], nacc);
      }
      acc = 0.f; nacc = 0; cur = b;
    }
    acc += b2f(h[(size_t)r*HID + c]);
    nacc++;
  }
  if ((unsigned)cur < NGRAPHS){
    atomicAdd(&gsum[cur*HID + c], acc);
    if (c == 0) atomicAdd(&gcnt[cur], nacc);
  }
}

// Tier A: pool fused with last layer's BN+ReLU+residual.
// 64-row chunks, 4 waves x 16-row substripes, lane owns 4 channels (u16x4 loads).
__global__ __launch_bounds__(256) void k_pool_fused(const u16* __restrict__ h,
    const u16* __restrict__ gout, const float* __restrict__ scale, const float* __restrict__ shift,
    const int* __restrict__ batch, float* __restrict__ gsum, int* __restrict__ gcnt){
  __shared__ int lb[64];
  int tid = threadIdx.x;
  int r0 = blockIdx.x*64;
  if (tid < 64){
    int rr = r0 + tid;
    lb[tid] = (rr < N_NODESC) ? batch[rr] : -1;
  }
  __syncthreads();
  int wid = tid >> 6, lane = tid & 63;
  int c4 = lane*4;
  const f32x4 sc = *(const f32x4*)(scale + c4);
  const f32x4 sh = *(const f32x4*)(shift + c4);
  int rbase = r0 + wid*16;
  f32x4 acc = (f32x4){0.f,0.f,0.f,0.f};
  int nacc = 0, cur = -1;
  #pragma unroll 4
  for (int k = 0; k < 16; ++k){
    int r = rbase + k;
    if (r >= N_NODESC) break;
    int b = lb[wid*16 + k];
    if ((unsigned)b >= NGRAPHS) continue;
    if (b != cur){
      if ((unsigned)cur < NGRAPHS){
        atomicAdd(&gsum[cur*HID + c4+0], acc[0]);
        atomicAdd(&gsum[cur*HID + c4+1], acc[1]);
        atomicAdd(&gsum[cur*HID + c4+2], acc[2]);
        atomicAdd(&gsum[cur*HID + c4+3], acc[3]);
        if (lane == 0) atomicAdd(&gcnt[cur], nacc);
      }
      acc = (f32x4){0.f,0.f,0.f,0.f}; nacc = 0; cur = b;
    }
    const u16x4 hv = *(const u16x4*)(h    + (size_t)r*HID + c4);
    const u16x4 gv = *(const u16x4*)(gout + (size_t)r*HID + c4);
    #pragma unroll
    for (int j = 0; j < 4; ++j){
      float t = b2f(gv[j])*sc[j] + sh[j];
      t = (t > 0.f) ? t : 0.f;
      acc[j] += b2f(hv[j]) + t;
    }
    nacc++;
  }
  if ((unsigned)cur < NGRAPHS){
    atomicAdd(&gsum[cur*HID + c4+0], acc[0]);
    atomicAdd(&gsum[cur*HID + c4+1], acc[1]);
    atomicAdd(&gsum[cur*HID + c4+2], acc[2]);
    atomicAdd(&gsum[cur*HID + c4+3], acc[3]);
    if (lane == 0) atomicAdd(&gcnt[cur], nacc);
  }
}

// ---------------- G prep: mean-divide and convert to bf16 (64 KB, L2-resident) ----------------
__global__ __launch_bounds__(256) void k_gprep(const float* __restrict__ gsum,
    const int* __restrict__ gcnt, u16* __restrict__ gbf){
  int g = blockIdx.x, c = threadIdx.x;
  int cc = gcnt[g]; if (cc < 1) cc = 1;
  gbf[g*HID + c] = f2b(gsum[(size_t)g*HID + c] * (1.f/(float)cc));
}

// ---------------- token predictors: MFMA GEMM  preds[s] = G[128,256] @ W_s[256,5002] ----------------
__global__ __launch_bounds__(256) void k_pred(const u16* __restrict__ gbf,
    const void* __restrict__ tokW, const void* __restrict__ tokb, void* __restrict__ out,
    const int* __restrict__ flagp){
  int f = *flagp;
  int wave = threadIdx.x >> 6, lane = threadIdx.x & 63;
  int m = lane & 15, quad = lane >> 4;
  int s = blockIdx.y;
  int v = blockIdx.x*64 + wave*16 + m;       // this lane's vocab column
  bool vok = (v < VOCABC);

  f32x4 acc[8];
  #pragma unroll
  for (int t = 0; t < 8; ++t) acc[t] = (f32x4){0.f,0.f,0.f,0.f};

  const size_t wrow = (size_t)s*HID*VOCABC + v;
  #pragma unroll
  for (int ks = 0; ks < 8; ++ks){
    int kb = ks*32 + quad*8;
    short8 b;
    #pragma unroll
    for (int j = 0; j < 8; ++j)
      b[j] = vok ? (short)f2b(ldp(tokW, wrow + (size_t)(kb + j)*VOCABC, f)) : (short)0;
    #pragma unroll
    for (int t = 0; t < 8; ++t){
      const short8 a = *(const short8*)(gbf + (size_t)(t*16 + m)*HID + kb);
      acc[t] = __builtin_amdgcn_mfma_f32_16x16x32_bf16(a, b, acc[t], 0, 0, 0);
    }
  }

  float bb = vok ? ldp(tokb, (size_t)s*VOCABC + v, f) : 0.f;
  if (!vok) return;
  #pragma unroll
  for (int t = 0; t < 8; ++t){
    #pragma unroll
    for (int r = 0; r < 4; ++r){
      int grow = t*16 + quad*4 + r;
      float val = acc[t][r] + bb;
      size_t oi = ((size_t)(s*NGRAPHS + grow)*VOCABC) + v;
      if (f) ((float*)out)[oi] = val;
      else   ((u16*)out)[oi]   = f2b(val);
    }
  }
}

// ---------------- host launcher ----------------
extern "C" void kernel_launch(void* const* d_in, const int* in_sizes, int n_in,
                              void* d_out, int out_size, void* d_ws, size_t ws_size,
                              hipStream_t stream) {
  const int* x          = (const int*)d_in[0];
  const int* node_depth = (const int*)d_in[1];
  const int* edge_index = (const int*)d_in[2];
  const int* batch      = (const int*)d_in[3];
  const void* type_emb  = d_in[4];
  const void* attr_emb  = d_in[5];
  const void* depth_emb = d_in[6];
  const void* Ws        = d_in[7];
  const void* att_src   = d_in[8];
  const void* att_dst   = d_in[9];
  // d_in[10] = gat_bias: dropped (constant per channel cancels inside BatchNorm)
  const void* bn_gamma  = d_in[11];
  const void* bn_beta   = d_in[12];
  const void* tok_W     = d_in[13];
  const void* tok_b     = d_in[14];

  // ---- workspace carve ----
  char* base = (char*)d_ws;
  size_t off = 0;
  auto carve = [&](size_t bytes) -> void* {
    void* p = base + off;
    off += (bytes + 255) & ~(size_t)255;
    return p;
  };
  u16*   h     = (u16*)carve((size_t)N_NODESC*HID*2);     // 51.2 MB
  u16*   hh    = (u16*)carve((size_t)N_NODESC*HID*2);     // 51.2 MB
  float* ssrc  = (float*)carve((size_t)N_NODESC*8*4);     // 3.2 MB
  float* sdst  = (float*)carve((size_t)N_NODESC*8*4);     // 3.2 MB
  int*   soff  = (int*)carve((size_t)(N_NODESC+1)*4);
  int*   cursor= (int*)carve((size_t)N_NODESC*4);
  int*   ssorted=(int*)carve((size_t)E_TOT*4);            // 2.0 MB
  int*   btot  = (int*)carve((size_t)NCHUNK*4);
  int*   boff  = (int*)carve((size_t)NCHUNK*4);
  u16*   WT    = (u16*)carve((size_t)NLAYERS*HID*HID*2);  // 0.5 MB
  float* bnpart= (float*)carve((size_t)NPART*512*4);      // 128 KB BN partials
  float* bnscale=(float*)carve(HID*4);
  float* bnshift=(float*)carve(HID*4);
  float* gsum  = (float*)carve((size_t)NGRAPHS*HID*4);    // 128 KB
  int*   gcnt  = (int*)carve((size_t)NGRAPHS*4);          // adjacent to gsum
  u16*   gbf   = (u16*)carve((size_t)NGRAPHS*HID*2);      // 64 KB bf16 pooled graphs
  int*   dflag = (int*)carve(256);
  size_t common = off;
  u16*   gout  = (u16*)carve((size_t)N_NODESC*HID*2);     // +51.2 MB
  const bool useGout = (off <= ws_size);
  if (common > ws_size) return;  // cannot run at all

  const int EB  = (E_TOT + 255)/256;
  const int NB4 = (N_NODESC + 3)/4;      // wave-per-node kernels

  // dtype detection first
  k_detect<<<1, 64, 0, stream>>>(type_emb, dflag);

  // setup (k_embed also zeroes cursor)
  k_embed<<<NCH64, 256, 0, stream>>>(x, node_depth, type_emb, attr_emb, depth_emb, h, dflag, cursor);
  k_transW<<<dim3(256, NLAYERS), 256, 0, stream>>>(Ws, WT, dflag);
  k_hist<<<EB, 256, 0, stream>>>(edge_index, cursor);
  k_scan_part<<<NCHUNK, 256, 0, stream>>>(cursor, soff, btot);
  k_scan_tot<<<1, 256, 0, stream>>>(btot, boff, soff + N_NODESC);
  k_scan_add<<<NCHUNK, 256, 0, stream>>>(soff, boff, cursor);   // also zeroes cursor
  k_scatter<<<EB, 256, 0, stream>>>(edge_index, soff, cursor, ssorted);

  // layers
  for (int l = 0; l < NLAYERS; ++l){
    int H = (l == NLAYERS-1) ? 1 : 8;
    k_gemm<<<1024, 256, 0, stream>>>(h, WT + (size_t)l*HID*HID, hh);
    k_scores<<<NB4, 256, 0, stream>>>(hh, att_src, att_dst, ssrc, sdst, H, dflag, l*HID, bnpart);
    if (useGout){
      k_attn_gout<<<ATTNB, 256, 0, stream>>>(hh, ssrc, sdst, soff, ssorted, gout, H, bnpart);
      k_bn_final<<<1, 256, 0, stream>>>(bnpart, bn_gamma, bn_beta, bnscale, bnshift, dflag, l*HID);
      if (l < NLAYERS-1)
        k_bn_apply<<<(N_NODESC*HID/4)/256, 256, 0, stream>>>(gout, bnscale, bnshift, h);
    } else {
      k_attn_stats<<<2048, 256, 0, stream>>>(hh, ssrc, sdst, soff, ssorted, bnpart, H);
      k_bn_final<<<1, 256, 0, stream>>>(bnpart, bn_gamma, bn_beta, bnscale, bnshift, dflag, l*HID);
      k_attn_apply<<<NB4, 256, 0, stream>>>(hh, ssrc, sdst, soff, ssorted, bnscale, bnshift, h, H);
    }
  }

  // pool (gsum+gcnt adjacent -> single zero launch)
  k_zero<<<(NGRAPHS*HID + NGRAPHS + 255)/256, 256, 0, stream>>>((int*)gsum, NGRAPHS*HID + NGRAPHS);
  if (useGout)
    k_pool_fused<<<NCH64, 256, 0, stream>>>(h, gout, bnscale, bnshift, batch, gsum, gcnt);
  else
    k_pool<<<NCHUNK, 256, 0, stream>>>(h, batch, gsum, gcnt);
  k_gprep<<<NGRAPHS, 256, 0, stream>>>(gsum, gcnt, gbf);

  // predictors (MFMA GEMM)
  k_pred<<<dim3(NVQ, SEQLEN), 256, 0, stream>>>(gbf, tok_W, tok_b, d_out, dflag);
}

// Round 12
// 912.533 us; speedup vs baseline: 2.8335x; 1.0800x over previous
//
#include <hip/hip_runtime.h>
#include <stdint.h>

typedef uint16_t u16;
typedef uint32_t u32;

#define N_NODESC 100000
#define N_EDGESC 400000
#define E_TOT    500000   // edges + self loops
#define HID      256
#define NLAYERS  4
#define NGRAPHS  128
#define SEQLEN   5
#define VOCABC   5002
#define MAXDEPTH 20
#define NEG_SLOPE 0.2f
#define BN_EPSC  1e-5f
#define NCHUNK   ((N_NODESC + 255)/256)   // 391
#define NCH64    ((N_NODESC + 63)/64)     // 1563 (64-row chunks)
#define NROWT    (N_NODESC/16)            // 6250 row tiles, exact
#define NPART    64                       // BN partial rows (each 512 floats: 256 sum + 256 sq)
#define NVQ      ((VOCABC + 63)/64)       // 79 vocab quads for k_pred
#define ATTNB    2048                     // grid for k_attn_gout
#define LDSROW   264                      // padded LDS row (u16): stride 132 words -> 2-way alias only

typedef __attribute__((ext_vector_type(8))) short short8;
typedef __attribute__((ext_vector_type(4))) float f32x4;
typedef __attribute__((ext_vector_type(4))) unsigned short u16x4;

__device__ __forceinline__ float b2f(u16 u){
  union { u32 i; float f; } v; v.i = ((u32)u) << 16; return v.f;
}
__device__ __forceinline__ u16 f2b(float f){
  union { float f; u32 i; } v; v.f = f;
  u32 u = v.i;
  u += 0x7FFFu + ((u >> 16) & 1u);   // RNE
  return (u16)(u >> 16);
}
// dual-dtype parameter load: flag=1 -> f32, flag=0 -> bf16
__device__ __forceinline__ float ldp(const void* p, size_t i, int f){
  return f ? ((const float*)p)[i] : b2f(((const u16*)p)[i]);
}
// 4-wide dual-dtype load (i must be 4-element aligned)
__device__ __forceinline__ f32x4 ld4(const void* p, size_t i, int f){
  f32x4 r;
  if (f){
    r = *(const f32x4*)((const float*)p + i);
  } else {
    const u16x4 u = *(const u16x4*)((const u16*)p + i);
    r[0] = b2f(u[0]); r[1] = b2f(u[1]); r[2] = b2f(u[2]); r[3] = b2f(u[3]);
  }
  return r;
}

// ---------------- dtype detector: sample type_emb both ways ----------------
__global__ __launch_bounds__(64) void k_detect(const void* temb, int* flag){
  int lane = threadIdx.x;
  const u32* w32 = (const u32*)temb;
  int sf = 0, sb = 0;
  for (int i = lane; i < 256; i += 64){
    u32 w = w32[i];
    union { u32 u; float f; } cf; cf.u = w;
    float af = fabsf(cf.f);
    if (cf.f == 0.0f || (af >= 1e-12f && af <= 4096.f)) sf++;
    float b0 = b2f((u16)(w & 0xFFFFu));
    float b1 = b2f((u16)(w >> 16));
    float a0 = fabsf(b0), a1 = fabsf(b1);
    if (b0 == 0.f || (a0 >= 1e-12f && a0 <= 4096.f)) sb++;
    if (b1 == 0.f || (a1 >= 1e-12f && a1 <= 4096.f)) sb++;
  }
  #pragma unroll
  for (int o = 1; o < 64; o <<= 1){ sf += __shfl_xor(sf, o); sb += __shfl_xor(sb, o); }
  if (lane == 0) *flag = (2*sf > sb) ? 1 : 0;
}

// ---------------- utility ----------------
__global__ __launch_bounds__(256) void k_zero(int* __restrict__ p, int n){
  int i = blockIdx.x*256 + threadIdx.x;
  if (i < n) p[i] = 0;
}

// ---------------- embedding: 64-node chunks, lane owns 4 channels; zeroes cursor ----------------
__global__ __launch_bounds__(256) void k_embed(const int* __restrict__ x, const int* __restrict__ nd,
    const void* __restrict__ temb, const void* __restrict__ aemb, const void* __restrict__ demb,
    u16* __restrict__ h, const int* __restrict__ flagp, int* __restrict__ cursor){
  int f = *flagp;
  int tid = threadIdx.x;
  int r0 = blockIdx.x*64;
  if (tid < 64 && r0 + tid < N_NODESC) cursor[r0 + tid] = 0;
  int wid = tid >> 6, lane = tid & 63;
  int c4 = lane*4;
  #pragma unroll 4
  for (int k = 0; k < 16; ++k){
    int n = r0 + wid*16 + k;
    if (n >= N_NODESC) break;
    int t = x[n*2+0], a = x[n*2+1];
    if (t < 0) t = 0; if (t > 97) t = 97;
    if (a < 0) a = 0; if (a > 10029) a = 10029;
    int d = nd[n]; if (d > MAXDEPTH) d = MAXDEPTH; if (d < 0) d = 0;
    const f32x4 vt = ld4(temb, (size_t)t*HID + c4, f);
    const f32x4 va = ld4(aemb, (size_t)a*HID + c4, f);
    const f32x4 vd = ld4(demb, (size_t)d*HID + c4, f);
    u16x4 o;
    #pragma unroll
    for (int j = 0; j < 4; ++j) o[j] = f2b(vt[j] + va[j] + vd[j]);
    *(u16x4*)(h + (size_t)n*HID + c4) = o;
  }
}

// ---------------- edge sort by dst (counting sort) ----------------
__global__ __launch_bounds__(256) void k_hist(const int* __restrict__ ei, int* __restrict__ cnt){
  int e = blockIdx.x*256 + threadIdx.x;
  if (e >= E_TOT) return;
  int dst = (e < N_EDGESC) ? ei[N_EDGESC + e] : (e - N_EDGESC);
  if ((unsigned)dst >= N_NODESC) return;
  atomicAdd(&cnt[dst], 1);
}

// hierarchical scan, phase 1: per-256-chunk exclusive scan + chunk total
__global__ __launch_bounds__(256) void k_scan_part(const int* __restrict__ cnt,
    int* __restrict__ off, int* __restrict__ btot){
  __shared__ int lds[256];
  int b = blockIdx.x, tid = threadIdx.x;
  int i = b*256 + tid;
  int v = (i < N_NODESC) ? cnt[i] : 0;
  lds[tid] = v;
  __syncthreads();
  #pragma unroll
  for (int s = 1; s < 256; s <<= 1){
    int t = (tid >= s) ? lds[tid - s] : 0;
    __syncthreads();
    lds[tid] += t;
    __syncthreads();
  }
  if (i < N_NODESC) off[i] = lds[tid] - v;   // chunk-local exclusive
  if (tid == 255) btot[b] = lds[255];
}

// phase 2: scan the 391 chunk totals (1 block), write grand total to offN
__global__ __launch_bounds__(256) void k_scan_tot(const int* __restrict__ btot,
    int* __restrict__ boff, int* __restrict__ offN){
  __shared__ int lds[256];
  __shared__ int s_carry;
  int tid = threadIdx.x;
  if (tid == 0) s_carry = 0;
  __syncthreads();
  for (int base = 0; base < NCHUNK; base += 256){
    int i = base + tid;
    int v = (i < NCHUNK) ? btot[i] : 0;
    lds[tid] = v;
    __syncthreads();
    #pragma unroll
    for (int s = 1; s < 256; s <<= 1){
      int t = (tid >= s) ? lds[tid - s] : 0;
      __syncthreads();
      lds[tid] += t;
      __syncthreads();
    }
    if (i < NCHUNK) boff[i] = s_carry + lds[tid] - v;
    __syncthreads();
    if (tid == 255) s_carry += lds[255];
    __syncthreads();
  }
  if (tid == 0) *offN = s_carry;
}

// phase 3: add chunk offsets; also re-zero cursor for the scatter pass
__global__ __launch_bounds__(256) void k_scan_add(int* __restrict__ off,
    const int* __restrict__ boff, int* __restrict__ cursor){
  int b = blockIdx.x;
  int i = b*256 + threadIdx.x;
  if (i < N_NODESC){ off[i] += boff[b]; cursor[i] = 0; }
}

__global__ __launch_bounds__(256) void k_scatter(const int* __restrict__ ei,
    const int* __restrict__ soff, int* __restrict__ cursor, int* __restrict__ ssorted){
  int e = blockIdx.x*256 + threadIdx.x;
  if (e >= E_TOT) return;
  int src = (e < N_EDGESC) ? ei[e]            : (e - N_EDGESC);
  int dst = (e < N_EDGESC) ? ei[N_EDGESC + e] : (e - N_EDGESC);
  if ((unsigned)dst >= N_NODESC || (unsigned)src >= N_NODESC) return;
  int pos = soff[dst] + atomicAdd(&cursor[dst], 1);
  if ((unsigned)pos < E_TOT) ssorted[pos] = src;
}

// ---------------- W transpose -> bf16 WT, all layers ----------------
__global__ __launch_bounds__(256) void k_transW(const void* __restrict__ W, u16* __restrict__ WT,
    const int* __restrict__ flagp){
  int f = *flagp;
  int l = blockIdx.y, n2 = blockIdx.x, k = threadIdx.x;
  WT[(l*HID + n2)*HID + k] = f2b(ldp(W, (size_t)(l*HID + k)*HID + n2, f));
}

// ---------------- GEMM + fused previous-layer BN apply ----------------
// Preamble: block builds h_new (= h + relu(bn(gout)) when doApply) for its 16-row tile
// into LDS (padded row 264 -> 2-way bank alias only) and writes it back to h.
// MFMA loop reads A-frags from LDS; B register-resident as before.
__global__ __launch_bounds__(256) void k_gemm(u16* __restrict__ h,
    const u16* __restrict__ gout, const float* __restrict__ scale,
    const float* __restrict__ shift, int doApply,
    const u16* __restrict__ WT, u16* __restrict__ hh){
  __shared__ u16 hA[16*LDSROW];
  int tid = threadIdx.x;
  int wave = tid >> 6, lane = tid & 63;
  int m = lane & 15, quad = lane >> 4;
  int prow = tid >> 4, pch = (tid & 15)*16;

  short8 B[4][8];
  #pragma unroll
  for (int j = 0; j < 4; ++j){
    const u16* wp = WT + (size_t)((wave*4 + j)*16 + m)*HID + quad*8;
    #pragma unroll
    for (int ks = 0; ks < 8; ++ks)
      B[j][ks] = *(const short8*)(wp + ks*32);
  }

  for (int t = blockIdx.x; t < NROWT; t += gridDim.x){
    int r0 = t*16;
    // preamble: 16 rows x 256 ch; thread owns (row=prow, ch pch..pch+15)
    {
      size_t base = (size_t)(r0 + prow)*HID + pch;
      short8 h0 = *(const short8*)(h + base);
      short8 h1 = *(const short8*)(h + base + 8);
      if (doApply){
        const short8 g0 = *(const short8*)(gout + base);
        const short8 g1 = *(const short8*)(gout + base + 8);
        #pragma unroll
        for (int v = 0; v < 2; ++v){
          const f32x4 sc = *(const f32x4*)(scale + pch + v*4);
          const f32x4 sh = *(const f32x4*)(shift + pch + v*4);
          #pragma unroll
          for (int j = 0; j < 4; ++j){
            float tv = b2f((u16)g0[v*4+j])*sc[j] + sh[j];
            tv = (tv > 0.f) ? tv : 0.f;
            h0[v*4+j] = (short)f2b(b2f((u16)h0[v*4+j]) + tv);
          }
        }
        #pragma unroll
        for (int v = 0; v < 2; ++v){
          const f32x4 sc = *(const f32x4*)(scale + pch + 8 + v*4);
          const f32x4 sh = *(const f32x4*)(shift + pch + 8 + v*4);
          #pragma unroll
          for (int j = 0; j < 4; ++j){
            float tv = b2f((u16)g1[v*4+j])*sc[j] + sh[j];
            tv = (tv > 0.f) ? tv : 0.f;
            h1[v*4+j] = (short)f2b(b2f((u16)h1[v*4+j]) + tv);
          }
        }
        *(short8*)(h + base)     = h0;   // write back h_new (rows uniquely owned)
        *(short8*)(h + base + 8) = h1;
      }
      *(short8*)(&hA[prow*LDSROW + pch])     = h0;
      *(short8*)(&hA[prow*LDSROW + pch + 8]) = h1;
    }
    __syncthreads();

    short8 A[8];
    #pragma unroll
    for (int ks = 0; ks < 8; ++ks)
      A[ks] = *(const short8*)(&hA[m*LDSROW + ks*32 + quad*8]);

    f32x4 acc[4];
    #pragma unroll
    for (int j = 0; j < 4; ++j) acc[j] = (f32x4){0.f,0.f,0.f,0.f};
    #pragma unroll
    for (int ks = 0; ks < 8; ++ks){
      #pragma unroll
      for (int j = 0; j < 4; ++j)
        acc[j] = __builtin_amdgcn_mfma_f32_16x16x32_bf16(A[ks], B[j][ks], acc[j], 0, 0, 0);
    }

    #pragma unroll
    for (int j = 0; j < 4; ++j){
      int col = (wave*4 + j)*16 + m;
      #pragma unroll
      for (int r = 0; r < 4; ++r){
        int orow = r0 + quad*4 + r;
        hh[(size_t)orow*HID + col] = f2b(acc[j][r]);
      }
    }
    __syncthreads();   // protect LDS before next tile's preamble
  }
}

// ---------------- per-head scores (blocks 0..127 also zero BN partials) ----------------
__global__ __launch_bounds__(256) void k_scores(const u16* __restrict__ hh,
    const void* __restrict__ asrc, const void* __restrict__ adst,
    float* __restrict__ ssrc, float* __restrict__ sdst, int H,
    const int* __restrict__ flagp, int loff,
    float* __restrict__ bnpart){
  if (blockIdx.x < NPART*2) bnpart[blockIdx.x*256 + threadIdx.x] = 0.f;  // 64*512 floats
  int f = *flagp;
  int wid = threadIdx.x >> 6, lane = threadIdx.x & 63;
  int n = blockIdx.x*4 + wid;
  if (n >= N_NODESC) return;
  int f0 = lane*4;
  const u16x4 hv = *(const u16x4*)(hh + (size_t)n*HID + f0);
  float ps = 0.f, pd = 0.f;
  #pragma unroll
  for (int j = 0; j < 4; ++j){
    float hvf = b2f(hv[j]);
    ps += hvf * ldp(asrc, (size_t)loff + f0 + j, f);
    pd += hvf * ldp(adst, (size_t)loff + f0 + j, f);
  }
  if (H == 8){
    #pragma unroll
    for (int o = 1; o < 8; o <<= 1){ ps += __shfl_xor(ps, o); pd += __shfl_xor(pd, o); }
    if ((lane & 7) == 0){ ssrc[n*8 + (lane>>3)] = ps; sdst[n*8 + (lane>>3)] = pd; }
  } else {
    #pragma unroll
    for (int o = 1; o < 64; o <<= 1){ ps += __shfl_xor(ps, o); pd += __shfl_xor(pd, o); }
    if (lane == 0){ ssrc[n] = ps; sdst[n] = pd; }
  }
}

// ---------------- attention core: softmax WITHOUT max-subtraction ----------------
// Scores are O(few) (bounded activations x N(0,1/16) weights); exp clamped at +-60 never
// triggers on sane data and softmax is shift-invariant, so this matches the reference.
// Plain FMA accumulation (no rescale chain) + 1-deep prefetch -> much better ILP.
__device__ __forceinline__ void attn_node(int n, int lane, const u16* __restrict__ hh,
    const float* __restrict__ ssrc, const float* __restrict__ sdst,
    const int* __restrict__ soff, const int* __restrict__ ssorted, int H, float r[4]){
  int f0 = lane*4;
  int hl = (H == 8) ? (lane >> 3) : 0;
  float sd = sdst[n*H + hl];
  int beg = soff[n], end = soff[n+1];
  if (beg < 0) beg = 0;
  if (end > E_TOT) end = E_TOT;
  r[0] = r[1] = r[2] = r[3] = 0.f;
  if (beg >= end) return;
  int src = ssorted[beg];
  if ((unsigned)src >= N_NODESC) src = n;   // poison guard (unreachable in practice)
  u16x4 hvv = *(const u16x4*)(hh + (size_t)src*HID + f0);
  float es = ssrc[src*H + hl];
  float lval = 0.f;
  float o0 = 0.f, o1 = 0.f, o2 = 0.f, o3 = 0.f;
  for (int i = beg; i < end; ++i){
    int nsrc = src;
    if (i + 1 < end){
      nsrc = ssorted[i+1];
      if ((unsigned)nsrc >= N_NODESC) nsrc = src;
    }
    const u16x4 nh = *(const u16x4*)(hh + (size_t)nsrc*HID + f0);   // prefetch next row
    const float nes = ssrc[nsrc*H + hl];
    float ev = es + sd;
    ev = (ev > 0.f) ? ev : NEG_SLOPE*ev;
    ev = fminf(fmaxf(ev, -60.f), 60.f);
    float wv = __expf(ev);
    lval += wv;
    o0 += wv*b2f(hvv[0]);
    o1 += wv*b2f(hvv[1]);
    o2 += wv*b2f(hvv[2]);
    o3 += wv*b2f(hvv[3]);
    hvv = nh; es = nes;
  }
  float inv = (lval > 0.f) ? 1.f/lval : 0.f;
  r[0] = o0*inv; r[1] = o1*inv; r[2] = o2*inv; r[3] = o3*inv;
}

// Tier A: grid-stride attention, gout write + register-accumulated BN stats (1 atomic set/block)
__global__ __launch_bounds__(256) void k_attn_gout(const u16* __restrict__ hh,
    const float* __restrict__ ssrc, const float* __restrict__ sdst,
    const int* __restrict__ soff, const int* __restrict__ ssorted,
    u16* __restrict__ gout, int H, float* __restrict__ bnpart){
  __shared__ float lsum[4*HID];
  __shared__ float lsq[4*HID];
  int wid = threadIdx.x >> 6, lane = threadIdx.x & 63;
  int f0 = lane*4;
  float s[4] = {0.f,0.f,0.f,0.f}, q[4] = {0.f,0.f,0.f,0.f};
  int gw = blockIdx.x*4 + wid;
  int nw = gridDim.x*4;
  for (int n = gw; n < N_NODESC; n += nw){
    float r[4];
    attn_node(n, lane, hh, ssrc, sdst, soff, ssorted, H, r);
    u16x4 o;
    #pragma unroll
    for (int j = 0; j < 4; ++j){
      o[j] = f2b(r[j]);
      s[j] += r[j];
      q[j] += r[j]*r[j];
    }
    *(u16x4*)(gout + (size_t)n*HID + f0) = o;
  }
  #pragma unroll
  for (int j = 0; j < 4; ++j){
    lsum[wid*HID + f0 + j] = s[j];
    lsq [wid*HID + f0 + j] = q[j];
  }
  __syncthreads();
  int c = threadIdx.x;
  float ts = lsum[c] + lsum[HID+c] + lsum[2*HID+c] + lsum[3*HID+c];
  float tq = lsq[c]  + lsq[HID+c]  + lsq[2*HID+c]  + lsq[3*HID+c];
  float* prow = bnpart + (size_t)(blockIdx.x & (NPART-1))*512;
  atomicAdd(&prow[c], ts);
  atomicAdd(&prow[HID + c], tq);
}

// Tier B pass 1: recompute attention, block-reduce BN stats into partials
__global__ __launch_bounds__(256) void k_attn_stats(const u16* __restrict__ hh,
    const float* __restrict__ ssrc, const float* __restrict__ sdst,
    const int* __restrict__ soff, const int* __restrict__ ssorted,
    float* __restrict__ bnpart, int H){
  __shared__ float lsum[4*HID];
  __shared__ float lsq[4*HID];
  int wid = threadIdx.x >> 6, lane = threadIdx.x & 63;
  int gw = blockIdx.x*4 + wid;
  int nw = gridDim.x*4;
  float s[4] = {0.f,0.f,0.f,0.f}, q[4] = {0.f,0.f,0.f,0.f};
  for (int n = gw; n < N_NODESC; n += nw){
    float r[4];
    attn_node(n, lane, hh, ssrc, sdst, soff, ssorted, H, r);
    #pragma unroll
    for (int j = 0; j < 4; ++j){ s[j] += r[j]; q[j] += r[j]*r[j]; }
  }
  int f0 = lane*4;
  #pragma unroll
  for (int j = 0; j < 4; ++j){ lsum[wid*HID + f0 + j] = s[j]; lsq[wid*HID + f0 + j] = q[j]; }
  __syncthreads();
  int c = threadIdx.x;
  float ts = lsum[c] + lsum[HID+c] + lsum[2*HID+c] + lsum[3*HID+c];
  float tq = lsq[c]  + lsq[HID+c]  + lsq[2*HID+c]  + lsq[3*HID+c];
  float* prow = bnpart + (size_t)(blockIdx.x & (NPART-1))*512;
  atomicAdd(&prow[c], ts);
  atomicAdd(&prow[HID + c], tq);
}

// Tier B pass 2: recompute attention, fused BN+ReLU+residual into h
__global__ __launch_bounds__(256) void k_attn_apply(const u16* __restrict__ hh,
    const float* __restrict__ ssrc, const float* __restrict__ sdst,
    const int* __restrict__ soff, const int* __restrict__ ssorted,
    const float* __restrict__ scale, const float* __restrict__ shift,
    u16* __restrict__ h, int H){
  int wid = threadIdx.x >> 6, lane = threadIdx.x & 63;
  int n = blockIdx.x*4 + wid;
  if (n >= N_NODESC) return;
  float r[4];
  attn_node(n, lane, hh, ssrc, sdst, soff, ssorted, H, r);
  int f0 = lane*4;
  const f32x4 sc = *(const f32x4*)(scale + f0);
  const f32x4 sh = *(const f32x4*)(shift + f0);
  u16x4 hv = *(u16x4*)(h + (size_t)n*HID + f0);
  u16x4 o;
  #pragma unroll
  for (int j = 0; j < 4; ++j){
    float t = r[j]*sc[j] + sh[j];
    t = (t > 0.f) ? t : 0.f;
    o[j] = f2b(b2f(hv[j]) + t);
  }
  *(u16x4*)(h + (size_t)n*HID + f0) = o;
}

// ---------------- BN finalize: reduce 64 partial rows -> scale/shift ----------------
__global__ __launch_bounds__(256) void k_bn_final(const float* __restrict__ bnpart,
    const void* __restrict__ gamma, const void* __restrict__ beta,
    float* __restrict__ scale, float* __restrict__ shift,
    const int* __restrict__ flagp, int loff){
  int f = *flagp;
  int c = threadIdx.x;
  float s = 0.f, q = 0.f;
  #pragma unroll 4
  for (int p = 0; p < NPART; ++p){
    s += bnpart[(size_t)p*512 + c];
    q += bnpart[(size_t)p*512 + HID + c];
  }
  float mu  = s * (1.f/N_NODESC);
  float var = q * (1.f/N_NODESC) - mu*mu;
  if (!(var >= 0.f)) var = 0.f;   // also catches NaN
  float sc = ldp(gamma, (size_t)loff + c, f) * rsqrtf(var + BN_EPSC);
  scale[c] = sc;
  shift[c] = ldp(beta, (size_t)loff + c, f) - mu*sc;
}

// ---------------- mean pool per graph (Tier B; batch sorted, counts fused) ----------------
__global__ __launch_bounds__(256) void k_pool(const u16* __restrict__ h,
    const int* __restrict__ batch, float* __restrict__ gsum, int* __restrict__ gcnt){
  int c = threadIdx.x;
  int r0 = blockIdx.x * 256;
  int r1 = min(r0 + 256, N_NODESC);
  if (r0 >= N_NODESC) return;
  int cur = batch[r0];
  float acc = 0.f;
  int nacc = 0;
  for (int r = r0; r < r1; ++r){
    int b = batch[r];
    if ((unsigned)b >= NGRAPHS) continue;
    if (b != cur){
      if ((unsigned)cur < NGRAPHS){
        atomicAdd(&gsum[cur*HID + c], acc);
        if (c == 0) atomicAdd(&gcnt[cur], nacc);
      }
      acc = 0.f; nacc = 0; cur = b;
    }
    acc += b2f(h[(size_t)r*HID + c]);
    nacc++;
  }
  if ((unsigned)cur < NGRAPHS){
    atomicAdd(&gsum[cur*HID + c], acc);
    if (c == 0) atomicAdd(&gcnt[cur], nacc);
  }
}

// Tier A: pool fused with last layer's BN+ReLU+residual.
// 64-row chunks, 4 waves x 16-row substripes, lane owns 4 channels (u16x4 loads).
__global__ __launch_bounds__(256) void k_pool_fused(const u16* __restrict__ h,
    const u16* __restrict__ gout, const float* __restrict__ scale, const float* __restrict__ shift,
    const int* __restrict__ batch, float* __restrict__ gsum, int* __restrict__ gcnt){
  __shared__ int lb[64];
  int tid = threadIdx.x;
  int r0 = blockIdx.x*64;
  if (tid < 64){
    int rr = r0 + tid;
    lb[tid] = (rr < N_NODESC) ? batch[rr] : -1;
  }
  __syncthreads();
  int wid = tid >> 6, lane = tid & 63;
  int c4 = lane*4;
  const f32x4 sc = *(const f32x4*)(scale + c4);
  const f32x4 sh = *(const f32x4*)(shift + c4);
  int rbase = r0 + wid*16;
  f32x4 acc = (f32x4){0.f,0.f,0.f,0.f};
  int nacc = 0, cur = -1;
  #pragma unroll 4
  for (int k = 0; k < 16; ++k){
    int r = rbase + k;
    if (r >= N_NODESC) break;
    int b = lb[wid*16 + k];
    if ((unsigned)b >= NGRAPHS) continue;
    if (b != cur){
      if ((unsigned)cur < NGRAPHS){
        atomicAdd(&gsum[cur*HID + c4+0], acc[0]);
        atomicAdd(&gsum[cur*HID + c4+1], acc[1]);
        atomicAdd(&gsum[cur*HID + c4+2], acc[2]);
        atomicAdd(&gsum[cur*HID + c4+3], acc[3]);
        if (lane == 0) atomicAdd(&gcnt[cur], nacc);
      }
      acc = (f32x4){0.f,0.f,0.f,0.f}; nacc = 0; cur = b;
    }
    const u16x4 hv = *(const u16x4*)(h    + (size_t)r*HID + c4);
    const u16x4 gv = *(const u16x4*)(gout + (size_t)r*HID + c4);
    #pragma unroll
    for (int j = 0; j < 4; ++j){
      float t = b2f(gv[j])*sc[j] + sh[j];
      t = (t > 0.f) ? t : 0.f;
      acc[j] += b2f(hv[j]) + t;
    }
    nacc++;
  }
  if ((unsigned)cur < NGRAPHS){
    atomicAdd(&gsum[cur*HID + c4+0], acc[0]);
    atomicAdd(&gsum[cur*HID + c4+1], acc[1]);
    atomicAdd(&gsum[cur*HID + c4+2], acc[2]);
    atomicAdd(&gsum[cur*HID + c4+3], acc[3]);
    if (lane == 0) atomicAdd(&gcnt[cur], nacc);
  }
}

// ---------------- G prep: mean-divide and convert to bf16 (64 KB, L2-resident) ----------------
__global__ __launch_bounds__(256) void k_gprep(const float* __restrict__ gsum,
    const int* __restrict__ gcnt, u16* __restrict__ gbf){
  int g = blockIdx.x, c = threadIdx.x;
  int cc = gcnt[g]; if (cc < 1) cc = 1;
  gbf[g*HID + c] = f2b(gsum[(size_t)g*HID + c] * (1.f/(float)cc));
}

// ---------------- token predictors: MFMA GEMM  preds[s] = G[128,256] @ W_s[256,5002] ----------------
__global__ __launch_bounds__(256) void k_pred(const u16* __restrict__ gbf,
    const void* __restrict__ tokW, const void* __restrict__ tokb, void* __restrict__ out,
    const int* __restrict__ flagp){
  int f = *flagp;
  int wave = threadIdx.x >> 6, lane = threadIdx.x & 63;
  int m = lane & 15, quad = lane >> 4;
  int s = blockIdx.y;
  int v = blockIdx.x*64 + wave*16 + m;       // this lane's vocab column
  bool vok = (v < VOCABC);

  f32x4 acc[8];
  #pragma unroll
  for (int t = 0; t < 8; ++t) acc[t] = (f32x4){0.f,0.f,0.f,0.f};

  const size_t wrow = (size_t)s*HID*VOCABC + v;
  #pragma unroll
  for (int ks = 0; ks < 8; ++ks){
    int kb = ks*32 + quad*8;
    short8 b;
    #pragma unroll
    for (int j = 0; j < 8; ++j)
      b[j] = vok ? (short)f2b(ldp(tokW, wrow + (size_t)(kb + j)*VOCABC, f)) : (short)0;
    #pragma unroll
    for (int t = 0; t < 8; ++t){
      const short8 a = *(const short8*)(gbf + (size_t)(t*16 + m)*HID + kb);
      acc[t] = __builtin_amdgcn_mfma_f32_16x16x32_bf16(a, b, acc[t], 0, 0, 0);
    }
  }

  float bb = vok ? ldp(tokb, (size_t)s*VOCABC + v, f) : 0.f;
  if (!vok) return;
  #pragma unroll
  for (int t = 0; t < 8; ++t){
    #pragma unroll
    for (int r = 0; r < 4; ++r){
      int grow = t*16 + quad*4 + r;
      float val = acc[t][r] + bb;
      size_t oi = ((size_t)(s*NGRAPHS + grow)*VOCABC) + v;
      if (f) ((float*)out)[oi] = val;
      else   ((u16*)out)[oi]   = f2b(val);
    }
  }
}

// ---------------- host launcher ----------------
extern "C" void kernel_launch(void* const* d_in, const int* in_sizes, int n_in,
                              void* d_out, int out_size, void* d_ws, size_t ws_size,
                              hipStream_t stream) {
  const int* x          = (const int*)d_in[0];
  const int* node_depth = (const int*)d_in[1];
  const int* edge_index = (const int*)d_in[2];
  const int* batch      = (const int*)d_in[3];
  const void* type_emb  = d_in[4];
  const void* attr_emb  = d_in[5];
  const void* depth_emb = d_in[6];
  const void* Ws        = d_in[7];
  const void* att_src   = d_in[8];
  const void* att_dst   = d_in[9];
  // d_in[10] = gat_bias: dropped (constant per channel cancels inside BatchNorm)
  const void* bn_gamma  = d_in[11];
  const void* bn_beta   = d_in[12];
  const void* tok_W     = d_in[13];
  const void* tok_b     = d_in[14];

  // ---- workspace carve ----
  char* base = (char*)d_ws;
  size_t off = 0;
  auto carve = [&](size_t bytes) -> void* {
    void* p = base + off;
    off += (bytes + 255) & ~(size_t)255;
    return p;
  };
  u16*   h     = (u16*)carve((size_t)N_NODESC*HID*2);     // 51.2 MB
  u16*   hh    = (u16*)carve((size_t)N_NODESC*HID*2);     // 51.2 MB
  float* ssrc  = (float*)carve((size_t)N_NODESC*8*4);     // 3.2 MB
  float* sdst  = (float*)carve((size_t)N_NODESC*8*4);     // 3.2 MB
  int*   soff  = (int*)carve((size_t)(N_NODESC+1)*4);
  int*   cursor= (int*)carve((size_t)N_NODESC*4);
  int*   ssorted=(int*)carve((size_t)E_TOT*4);            // 2.0 MB
  int*   btot  = (int*)carve((size_t)NCHUNK*4);
  int*   boff  = (int*)carve((size_t)NCHUNK*4);
  u16*   WT    = (u16*)carve((size_t)NLAYERS*HID*HID*2);  // 0.5 MB
  float* bnpart= (float*)carve((size_t)NPART*512*4);      // 128 KB BN partials
  float* bnscale=(float*)carve(HID*4);
  float* bnshift=(float*)carve(HID*4);
  float* gsum  = (float*)carve((size_t)NGRAPHS*HID*4);    // 128 KB
  int*   gcnt  = (int*)carve((size_t)NGRAPHS*4);          // adjacent to gsum
  u16*   gbf   = (u16*)carve((size_t)NGRAPHS*HID*2);      // 64 KB bf16 pooled graphs
  int*   dflag = (int*)carve(256);
  size_t common = off;
  u16*   gout  = (u16*)carve((size_t)N_NODESC*HID*2);     // +51.2 MB
  const bool useGout = (off <= ws_size);
  if (common > ws_size) return;  // cannot run at all

  const int EB  = (E_TOT + 255)/256;
  const int NB4 = (N_NODESC + 3)/4;      // wave-per-node kernels

  // dtype detection first
  k_detect<<<1, 64, 0, stream>>>(type_emb, dflag);

  // setup (k_embed also zeroes cursor)
  k_embed<<<NCH64, 256, 0, stream>>>(x, node_depth, type_emb, attr_emb, depth_emb, h, dflag, cursor);
  k_transW<<<dim3(256, NLAYERS), 256, 0, stream>>>(Ws, WT, dflag);
  k_hist<<<EB, 256, 0, stream>>>(edge_index, cursor);
  k_scan_part<<<NCHUNK, 256, 0, stream>>>(cursor, soff, btot);
  k_scan_tot<<<1, 256, 0, stream>>>(btot, boff, soff + N_NODESC);
  k_scan_add<<<NCHUNK, 256, 0, stream>>>(soff, boff, cursor);   // also zeroes cursor
  k_scatter<<<EB, 256, 0, stream>>>(edge_index, soff, cursor, ssorted);

  // layers — Tier A: bn_apply of layer l-1 fused into gemm of layer l
  for (int l = 0; l < NLAYERS; ++l){
    int H = (l == NLAYERS-1) ? 1 : 8;
    int doApply = (useGout && l > 0) ? 1 : 0;
    k_gemm<<<1024, 256, 0, stream>>>(h, gout, bnscale, bnshift, doApply,
                                     WT + (size_t)l*HID*HID, hh);
    k_scores<<<NB4, 256, 0, stream>>>(hh, att_src, att_dst, ssrc, sdst, H, dflag, l*HID, bnpart);
    if (useGout){
      k_attn_gout<<<ATTNB, 256, 0, stream>>>(hh, ssrc, sdst, soff, ssorted, gout, H, bnpart);
      k_bn_final<<<1, 256, 0, stream>>>(bnpart, bn_gamma, bn_beta, bnscale, bnshift, dflag, l*HID);
    } else {
      k_attn_stats<<<2048, 256, 0, stream>>>(hh, ssrc, sdst, soff, ssorted, bnpart, H);
      k_bn_final<<<1, 256, 0, stream>>>(bnpart, bn_gamma, bn_beta, bnscale, bnshift, dflag, l*HID);
      k_attn_apply<<<NB4, 256, 0, stream>>>(hh, ssrc, sdst, soff, ssorted, bnscale, bnshift, h, H);
    }
  }

  // pool (gsum+gcnt adjacent -> single zero launch)
  k_zero<<<(NGRAPHS*HID + NGRAPHS + 255)/256, 256, 0, stream>>>((int*)gsum, NGRAPHS*HID + NGRAPHS);
  if (useGout)
    k_pool_fused<<<NCH64, 256, 0, stream>>>(h, gout, bnscale, bnshift, batch, gsum, gcnt);
  else
    k_pool<<<NCHUNK, 256, 0, stream>>>(h, batch, gsum, gcnt);
  k_gprep<<<NGRAPHS, 256, 0, stream>>>(gsum, gcnt, gbf);

  // predictors (MFMA GEMM)
  k_pred<<<dim3(NVQ, SEQLEN), 256, 0, stream>>>(gbf, tok_W, tok_b, d_out, dflag);
}

// Round 13
// 830.477 us; speedup vs baseline: 3.1134x; 1.0988x over previous
//
#include <hip/hip_runtime.h>
#include <stdint.h>

typedef uint16_t u16;
typedef uint32_t u32;

#define N_NODESC 100000
#define N_EDGESC 400000
#define E_TOT    500000   // edges + self loops
#define HID      256
#define NLAYERS  4
#define NGRAPHS  128
#define SEQLEN   5
#define VOCABC   5002
#define MAXDEPTH 20
#define NEG_SLOPE 0.2f
#define BN_EPSC  1e-5f
#define NCHUNK   ((N_NODESC + 255)/256)   // 391
#define NCH64    ((N_NODESC + 63)/64)     // 1563 (64-row chunks)
#define NROWT    (N_NODESC/16)            // 6250 row tiles, exact
#define NPART    64                       // BN partial rows (each 512 floats: 256 sum + 256 sq)
#define NVQ      ((VOCABC + 63)/64)       // 79 vocab quads for k_pred
#define ATTNB    2048                     // grid for k_attn_gout
#define LDSROW   264                      // padded LDS row (u16): 2-way alias only

typedef __attribute__((ext_vector_type(8))) short short8;
typedef __attribute__((ext_vector_type(4))) float f32x4;
typedef __attribute__((ext_vector_type(4))) unsigned short u16x4;

__device__ __forceinline__ float b2f(u16 u){
  union { u32 i; float f; } v; v.i = ((u32)u) << 16; return v.f;
}
__device__ __forceinline__ u16 f2b(float f){
  union { float f; u32 i; } v; v.f = f;
  u32 u = v.i;
  u += 0x7FFFu + ((u >> 16) & 1u);   // RNE
  return (u16)(u >> 16);
}
// dual-dtype parameter load: flag=1 -> f32, flag=0 -> bf16
__device__ __forceinline__ float ldp(const void* p, size_t i, int f){
  return f ? ((const float*)p)[i] : b2f(((const u16*)p)[i]);
}
// 4-wide dual-dtype load (i must be 4-element aligned)
__device__ __forceinline__ f32x4 ld4(const void* p, size_t i, int f){
  f32x4 r;
  if (f){
    r = *(const f32x4*)((const float*)p + i);
  } else {
    const u16x4 u = *(const u16x4*)((const u16*)p + i);
    r[0] = b2f(u[0]); r[1] = b2f(u[1]); r[2] = b2f(u[2]); r[3] = b2f(u[3]);
  }
  return r;
}

// ---------------- dtype detector: sample type_emb both ways ----------------
__global__ __launch_bounds__(64) void k_detect(const void* temb, int* flag){
  int lane = threadIdx.x;
  const u32* w32 = (const u32*)temb;
  int sf = 0, sb = 0;
  for (int i = lane; i < 256; i += 64){
    u32 w = w32[i];
    union { u32 u; float f; } cf; cf.u = w;
    float af = fabsf(cf.f);
    if (cf.f == 0.0f || (af >= 1e-12f && af <= 4096.f)) sf++;
    float b0 = b2f((u16)(w & 0xFFFFu));
    float b1 = b2f((u16)(w >> 16));
    float a0 = fabsf(b0), a1 = fabsf(b1);
    if (b0 == 0.f || (a0 >= 1e-12f && a0 <= 4096.f)) sb++;
    if (b1 == 0.f || (a1 >= 1e-12f && a1 <= 4096.f)) sb++;
  }
  #pragma unroll
  for (int o = 1; o < 64; o <<= 1){ sf += __shfl_xor(sf, o); sb += __shfl_xor(sb, o); }
  if (lane == 0) *flag = (2*sf > sb) ? 1 : 0;
}

// ---------------- utility ----------------
__global__ __launch_bounds__(256) void k_zero(int* __restrict__ p, int n){
  int i = blockIdx.x*256 + threadIdx.x;
  if (i < n) p[i] = 0;
}

// ---------------- embedding: 64-node chunks, lane owns 4 channels; zeroes cursor ----------------
__global__ __launch_bounds__(256) void k_embed(const int* __restrict__ x, const int* __restrict__ nd,
    const void* __restrict__ temb, const void* __restrict__ aemb, const void* __restrict__ demb,
    u16* __restrict__ h, const int* __restrict__ flagp, int* __restrict__ cursor){
  int f = *flagp;
  int tid = threadIdx.x;
  int r0 = blockIdx.x*64;
  if (tid < 64 && r0 + tid < N_NODESC) cursor[r0 + tid] = 0;
  int wid = tid >> 6, lane = tid & 63;
  int c4 = lane*4;
  #pragma unroll 4
  for (int k = 0; k < 16; ++k){
    int n = r0 + wid*16 + k;
    if (n >= N_NODESC) break;
    int t = x[n*2+0], a = x[n*2+1];
    if (t < 0) t = 0; if (t > 97) t = 97;
    if (a < 0) a = 0; if (a > 10029) a = 10029;
    int d = nd[n]; if (d > MAXDEPTH) d = MAXDEPTH; if (d < 0) d = 0;
    const f32x4 vt = ld4(temb, (size_t)t*HID + c4, f);
    const f32x4 va = ld4(aemb, (size_t)a*HID + c4, f);
    const f32x4 vd = ld4(demb, (size_t)d*HID + c4, f);
    u16x4 o;
    #pragma unroll
    for (int j = 0; j < 4; ++j) o[j] = f2b(vt[j] + va[j] + vd[j]);
    *(u16x4*)(h + (size_t)n*HID + c4) = o;
  }
}

// ---------------- edge sort by dst (counting sort) ----------------
__global__ __launch_bounds__(256) void k_hist(const int* __restrict__ ei, int* __restrict__ cnt){
  int e = blockIdx.x*256 + threadIdx.x;
  if (e >= E_TOT) return;
  int dst = (e < N_EDGESC) ? ei[N_EDGESC + e] : (e - N_EDGESC);
  if ((unsigned)dst >= N_NODESC) return;
  atomicAdd(&cnt[dst], 1);
}

// hierarchical scan, phase 1: per-256-chunk exclusive scan + chunk total
__global__ __launch_bounds__(256) void k_scan_part(const int* __restrict__ cnt,
    int* __restrict__ off, int* __restrict__ btot){
  __shared__ int lds[256];
  int b = blockIdx.x, tid = threadIdx.x;
  int i = b*256 + tid;
  int v = (i < N_NODESC) ? cnt[i] : 0;
  lds[tid] = v;
  __syncthreads();
  #pragma unroll
  for (int s = 1; s < 256; s <<= 1){
    int t = (tid >= s) ? lds[tid - s] : 0;
    __syncthreads();
    lds[tid] += t;
    __syncthreads();
  }
  if (i < N_NODESC) off[i] = lds[tid] - v;   // chunk-local exclusive
  if (tid == 255) btot[b] = lds[255];
}

// phase 2: scan the 391 chunk totals (1 block), write grand total to offN
__global__ __launch_bounds__(256) void k_scan_tot(const int* __restrict__ btot,
    int* __restrict__ boff, int* __restrict__ offN){
  __shared__ int lds[256];
  __shared__ int s_carry;
  int tid = threadIdx.x;
  if (tid == 0) s_carry = 0;
  __syncthreads();
  for (int base = 0; base < NCHUNK; base += 256){
    int i = base + tid;
    int v = (i < NCHUNK) ? btot[i] : 0;
    lds[tid] = v;
    __syncthreads();
    #pragma unroll
    for (int s = 1; s < 256; s <<= 1){
      int t = (tid >= s) ? lds[tid - s] : 0;
      __syncthreads();
      lds[tid] += t;
      __syncthreads();
    }
    if (i < NCHUNK) boff[i] = s_carry + lds[tid] - v;
    __syncthreads();
    if (tid == 255) s_carry += lds[255];
    __syncthreads();
  }
  if (tid == 0) *offN = s_carry;
}

// phase 3: add chunk offsets; also re-zero cursor for the scatter pass
__global__ __launch_bounds__(256) void k_scan_add(int* __restrict__ off,
    const int* __restrict__ boff, int* __restrict__ cursor){
  int b = blockIdx.x;
  int i = b*256 + threadIdx.x;
  if (i < N_NODESC){ off[i] += boff[b]; cursor[i] = 0; }
}

__global__ __launch_bounds__(256) void k_scatter(const int* __restrict__ ei,
    const int* __restrict__ soff, int* __restrict__ cursor, int* __restrict__ ssorted){
  int e = blockIdx.x*256 + threadIdx.x;
  if (e >= E_TOT) return;
  int src = (e < N_EDGESC) ? ei[e]            : (e - N_EDGESC);
  int dst = (e < N_EDGESC) ? ei[N_EDGESC + e] : (e - N_EDGESC);
  if ((unsigned)dst >= N_NODESC || (unsigned)src >= N_NODESC) return;
  int pos = soff[dst] + atomicAdd(&cursor[dst], 1);
  if ((unsigned)pos < E_TOT) ssorted[pos] = src;
}

// ---------------- W transpose -> bf16 WT, all layers ----------------
__global__ __launch_bounds__(256) void k_transW(const void* __restrict__ W, u16* __restrict__ WT,
    const int* __restrict__ flagp){
  int f = *flagp;
  int l = blockIdx.y, n2 = blockIdx.x, k = threadIdx.x;
  WT[(l*HID + n2)*HID + k] = f2b(ldp(W, (size_t)(l*HID + k)*HID + n2, f));
}

// ---------------- VA precompute: VA[i, h*2+sd] = sum_{o in head h} W[i,o]*a_{src,dst}[o] ----------------
// Stored transposed like WT: VAT[(l*16 + col)*HID + i], bf16. For H=1 layer: col0=full src, col1=full dst.
__global__ __launch_bounds__(256) void k_prepVA(const void* __restrict__ Ws,
    const void* __restrict__ asrc, const void* __restrict__ adst,
    u16* __restrict__ VAT, const int* __restrict__ flagp){
  int f = *flagp;
  int l = blockIdx.x;
  int i = threadIdx.x;           // input channel
  int H = (l == NLAYERS-1) ? 1 : 8;
  float col[16];
  #pragma unroll
  for (int c = 0; c < 16; ++c) col[c] = 0.f;
  if (H == 8){
    for (int h = 0; h < 8; ++h){
      float vs = 0.f, vd = 0.f;
      for (int o = h*32; o < h*32+32; ++o){
        float w = ldp(Ws, ((size_t)l*HID + i)*HID + o, f);
        vs += w * ldp(asrc, (size_t)l*HID + o, f);
        vd += w * ldp(adst, (size_t)l*HID + o, f);
      }
      col[h*2] = vs; col[h*2+1] = vd;
    }
  } else {
    float vs = 0.f, vd = 0.f;
    for (int o = 0; o < HID; ++o){
      float w = ldp(Ws, ((size_t)l*HID + i)*HID + o, f);
      vs += w * ldp(asrc, (size_t)l*HID + o, f);
      vd += w * ldp(adst, (size_t)l*HID + o, f);
    }
    col[0] = vs; col[1] = vd;
  }
  #pragma unroll
  for (int c = 0; c < 16; ++c)
    VAT[((size_t)l*16 + c)*HID + i] = f2b(col[c]);
}

// ---------------- GEMM + fused prev-layer BN apply + fused scores (17th B-tile) ----------------
// Preamble builds h_new into LDS (+writeback). MFMA main loop (4 tiles/wave, reg-resident B).
// Wave 0 additionally multiplies by VA (16 cols) -> D-frag IS the per-head scores; stored to ssrc/sdst.
// Blocks 0..127 zero the BN partial buffer for this layer's attention.
__global__ __launch_bounds__(256) void k_gemm(u16* __restrict__ h,
    const u16* __restrict__ gout, const float* __restrict__ scale,
    const float* __restrict__ shift, int doApply,
    const u16* __restrict__ WT, const u16* __restrict__ VAT,
    u16* __restrict__ hh, float* __restrict__ ssrc, float* __restrict__ sdst,
    int H, float* __restrict__ bnpart){
  __shared__ u16 hA[16*LDSROW];
  int tid = threadIdx.x;
  if (blockIdx.x < NPART*2) bnpart[blockIdx.x*256 + tid] = 0.f;
  int wave = tid >> 6, lane = tid & 63;
  int m = lane & 15, quad = lane >> 4;
  int prow = tid >> 4, pch = (tid & 15)*16;

  short8 B[4][8];
  #pragma unroll
  for (int j = 0; j < 4; ++j){
    const u16* wp = WT + (size_t)((wave*4 + j)*16 + m)*HID + quad*8;
    #pragma unroll
    for (int ks = 0; ks < 8; ++ks)
      B[j][ks] = *(const short8*)(wp + ks*32);
  }
  short8 B5[8];
  if (wave == 0){
    const u16* vp = VAT + (size_t)m*HID + quad*8;
    #pragma unroll
    for (int ks = 0; ks < 8; ++ks)
      B5[ks] = *(const short8*)(vp + ks*32);
  }

  for (int t = blockIdx.x; t < NROWT; t += gridDim.x){
    int r0 = t*16;
    // preamble: 16 rows x 256 ch; thread owns (row=prow, ch pch..pch+15)
    {
      size_t base = (size_t)(r0 + prow)*HID + pch;
      short8 h0 = *(const short8*)(h + base);
      short8 h1 = *(const short8*)(h + base + 8);
      if (doApply){
        const short8 g0 = *(const short8*)(gout + base);
        const short8 g1 = *(const short8*)(gout + base + 8);
        #pragma unroll
        for (int v = 0; v < 2; ++v){
          const f32x4 sc = *(const f32x4*)(scale + pch + v*4);
          const f32x4 sh = *(const f32x4*)(shift + pch + v*4);
          #pragma unroll
          for (int j = 0; j < 4; ++j){
            float tv = b2f((u16)g0[v*4+j])*sc[j] + sh[j];
            tv = (tv > 0.f) ? tv : 0.f;
            h0[v*4+j] = (short)f2b(b2f((u16)h0[v*4+j]) + tv);
          }
        }
        #pragma unroll
        for (int v = 0; v < 2; ++v){
          const f32x4 sc = *(const f32x4*)(scale + pch + 8 + v*4);
          const f32x4 sh = *(const f32x4*)(shift + pch + 8 + v*4);
          #pragma unroll
          for (int j = 0; j < 4; ++j){
            float tv = b2f((u16)g1[v*4+j])*sc[j] + sh[j];
            tv = (tv > 0.f) ? tv : 0.f;
            h1[v*4+j] = (short)f2b(b2f((u16)h1[v*4+j]) + tv);
          }
        }
        *(short8*)(h + base)     = h0;   // write back h_new (rows uniquely owned)
        *(short8*)(h + base + 8) = h1;
      }
      *(short8*)(&hA[prow*LDSROW + pch])     = h0;
      *(short8*)(&hA[prow*LDSROW + pch + 8]) = h1;
    }
    __syncthreads();

    short8 A[8];
    #pragma unroll
    for (int ks = 0; ks < 8; ++ks)
      A[ks] = *(const short8*)(&hA[m*LDSROW + ks*32 + quad*8]);

    f32x4 acc[4];
    #pragma unroll
    for (int j = 0; j < 4; ++j) acc[j] = (f32x4){0.f,0.f,0.f,0.f};
    #pragma unroll
    for (int ks = 0; ks < 8; ++ks){
      #pragma unroll
      for (int j = 0; j < 4; ++j)
        acc[j] = __builtin_amdgcn_mfma_f32_16x16x32_bf16(A[ks], B[j][ks], acc[j], 0, 0, 0);
    }

    // fused scores: wave 0, 17th B-tile; D col = head*2+sd, row = quad*4+r
    if (wave == 0){
      f32x4 acc5 = (f32x4){0.f,0.f,0.f,0.f};
      #pragma unroll
      for (int ks = 0; ks < 8; ++ks)
        acc5 = __builtin_amdgcn_mfma_f32_16x16x32_bf16(A[ks], B5[ks], acc5, 0, 0, 0);
      int hidx = m >> 1, sd = m & 1;
      #pragma unroll
      for (int r = 0; r < 4; ++r){
        int row = r0 + quad*4 + r;
        float val = acc5[r];
        if (H == 8){
          if (sd == 0) ssrc[row*8 + hidx] = val;
          else         sdst[row*8 + hidx] = val;
        } else {
          if (m == 0)      ssrc[row] = val;
          else if (m == 1) sdst[row] = val;
        }
      }
    }

    #pragma unroll
    for (int j = 0; j < 4; ++j){
      int col = (wave*4 + j)*16 + m;
      #pragma unroll
      for (int r = 0; r < 4; ++r){
        int orow = r0 + quad*4 + r;
        hh[(size_t)orow*HID + col] = f2b(acc[j][r]);
      }
    }
    __syncthreads();   // protect LDS before next tile's preamble
  }
}

// ---------------- attention core: softmax WITHOUT max-subtraction ----------------
// Scores are O(few); exp clamped at +-60 never triggers on sane data; softmax shift-invariant.
__device__ __forceinline__ void attn_node(int n, int lane, const u16* __restrict__ hh,
    const float* __restrict__ ssrc, const float* __restrict__ sdst,
    const int* __restrict__ soff, const int* __restrict__ ssorted, int H, float r[4]){
  int f0 = lane*4;
  int hl = (H == 8) ? (lane >> 3) : 0;
  float sd = sdst[n*H + hl];
  int beg = soff[n], end = soff[n+1];
  if (beg < 0) beg = 0;
  if (end > E_TOT) end = E_TOT;
  r[0] = r[1] = r[2] = r[3] = 0.f;
  if (beg >= end) return;
  int src = ssorted[beg];
  if ((unsigned)src >= N_NODESC) src = n;   // poison guard (unreachable in practice)
  u16x4 hvv = *(const u16x4*)(hh + (size_t)src*HID + f0);
  float es = ssrc[src*H + hl];
  float lval = 0.f;
  float o0 = 0.f, o1 = 0.f, o2 = 0.f, o3 = 0.f;
  for (int i = beg; i < end; ++i){
    int nsrc = src;
    if (i + 1 < end){
      nsrc = ssorted[i+1];
      if ((unsigned)nsrc >= N_NODESC) nsrc = src;
    }
    const u16x4 nh = *(const u16x4*)(hh + (size_t)nsrc*HID + f0);   // prefetch next row
    const float nes = ssrc[nsrc*H + hl];
    float ev = es + sd;
    ev = (ev > 0.f) ? ev : NEG_SLOPE*ev;
    ev = fminf(fmaxf(ev, -60.f), 60.f);
    float wv = __expf(ev);
    lval += wv;
    o0 += wv*b2f(hvv[0]);
    o1 += wv*b2f(hvv[1]);
    o2 += wv*b2f(hvv[2]);
    o3 += wv*b2f(hvv[3]);
    hvv = nh; es = nes;
  }
  float inv = (lval > 0.f) ? 1.f/lval : 0.f;
  r[0] = o0*inv; r[1] = o1*inv; r[2] = o2*inv; r[3] = o3*inv;
}

// Tier A: grid-stride attention, gout write + register-accumulated BN stats (1 atomic set/block)
__global__ __launch_bounds__(256) void k_attn_gout(const u16* __restrict__ hh,
    const float* __restrict__ ssrc, const float* __restrict__ sdst,
    const int* __restrict__ soff, const int* __restrict__ ssorted,
    u16* __restrict__ gout, int H, float* __restrict__ bnpart){
  __shared__ float lsum[4*HID];
  __shared__ float lsq[4*HID];
  int wid = threadIdx.x >> 6, lane = threadIdx.x & 63;
  int f0 = lane*4;
  float s[4] = {0.f,0.f,0.f,0.f}, q[4] = {0.f,0.f,0.f,0.f};
  int gw = blockIdx.x*4 + wid;
  int nw = gridDim.x*4;
  for (int n = gw; n < N_NODESC; n += nw){
    float r[4];
    attn_node(n, lane, hh, ssrc, sdst, soff, ssorted, H, r);
    u16x4 o;
    #pragma unroll
    for (int j = 0; j < 4; ++j){
      o[j] = f2b(r[j]);
      s[j] += r[j];
      q[j] += r[j]*r[j];
    }
    *(u16x4*)(gout + (size_t)n*HID + f0) = o;
  }
  #pragma unroll
  for (int j = 0; j < 4; ++j){
    lsum[wid*HID + f0 + j] = s[j];
    lsq [wid*HID + f0 + j] = q[j];
  }
  __syncthreads();
  int c = threadIdx.x;
  float ts = lsum[c] + lsum[HID+c] + lsum[2*HID+c] + lsum[3*HID+c];
  float tq = lsq[c]  + lsq[HID+c]  + lsq[2*HID+c]  + lsq[3*HID+c];
  float* prow = bnpart + (size_t)(blockIdx.x & (NPART-1))*512;
  atomicAdd(&prow[c], ts);
  atomicAdd(&prow[HID + c], tq);
}

// Tier B pass 1: recompute attention, block-reduce BN stats into partials
__global__ __launch_bounds__(256) void k_attn_stats(const u16* __restrict__ hh,
    const float* __restrict__ ssrc, const float* __restrict__ sdst,
    const int* __restrict__ soff, const int* __restrict__ ssorted,
    float* __restrict__ bnpart, int H){
  __shared__ float lsum[4*HID];
  __shared__ float lsq[4*HID];
  int wid = threadIdx.x >> 6, lane = threadIdx.x & 63;
  int gw = blockIdx.x*4 + wid;
  int nw = gridDim.x*4;
  float s[4] = {0.f,0.f,0.f,0.f}, q[4] = {0.f,0.f,0.f,0.f};
  for (int n = gw; n < N_NODESC; n += nw){
    float r[4];
    attn_node(n, lane, hh, ssrc, sdst, soff, ssorted, H, r);
    #pragma unroll
    for (int j = 0; j < 4; ++j){ s[j] += r[j]; q[j] += r[j]*r[j]; }
  }
  int f0 = lane*4;
  #pragma unroll
  for (int j = 0; j < 4; ++j){ lsum[wid*HID + f0 + j] = s[j]; lsq[wid*HID + f0 + j] = q[j]; }
  __syncthreads();
  int c = threadIdx.x;
  float ts = lsum[c] + lsum[HID+c] + lsum[2*HID+c] + lsum[3*HID+c];
  float tq = lsq[c]  + lsq[HID+c]  + lsq[2*HID+c]  + lsq[3*HID+c];
  float* prow = bnpart + (size_t)(blockIdx.x & (NPART-1))*512;
  atomicAdd(&prow[c], ts);
  atomicAdd(&prow[HID + c], tq);
}

// Tier B pass 2: recompute attention, fused BN+ReLU+residual into h
__global__ __launch_bounds__(256) void k_attn_apply(const u16* __restrict__ hh,
    const float* __restrict__ ssrc, const float* __restrict__ sdst,
    const int* __restrict__ soff, const int* __restrict__ ssorted,
    const float* __restrict__ scale, const float* __restrict__ shift,
    u16* __restrict__ h, int H){
  int wid = threadIdx.x >> 6, lane = threadIdx.x & 63;
  int n = blockIdx.x*4 + wid;
  if (n >= N_NODESC) return;
  float r[4];
  attn_node(n, lane, hh, ssrc, sdst, soff, ssorted, H, r);
  int f0 = lane*4;
  const f32x4 sc = *(const f32x4*)(scale + f0);
  const f32x4 sh = *(const f32x4*)(shift + f0);
  u16x4 hv = *(u16x4*)(h + (size_t)n*HID + f0);
  u16x4 o;
  #pragma unroll
  for (int j = 0; j < 4; ++j){
    float t = r[j]*sc[j] + sh[j];
    t = (t > 0.f) ? t : 0.f;
    o[j] = f2b(b2f(hv[j]) + t);
  }
  *(u16x4*)(h + (size_t)n*HID + f0) = o;
}

// ---------------- BN finalize: reduce 64 partial rows -> scale/shift ----------------
__global__ __launch_bounds__(256) void k_bn_final(const float* __restrict__ bnpart,
    const void* __restrict__ gamma, const void* __restrict__ beta,
    float* __restrict__ scale, float* __restrict__ shift,
    const int* __restrict__ flagp, int loff){
  int f = *flagp;
  int c = threadIdx.x;
  float s = 0.f, q = 0.f;
  #pragma unroll 4
  for (int p = 0; p < NPART; ++p){
    s += bnpart[(size_t)p*512 + c];
    q += bnpart[(size_t)p*512 + HID + c];
  }
  float mu  = s * (1.f/N_NODESC);
  float var = q * (1.f/N_NODESC) - mu*mu;
  if (!(var >= 0.f)) var = 0.f;   // also catches NaN
  float sc = ldp(gamma, (size_t)loff + c, f) * rsqrtf(var + BN_EPSC);
  scale[c] = sc;
  shift[c] = ldp(beta, (size_t)loff + c, f) - mu*sc;
}

// ---------------- mean pool per graph (Tier B; batch sorted, counts fused) ----------------
__global__ __launch_bounds__(256) void k_pool(const u16* __restrict__ h,
    const int* __restrict__ batch, float* __restrict__ gsum, int* __restrict__ gcnt){
  int c = threadIdx.x;
  int r0 = blockIdx.x * 256;
  int r1 = min(r0 + 256, N_NODESC);
  if (r0 >= N_NODESC) return;
  int cur = batch[r0];
  float acc = 0.f;
  int nacc = 0;
  for (int r = r0; r < r1; ++r){
    int b = batch[r];
    if ((unsigned)b >= NGRAPHS) continue;
    if (b != cur){
      if ((unsigned)cur < NGRAPHS){
        atomicAdd(&gsum[cur*HID + c], acc);
        if (c == 0) atomicAdd(&gcnt[cur], nacc);
      }
      acc = 0.f; nacc = 0; cur = b;
    }
    acc += b2f(h[(size_t)r*HID + c]);
    nacc++;
  }
  if ((unsigned)cur < NGRAPHS){
    atomicAdd(&gsum[cur*HID + c], acc);
    if (c == 0) atomicAdd(&gcnt[cur], nacc);
  }
}

// Tier A: pool fused with last layer's BN+ReLU+residual.
__global__ __launch_bounds__(256) void k_pool_fused(const u16* __restrict__ h,
    const u16* __restrict__ gout, const float* __restrict__ scale, const float* __restrict__ shift,
    const int* __restrict__ batch, float* __restrict__ gsum, int* __restrict__ gcnt){
  __shared__ int lb[64];
  int tid = threadIdx.x;
  int r0 = blockIdx.x*64;
  if (tid < 64){
    int rr = r0 + tid;
    lb[tid] = (rr < N_NODESC) ? batch[rr] : -1;
  }
  __syncthreads();
  int wid = tid >> 6, lane = tid & 63;
  int c4 = lane*4;
  const f32x4 sc = *(const f32x4*)(scale + c4);
  const f32x4 sh = *(const f32x4*)(shift + c4);
  int rbase = r0 + wid*16;
  f32x4 acc = (f32x4){0.f,0.f,0.f,0.f};
  int nacc = 0, cur = -1;
  #pragma unroll 4
  for (int k = 0; k < 16; ++k){
    int r = rbase + k;
    if (r >= N_NODESC) break;
    int b = lb[wid*16 + k];
    if ((unsigned)b >= NGRAPHS) continue;
    if (b != cur){
      if ((unsigned)cur < NGRAPHS){
        atomicAdd(&gsum[cur*HID + c4+0], acc[0]);
        atomicAdd(&gsum[cur*HID + c4+1], acc[1]);
        atomicAdd(&gsum[cur*HID + c4+2], acc[2]);
        atomicAdd(&gsum[cur*HID + c4+3], acc[3]);
        if (lane == 0) atomicAdd(&gcnt[cur], nacc);
      }
      acc = (f32x4){0.f,0.f,0.f,0.f}; nacc = 0; cur = b;
    }
    const u16x4 hv = *(const u16x4*)(h    + (size_t)r*HID + c4);
    const u16x4 gv = *(const u16x4*)(gout + (size_t)r*HID + c4);
    #pragma unroll
    for (int j = 0; j < 4; ++j){
      float t = b2f(gv[j])*sc[j] + sh[j];
      t = (t > 0.f) ? t : 0.f;
      acc[j] += b2f(hv[j]) + t;
    }
    nacc++;
  }
  if ((unsigned)cur < NGRAPHS){
    atomicAdd(&gsum[cur*HID + c4+0], acc[0]);
    atomicAdd(&gsum[cur*HID + c4+1], acc[1]);
    atomicAdd(&gsum[cur*HID + c4+2], acc[2]);
    atomicAdd(&gsum[cur*HID + c4+3], acc[3]);
    if (lane == 0) atomicAdd(&gcnt[cur], nacc);
  }
}

// ---------------- G prep: mean-divide and convert to bf16 (64 KB, L2-resident) ----------------
__global__ __launch_bounds__(256) void k_gprep(const float* __restrict__ gsum,
    const int* __restrict__ gcnt, u16* __restrict__ gbf){
  int g = blockIdx.x, c = threadIdx.x;
  int cc = gcnt[g]; if (cc < 1) cc = 1;
  gbf[g*HID + c] = f2b(gsum[(size_t)g*HID + c] * (1.f/(float)cc));
}

// ---------------- token predictors: MFMA GEMM  preds[s] = G[128,256] @ W_s[256,5002] ----------------
__global__ __launch_bounds__(256) void k_pred(const u16* __restrict__ gbf,
    const void* __restrict__ tokW, const void* __restrict__ tokb, void* __restrict__ out,
    const int* __restrict__ flagp){
  int f = *flagp;
  int wave = threadIdx.x >> 6, lane = threadIdx.x & 63;
  int m = lane & 15, quad = lane >> 4;
  int s = blockIdx.y;
  int v = blockIdx.x*64 + wave*16 + m;       // this lane's vocab column
  bool vok = (v < VOCABC);

  f32x4 acc[8];
  #pragma unroll
  for (int t = 0; t < 8; ++t) acc[t] = (f32x4){0.f,0.f,0.f,0.f};

  const size_t wrow = (size_t)s*HID*VOCABC + v;
  #pragma unroll
  for (int ks = 0; ks < 8; ++ks){
    int kb = ks*32 + quad*8;
    short8 b;
    #pragma unroll
    for (int j = 0; j < 8; ++j)
      b[j] = vok ? (short)f2b(ldp(tokW, wrow + (size_t)(kb + j)*VOCABC, f)) : (short)0;
    #pragma unroll
    for (int t = 0; t < 8; ++t){
      const short8 a = *(const short8*)(gbf + (size_t)(t*16 + m)*HID + kb);
      acc[t] = __builtin_amdgcn_mfma_f32_16x16x32_bf16(a, b, acc[t], 0, 0, 0);
    }
  }

  float bb = vok ? ldp(tokb, (size_t)s*VOCABC + v, f) : 0.f;
  if (!vok) return;
  #pragma unroll
  for (int t = 0; t < 8; ++t){
    #pragma unroll
    for (int r = 0; r < 4; ++r){
      int grow = t*16 + quad*4 + r;
      float val = acc[t][r] + bb;
      size_t oi = ((size_t)(s*NGRAPHS + grow)*VOCABC) + v;
      if (f) ((float*)out)[oi] = val;
      else   ((u16*)out)[oi]   = f2b(val);
    }
  }
}

// ---------------- host launcher ----------------
extern "C" void kernel_launch(void* const* d_in, const int* in_sizes, int n_in,
                              void* d_out, int out_size, void* d_ws, size_t ws_size,
                              hipStream_t stream) {
  const int* x          = (const int*)d_in[0];
  const int* node_depth = (const int*)d_in[1];
  const int* edge_index = (const int*)d_in[2];
  const int* batch      = (const int*)d_in[3];
  const void* type_emb  = d_in[4];
  const void* attr_emb  = d_in[5];
  const void* depth_emb = d_in[6];
  const void* Ws        = d_in[7];
  const void* att_src   = d_in[8];
  const void* att_dst   = d_in[9];
  // d_in[10] = gat_bias: dropped (constant per channel cancels inside BatchNorm)
  const void* bn_gamma  = d_in[11];
  const void* bn_beta   = d_in[12];
  const void* tok_W     = d_in[13];
  const void* tok_b     = d_in[14];

  // ---- workspace carve ----
  char* base = (char*)d_ws;
  size_t off = 0;
  auto carve = [&](size_t bytes) -> void* {
    void* p = base + off;
    off += (bytes + 255) & ~(size_t)255;
    return p;
  };
  u16*   h     = (u16*)carve((size_t)N_NODESC*HID*2);     // 51.2 MB
  u16*   hh    = (u16*)carve((size_t)N_NODESC*HID*2);     // 51.2 MB
  float* ssrc  = (float*)carve((size_t)N_NODESC*8*4);     // 3.2 MB
  float* sdst  = (float*)carve((size_t)N_NODESC*8*4);     // 3.2 MB
  int*   soff  = (int*)carve((size_t)(N_NODESC+1)*4);
  int*   cursor= (int*)carve((size_t)N_NODESC*4);
  int*   ssorted=(int*)carve((size_t)E_TOT*4);            // 2.0 MB
  int*   btot  = (int*)carve((size_t)NCHUNK*4);
  int*   boff  = (int*)carve((size_t)NCHUNK*4);
  u16*   WT    = (u16*)carve((size_t)NLAYERS*HID*HID*2);  // 0.5 MB
  u16*   VAT   = (u16*)carve((size_t)NLAYERS*16*HID*2);   // 32 KB fused-score matrices
  float* bnpart= (float*)carve((size_t)NPART*512*4);      // 128 KB BN partials
  float* bnscale=(float*)carve(HID*4);
  float* bnshift=(float*)carve(HID*4);
  float* gsum  = (float*)carve((size_t)NGRAPHS*HID*4);    // 128 KB
  int*   gcnt  = (int*)carve((size_t)NGRAPHS*4);          // adjacent to gsum
  u16*   gbf   = (u16*)carve((size_t)NGRAPHS*HID*2);      // 64 KB bf16 pooled graphs
  int*   dflag = (int*)carve(256);
  size_t common = off;
  u16*   gout  = (u16*)carve((size_t)N_NODESC*HID*2);     // +51.2 MB
  const bool useGout = (off <= ws_size);
  if (common > ws_size) return;  // cannot run at all

  const int EB  = (E_TOT + 255)/256;
  const int NB4 = (N_NODESC + 3)/4;      // wave-per-node kernels

  // dtype detection first
  k_detect<<<1, 64, 0, stream>>>(type_emb, dflag);

  // setup (k_embed also zeroes cursor)
  k_embed<<<NCH64, 256, 0, stream>>>(x, node_depth, type_emb, attr_emb, depth_emb, h, dflag, cursor);
  k_transW<<<dim3(256, NLAYERS), 256, 0, stream>>>(Ws, WT, dflag);
  k_prepVA<<<NLAYERS, 256, 0, stream>>>(Ws, att_src, att_dst, VAT, dflag);
  k_hist<<<EB, 256, 0, stream>>>(edge_index, cursor);
  k_scan_part<<<NCHUNK, 256, 0, stream>>>(cursor, soff, btot);
  k_scan_tot<<<1, 256, 0, stream>>>(btot, boff, soff + N_NODESC);
  k_scan_add<<<NCHUNK, 256, 0, stream>>>(soff, boff, cursor);   // also zeroes cursor
  k_scatter<<<EB, 256, 0, stream>>>(edge_index, soff, cursor, ssorted);

  // layers — Tier A: bn_apply of layer l-1 and scores fused into gemm of layer l
  for (int l = 0; l < NLAYERS; ++l){
    int H = (l == NLAYERS-1) ? 1 : 8;
    int doApply = (useGout && l > 0) ? 1 : 0;
    k_gemm<<<1024, 256, 0, stream>>>(h, gout, bnscale, bnshift, doApply,
                                     WT + (size_t)l*HID*HID, VAT + (size_t)l*16*HID,
                                     hh, ssrc, sdst, H, bnpart);
    if (useGout){
      k_attn_gout<<<ATTNB, 256, 0, stream>>>(hh, ssrc, sdst, soff, ssorted, gout, H, bnpart);
      k_bn_final<<<1, 256, 0, stream>>>(bnpart, bn_gamma, bn_beta, bnscale, bnshift, dflag, l*HID);
    } else {
      k_attn_stats<<<2048, 256, 0, stream>>>(hh, ssrc, sdst, soff, ssorted, bnpart, H);
      k_bn_final<<<1, 256, 0, stream>>>(bnpart, bn_gamma, bn_beta, bnscale, bnshift, dflag, l*HID);
      k_attn_apply<<<NB4, 256, 0, stream>>>(hh, ssrc, sdst, soff, ssorted, bnscale, bnshift, h, H);
    }
  }

  // pool (gsum+gcnt adjacent -> single zero launch)
  k_zero<<<(NGRAPHS*HID + NGRAPHS + 255)/256, 256, 0, stream>>>((int*)gsum, NGRAPHS*HID + NGRAPHS);
  if (useGout)
    k_pool_fused<<<NCH64, 256, 0, stream>>>(h, gout, bnscale, bnshift, batch, gsum, gcnt);
  else
    k_pool<<<NCHUNK, 256, 0, stream>>>(h, batch, gsum, gcnt);
  k_gprep<<<NGRAPHS, 256, 0, stream>>>(gsum, gcnt, gbf);

  // predictors (MFMA GEMM)
  k_pred<<<dim3(NVQ, SEQLEN), 256, 0, stream>>>(gbf, tok_W, tok_b, d_out, dflag);
}